// Round 1
// baseline (541.616 us; speedup 1.0000x reference)
//
#include <hip/hip_runtime.h>

#define TT 256   // output positions (per side) per block in the level kernels

__device__ __forceinline__ float fast_tanh(float x) {
  // 1 - 2/(e^{2x}+1); correct limits at +-inf, ~1e-6 rel error
  return 1.f - __fdividef(2.f, __expf(2.f * x) + 1.f);
}

// Two-layer conv chain (8ch -> 32ch K=3, leaky 0.01 -> 8ch K=3), producing the
// pre-tanh accumulators for 2 consecutive output positions t, t+1.
// in[ic][u] holds the (edge-clamped) conv-input at positions t-2 .. t+3.
__device__ __forceinline__ void conv_core(const float in[8][6],
                                          const float* __restrict__ w1,
                                          const float* __restrict__ w2,
                                          float acc[8][2])
{
#pragma unroll
  for (int c = 0; c < 8; ++c) { acc[c][0] = 0.f; acc[c][1] = 0.f; }

  for (int ocb = 0; ocb < 4; ++ocb) {          // 32 hidden ch in chunks of 8
    float hid[8][4];                           // hidden at positions t-1..t+2
#pragma unroll
    for (int oo = 0; oo < 8; ++oo) {
      hid[oo][0] = 0.f; hid[oo][1] = 0.f; hid[oo][2] = 0.f; hid[oo][3] = 0.f;
    }
#pragma unroll
    for (int ic = 0; ic < 8; ++ic)
#pragma unroll
      for (int oo = 0; oo < 8; ++oo)
#pragma unroll
        for (int k = 0; k < 3; ++k) {
          const float w = w1[(ocb * 8 + oo) * 24 + ic * 3 + k];   // uniform -> s_load
#pragma unroll
          for (int uu = 0; uu < 4; ++uu)
            hid[oo][uu] = fmaf(in[ic][uu + k], w, hid[oo][uu]);
        }
#pragma unroll
    for (int oo = 0; oo < 8; ++oo)
#pragma unroll
      for (int uu = 0; uu < 4; ++uu)
        hid[oo][uu] = hid[oo][uu] > 0.f ? hid[oo][uu] : 0.01f * hid[oo][uu];
#pragma unroll
    for (int c = 0; c < 8; ++c)
#pragma unroll
      for (int oo = 0; oo < 8; ++oo)
#pragma unroll
        for (int k = 0; k < 3; ++k) {
          const float w = w2[c * 96 + (ocb * 8 + oo) * 3 + k];    // uniform -> s_load
          acc[c][0] = fmaf(hid[oo][0 + k], w, acc[c][0]);
          acc[c][1] = fmaf(hid[oo][1 + k], w, acc[c][1]);
        }
  }
}

// Kernel A: X [nB][8][T] -> Es, Os [nB][8][T2]  (T2 = T/2)
//   Es = F_even * exp(conv_op(F_odd , pair1)),  Os = F_odd * exp(conv_op(F_even, pair3))
//   F_odd[j] = X[2j], F_even[j] = X[2j+1]
__global__ __launch_bounds__(256) void level_a(
    const float* __restrict__ X, float* __restrict__ Es, float* __restrict__ Os,
    const float* __restrict__ W1, const float* __restrict__ W2,
    int T2, int tilesPerSeq)
{
  __shared__ float Fo[8][TT + 6];
  __shared__ float Fe[8][TT + 6];
  const int blk = blockIdx.x;
  const int nb  = blk / tilesPerSeq;
  const int t0  = (blk - nb * tilesPerSeq) * TT;
  const float2* Xrow = (const float2*)(X + (size_t)nb * 8 * (2 * (size_t)T2));

  for (int c = 0; c < 8; ++c)
    for (int jj = threadIdx.x; jj < TT + 5; jj += 256) {
      int j = t0 - 2 + jj;
      j = j < 0 ? 0 : (j > T2 - 1 ? T2 - 1 : j);     // edge padding = clamp
      float2 v = Xrow[(size_t)c * T2 + j];
      Fo[c][jj] = v.x;
      Fe[c][jj] = v.y;
    }
  __syncthreads();

  const int sideU = __builtin_amdgcn_readfirstlane((int)(threadIdx.x >> 7)); // 0:even-out 1:odd-out
  const int lt = threadIdx.x & 127;
  const int tl = lt * 2;                              // local output pos (covers tl, tl+1)

  const float (*A)[TT + 6] = sideU ? Fe : Fo;         // conv input
  const float (*M)[TT + 6] = sideU ? Fo : Fe;         // multiplier source
  const float* w1 = W1 + (sideU ? 3 : 1) * 768;
  const float* w2 = W2 + (sideU ? 3 : 1) * 768;

  float in[8][6];
#pragma unroll
  for (int ic = 0; ic < 8; ++ic)
#pragma unroll
    for (int u = 0; u < 6; ++u)
      in[ic][u] = A[ic][tl + u];

  float acc[8][2];
  conv_core(in, w1, w2, acc);

  float* Out = sideU ? Os : Es;
#pragma unroll
  for (int c = 0; c < 8; ++c) {
    float2 v;
    v.x = M[c][tl + 2] * __expf(fast_tanh(acc[c][0]));
    v.y = M[c][tl + 3] * __expf(fast_tanh(acc[c][1]));
    *(float2*)(Out + ((size_t)nb * 8 + c) * T2 + t0 + tl) = v;
  }
}

// Kernel B: Es, Os [nB][8][T2] -> NEXT [(2i+side)*128+b][8][T2]
//   side0: F_even_final = Os - conv_op(Os, pair0)   -> seq 2i
//   side1: F_odd_final  = Es + conv_op(Es, pair2)   -> seq 2i+1
__global__ __launch_bounds__(256) void level_b(
    const float* __restrict__ Es, const float* __restrict__ Os, float* __restrict__ NEXT,
    const float* __restrict__ W1, const float* __restrict__ W2,
    int T2, int tilesPerSeq)
{
  __shared__ float Ae[8][TT + 6];
  __shared__ float Ao[8][TT + 6];
  const int blk = blockIdx.x;
  const int nb  = blk / tilesPerSeq;
  const int t0  = (blk - nb * tilesPerSeq) * TT;

  for (int c = 0; c < 8; ++c)
    for (int jj = threadIdx.x; jj < TT + 5; jj += 256) {
      int j = t0 - 2 + jj;
      j = j < 0 ? 0 : (j > T2 - 1 ? T2 - 1 : j);
      size_t base = ((size_t)nb * 8 + c) * T2 + j;
      Ae[c][jj] = Es[base];
      Ao[c][jj] = Os[base];
    }
  __syncthreads();

  const int sideU = __builtin_amdgcn_readfirstlane((int)(threadIdx.x >> 7));
  const int lt = threadIdx.x & 127;
  const int tl = lt * 2;

  const float (*A)[TT + 6] = sideU ? Ae : Ao;
  const float* w1 = W1 + (sideU ? 2 : 0) * 768;
  const float* w2 = W2 + (sideU ? 2 : 0) * 768;

  float in[8][6];
#pragma unroll
  for (int ic = 0; ic < 8; ++ic)
#pragma unroll
    for (int u = 0; u < 6; ++u)
      in[ic][u] = A[ic][tl + u];

  float acc[8][2];
  conv_core(in, w1, w2, acc);

  const float sgn = sideU ? 1.f : -1.f;
  const int i = nb >> 7;          // B = 128
  const int b = nb & 127;
  const int outseq = 2 * i + sideU;
#pragma unroll
  for (int c = 0; c < 8; ++c) {
    float2 v;
    v.x = A[c][tl + 2] + sgn * fast_tanh(acc[c][0]);
    v.y = A[c][tl + 3] + sgn * fast_tanh(acc[c][1]);
    *(float2*)(NEXT + (((size_t)outseq * 128 + b) * 8 + c) * T2 + t0 + tl) = v;
  }
}

// F_concat[row][8t+r] = P[bitrev3(r)][b][c][t] + x[row][8t+r],  row = b*8+c
__global__ __launch_bounds__(256) void concat_add(
    const float* __restrict__ P, const float* __restrict__ x, float* __restrict__ F)
{
  const int idx = blockIdx.x * 256 + threadIdx.x;   // 1024 rows * 1024 t
  const int row = idx >> 10;
  const int t   = idx & 1023;
  const int b = row >> 3, c = row & 7;
  const int rev[8] = {0, 4, 2, 6, 1, 5, 3, 7};
  float vals[8];
#pragma unroll
  for (int r = 0; r < 8; ++r)
    vals[r] = P[(((size_t)rev[r] * 128 + b) * 8 + c) * 1024 + t];
  const float4* x4 = (const float4*)(x + (size_t)row * 8192 + t * 8);
  float4 a0 = x4[0], a1 = x4[1];
  float4 o0 = make_float4(vals[0] + a0.x, vals[1] + a0.y, vals[2] + a0.z, vals[3] + a0.w);
  float4 o1 = make_float4(vals[4] + a1.x, vals[5] + a1.y, vals[6] + a1.z, vals[7] + a1.w);
  float4* F4 = (float4*)(F + (size_t)row * 8192 + t * 8);
  F4[0] = o0; F4[1] = o1;
}

// FC1 split-K GEMM stage: partial[ch][row][h64] += F[row][s]*W[h][s] over chunk ch
__global__ __launch_bounds__(256) void fc1_stage1(
    const float* __restrict__ F, const float* __restrict__ W, float* __restrict__ partial)
{
  const int rt = blockIdx.x & 31;   // row tile: 32 rows
  const int ch = blockIdx.x >> 5;   // 16 chunks of 512 s
  const int s0 = ch * 512;
  __shared__ float Fl[32][132];     // +pad to break bank alignment
  __shared__ float Wl[64][132];
  const int hg = threadIdx.x & 15;
  const int rg = threadIdx.x >> 4;  // 0..15
  float acc[2][4] = {{0.f, 0.f, 0.f, 0.f}, {0.f, 0.f, 0.f, 0.f}};

  for (int sb = 0; sb < 512; sb += 128) {
    __syncthreads();
    for (int i = threadIdx.x; i < 32 * 32; i += 256) {
      int r = i >> 5, s4 = i & 31;
      ((float4*)&Fl[r][0])[s4] =
          ((const float4*)(F + (size_t)(rt * 32 + r) * 8192 + s0 + sb))[s4];
    }
    for (int i = threadIdx.x; i < 64 * 32; i += 256) {
      int hh = i >> 5, s4 = i & 31;
      float4 v = make_float4(0.f, 0.f, 0.f, 0.f);
      if (hh < 50) v = ((const float4*)(W + (size_t)hh * 8192 + s0 + sb))[s4];
      ((float4*)&Wl[hh][0])[s4] = v;
    }
    __syncthreads();
    for (int s4 = 0; s4 < 32; ++s4) {
      float4 fa = ((const float4*)&Fl[rg * 2][0])[s4];
      float4 fb = ((const float4*)&Fl[rg * 2 + 1][0])[s4];
#pragma unroll
      for (int j = 0; j < 4; ++j) {
        float4 w = ((const float4*)&Wl[hg + 16 * j][0])[s4];
        acc[0][j] = fmaf(fa.x, w.x, fmaf(fa.y, w.y, fmaf(fa.z, w.z, fmaf(fa.w, w.w, acc[0][j]))));
        acc[1][j] = fmaf(fb.x, w.x, fmaf(fb.y, w.y, fmaf(fb.z, w.z, fmaf(fb.w, w.w, acc[1][j]))));
      }
    }
  }
#pragma unroll
  for (int rr = 0; rr < 2; ++rr)
#pragma unroll
    for (int j = 0; j < 4; ++j)
      partial[((size_t)ch * 1024 + rt * 32 + rg * 2 + rr) * 64 + hg + 16 * j] = acc[rr][j];
}

// reduce partials + bias + relu, then FC2 -> out[row][24]
__global__ __launch_bounds__(64) void fc_stage2(
    const float* __restrict__ partial, const float* __restrict__ fc1b,
    const float* __restrict__ fc2w, const float* __restrict__ fc2b,
    float* __restrict__ out)
{
  const int row = blockIdx.x;
  const int h = threadIdx.x;      // 0..63
  __shared__ float hs[64];
  float v = 0.f;
  if (h < 50) {
    for (int ch = 0; ch < 16; ++ch)
      v += partial[((size_t)ch * 1024 + row) * 64 + h];
    v += fc1b[h];
    v = v > 0.f ? v : 0.f;
  }
  hs[h] = v;
  __syncthreads();
  if (h < 24) {
    float a = fc2b[h];
    for (int j = 0; j < 50; ++j)
      a = fmaf(hs[j], fc2w[h * 50 + j], a);
    out[(size_t)row * 24 + h] = a;
  }
}

extern "C" void kernel_launch(void* const* d_in, const int* in_sizes, int n_in,
                              void* d_out, int out_size, void* d_ws, size_t ws_size,
                              hipStream_t stream)
{
  const float* x    = (const float*)d_in[0];
  const float* w1a  = (const float*)d_in[1];  // (3,4,32,8,3)
  const float* w2a  = (const float*)d_in[2];  // (3,4,8,32,3)
  const float* fc1w = (const float*)d_in[3];  // (50,8192)
  const float* fc1b = (const float*)d_in[4];  // (50,)
  const float* fc2w = (const float*)d_in[5];  // (24,50)
  const float* fc2b = (const float*)d_in[6];  // (24,)
  float* out = (float*)d_out;

  float* bufX = (float*)d_ws;                          // 8M floats (32 MB)
  float* bufY = bufX + (size_t)8 * 1024 * 1024;        // 8M floats (32 MB)
  float* partial = bufX;                               // 1M floats, reused after levels

  for (int lvl = 0; lvl < 3; ++lvl) {
    const int T2 = (8192 >> lvl) >> 1;
    const int tiles = T2 / TT;
    const int nB = 128 << lvl;
    const float* W1 = w1a + (size_t)lvl * 4 * 768;
    const float* W2 = w2a + (size_t)lvl * 4 * 768;
    const float* Xin = (lvl == 0) ? x : bufX;
    float* Es = bufY;
    float* Os = bufY + (size_t)4 * 1024 * 1024;
    level_a<<<dim3(nB * tiles), dim3(256), 0, stream>>>(Xin, Es, Os, W1, W2, T2, tiles);
    level_b<<<dim3(nB * tiles), dim3(256), 0, stream>>>(Es, Os, bufX, W1, W2, T2, tiles);
  }
  concat_add<<<dim3(4096), dim3(256), 0, stream>>>(bufX, x, bufY);
  fc1_stage1<<<dim3(512), dim3(256), 0, stream>>>(bufY, fc1w, partial);
  fc_stage2<<<dim3(1024), dim3(64), 0, stream>>>(partial, fc1b, fc2w, fc2b, out);
  (void)in_sizes; (void)n_in; (void)out_size; (void)ws_size;
}

// Round 4
// 394.635 us; speedup vs baseline: 1.3724x; 1.3724x over previous
//
#include <hip/hip_runtime.h>

#define TT 256   // output positions (per side) per block in the level kernels

typedef _Float16 h2 __attribute__((ext_vector_type(2)));
typedef __fp16 fp16v2 __attribute__((ext_vector_type(2)));

// Packed conv weights in device-global memory (NOT the d_ws workspace:
// level_b writes the full 8.4M-float tensor into bufX, which clobbered the
// previous in-workspace placement). Rewritten deterministically each launch.
__device__ unsigned int g_w1pk[12 * 384];   // [lvl*4+pair][oc=32][cp=4][k=3]
__device__ unsigned int g_w2pk[12 * 384];   // [lvl*4+pair][oc=8][icp=16][k=3]

__device__ __forceinline__ h2 pkh(float a, float b) {
  fp16v2 r = __builtin_amdgcn_cvt_pkrtz(a, b);
  return __builtin_bit_cast(h2, r);
}

#if __has_builtin(__builtin_amdgcn_fdot2)
#define FDOT2(w, i, c) __builtin_amdgcn_fdot2((w), (i), (c), false)
#else
#define FDOT2(w, i, c) fmaf((float)(w).x, (float)(i).x, fmaf((float)(w).y, (float)(i).y, (c)))
#endif

__device__ __forceinline__ float fast_tanh(float x) {
  return 1.f - __fdividef(2.f, __expf(2.f * x) + 1.f);
}

// Two-layer conv chain with channel-paired f16 dot2 (f32 accumulate).
// in2[cp][u] packs channels (2cp,2cp+1) at clamped position t-2+u.
__device__ __forceinline__ void conv_core_pk(const h2 in2[4][6],
                                             const unsigned int* __restrict__ w1pk,
                                             const unsigned int* __restrict__ w2pk,
                                             float acc[8][2])
{
#pragma unroll
  for (int c = 0; c < 8; ++c) { acc[c][0] = 0.f; acc[c][1] = 0.f; }

  for (int ocb = 0; ocb < 4; ++ocb) {          // 32 hidden ch in chunks of 8
    float hid[8][4];                           // hidden at positions t-1..t+2
#pragma unroll
    for (int oo = 0; oo < 8; ++oo) {
      hid[oo][0] = 0.f; hid[oo][1] = 0.f; hid[oo][2] = 0.f; hid[oo][3] = 0.f;
    }
#pragma unroll
    for (int cp = 0; cp < 4; ++cp)
#pragma unroll
      for (int oo = 0; oo < 8; ++oo)
#pragma unroll
        for (int k = 0; k < 3; ++k) {
          const h2 w = __builtin_bit_cast(h2, w1pk[((ocb * 8 + oo) * 4 + cp) * 3 + k]);
#pragma unroll
          for (int uu = 0; uu < 4; ++uu)
            hid[oo][uu] = FDOT2(w, in2[cp][uu + k], hid[oo][uu]);
        }
#pragma unroll
    for (int oo = 0; oo < 8; ++oo)
#pragma unroll
      for (int uu = 0; uu < 4; ++uu)
        hid[oo][uu] = hid[oo][uu] > 0.f ? hid[oo][uu] : 0.01f * hid[oo][uu];

    h2 hpk[4][4];                              // hidden channel pairs, f16
#pragma unroll
    for (int hp = 0; hp < 4; ++hp)
#pragma unroll
      for (int uu = 0; uu < 4; ++uu)
        hpk[hp][uu] = pkh(hid[2 * hp][uu], hid[2 * hp + 1][uu]);

#pragma unroll
    for (int c = 0; c < 8; ++c)
#pragma unroll
      for (int hp = 0; hp < 4; ++hp)
#pragma unroll
        for (int k = 0; k < 3; ++k) {
          const h2 w = __builtin_bit_cast(h2, w2pk[(c * 16 + ocb * 4 + hp) * 3 + k]);
          acc[c][0] = FDOT2(w, hpk[hp][0 + k], acc[c][0]);
          acc[c][1] = FDOT2(w, hpk[hp][1 + k], acc[c][1]);
        }
  }
}

// Pack conv weights into half2 pairs (channel-pairing). Grid covers 9216 elems.
__global__ __launch_bounds__(256) void pack_weights(
    const float* __restrict__ w1, const float* __restrict__ w2)
{
  int id = blockIdx.x * 256 + threadIdx.x;
  if (id < 4608) {
    int k = id % 3, t = id / 3;
    int cp = t & 3; t >>= 2;
    int oc = t & 31; int lp = t / 32;
    const float* s = w1 + (size_t)(lp * 32 + oc) * 24 + k;
    g_w1pk[id] = __builtin_bit_cast(unsigned int, pkh(s[(2 * cp) * 3], s[(2 * cp + 1) * 3]));
  } else if (id < 9216) {
    int j = id - 4608;
    int k = j % 3, t = j / 3;
    int icp = t & 15; t >>= 4;
    int oc = t & 7; int lp = t / 8;
    const float* s = w2 + (size_t)(lp * 8 + oc) * 96 + k;
    g_w2pk[j] = __builtin_bit_cast(unsigned int, pkh(s[(2 * icp) * 3], s[(2 * icp + 1) * 3]));
  }
}

// Kernel A: X [nB][8][T] -> Es, Os [nB][8][T2]  (T2 = T/2)
//   Es = F_even * exp(conv_op(F_odd , pair1)),  Os = F_odd * exp(conv_op(F_even, pair3))
//   F_odd[j] = X[2j], F_even[j] = X[2j+1]
__global__ __launch_bounds__(256) void level_a(
    const float* __restrict__ X, float* __restrict__ Es, float* __restrict__ Os,
    int lvl, int T2, int tilesPerSeq)
{
  __shared__ float Fo[8][TT + 6];
  __shared__ float Fe[8][TT + 6];
  const int blk = blockIdx.x;
  const int nb  = blk / tilesPerSeq;
  const int t0  = (blk - nb * tilesPerSeq) * TT;
  const float2* Xrow = (const float2*)(X + (size_t)nb * 8 * (2 * (size_t)T2));

  for (int c = 0; c < 8; ++c)
    for (int jj = threadIdx.x; jj < TT + 5; jj += 256) {
      int j = t0 - 2 + jj;
      j = j < 0 ? 0 : (j > T2 - 1 ? T2 - 1 : j);     // edge padding = clamp
      float2 v = Xrow[(size_t)c * T2 + j];
      Fo[c][jj] = v.x;
      Fe[c][jj] = v.y;
    }
  __syncthreads();

  const int sideU = __builtin_amdgcn_readfirstlane((int)(threadIdx.x >> 7)); // 0:even-out 1:odd-out
  const int lt = threadIdx.x & 127;
  const int tl = lt * 2;                              // local output pos (covers tl, tl+1)

  const float (*A)[TT + 6] = sideU ? Fe : Fo;         // conv input
  const float (*M)[TT + 6] = sideU ? Fo : Fe;         // multiplier source
  const unsigned int* w1 = g_w1pk + (lvl * 4 + (sideU ? 3 : 1)) * 384;
  const unsigned int* w2 = g_w2pk + (lvl * 4 + (sideU ? 3 : 1)) * 384;

  h2 in2[4][6];
#pragma unroll
  for (int cp = 0; cp < 4; ++cp)
#pragma unroll
    for (int u = 0; u < 6; ++u)
      in2[cp][u] = pkh(A[2 * cp][tl + u], A[2 * cp + 1][tl + u]);

  float acc[8][2];
  conv_core_pk(in2, w1, w2, acc);

  float* Out = sideU ? Os : Es;
#pragma unroll
  for (int c = 0; c < 8; ++c) {
    float2 v;
    v.x = M[c][tl + 2] * __expf(fast_tanh(acc[c][0]));
    v.y = M[c][tl + 3] * __expf(fast_tanh(acc[c][1]));
    *(float2*)(Out + ((size_t)nb * 8 + c) * T2 + t0 + tl) = v;
  }
}

// Kernel B: Es, Os [nB][8][T2] -> NEXT [(2i+side)*128+b][8][T2]
//   side0: F_even_final = Os - conv_op(Os, pair0)   -> seq 2i
//   side1: F_odd_final  = Es + conv_op(Es, pair2)   -> seq 2i+1
__global__ __launch_bounds__(256) void level_b(
    const float* __restrict__ Es, const float* __restrict__ Os, float* __restrict__ NEXT,
    int lvl, int T2, int tilesPerSeq)
{
  __shared__ float Ae[8][TT + 6];
  __shared__ float Ao[8][TT + 6];
  const int blk = blockIdx.x;
  const int nb  = blk / tilesPerSeq;
  const int t0  = (blk - nb * tilesPerSeq) * TT;

  for (int c = 0; c < 8; ++c)
    for (int jj = threadIdx.x; jj < TT + 5; jj += 256) {
      int j = t0 - 2 + jj;
      j = j < 0 ? 0 : (j > T2 - 1 ? T2 - 1 : j);
      size_t base = ((size_t)nb * 8 + c) * T2 + j;
      Ae[c][jj] = Es[base];
      Ao[c][jj] = Os[base];
    }
  __syncthreads();

  const int sideU = __builtin_amdgcn_readfirstlane((int)(threadIdx.x >> 7));
  const int lt = threadIdx.x & 127;
  const int tl = lt * 2;

  const float (*A)[TT + 6] = sideU ? Ae : Ao;
  const unsigned int* w1 = g_w1pk + (lvl * 4 + (sideU ? 2 : 0)) * 384;
  const unsigned int* w2 = g_w2pk + (lvl * 4 + (sideU ? 2 : 0)) * 384;

  h2 in2[4][6];
#pragma unroll
  for (int cp = 0; cp < 4; ++cp)
#pragma unroll
    for (int u = 0; u < 6; ++u)
      in2[cp][u] = pkh(A[2 * cp][tl + u], A[2 * cp + 1][tl + u]);

  float acc[8][2];
  conv_core_pk(in2, w1, w2, acc);

  const float sgn = sideU ? 1.f : -1.f;
  const int i = nb >> 7;          // B = 128
  const int b = nb & 127;
  const int outseq = 2 * i + sideU;
#pragma unroll
  for (int c = 0; c < 8; ++c) {
    float2 v;
    v.x = A[c][tl + 2] + sgn * fast_tanh(acc[c][0]);
    v.y = A[c][tl + 3] + sgn * fast_tanh(acc[c][1]);
    *(float2*)(NEXT + (((size_t)outseq * 128 + b) * 8 + c) * T2 + t0 + tl) = v;
  }
}

// F_concat[row][8t+r] = P[bitrev3(r)][b][c][t] + x[row][8t+r],  row = b*8+c
__global__ __launch_bounds__(256) void concat_add(
    const float* __restrict__ P, const float* __restrict__ x, float* __restrict__ F)
{
  const int idx = blockIdx.x * 256 + threadIdx.x;   // 1024 rows * 1024 t
  const int row = idx >> 10;
  const int t   = idx & 1023;
  const int b = row >> 3, c = row & 7;
  const int rev[8] = {0, 4, 2, 6, 1, 5, 3, 7};
  float vals[8];
#pragma unroll
  for (int r = 0; r < 8; ++r)
    vals[r] = P[(((size_t)rev[r] * 128 + b) * 8 + c) * 1024 + t];
  const float4* x4 = (const float4*)(x + (size_t)row * 8192 + t * 8);
  float4 a0 = x4[0], a1 = x4[1];
  float4 o0 = make_float4(vals[0] + a0.x, vals[1] + a0.y, vals[2] + a0.z, vals[3] + a0.w);
  float4 o1 = make_float4(vals[4] + a1.x, vals[5] + a1.y, vals[6] + a1.z, vals[7] + a1.w);
  float4* F4 = (float4*)(F + (size_t)row * 8192 + t * 8);
  F4[0] = o0; F4[1] = o1;
}

// FC1 split-K GEMM stage: partial[ch][row][h64] += F[row][s]*W[h][s] over chunk ch
__global__ __launch_bounds__(256) void fc1_stage1(
    const float* __restrict__ F, const float* __restrict__ W, float* __restrict__ partial)
{
  const int rt = blockIdx.x & 31;   // row tile: 32 rows
  const int ch = blockIdx.x >> 5;   // 16 chunks of 512 s
  const int s0 = ch * 512;
  __shared__ float Fl[32][132];     // +pad to break bank alignment
  __shared__ float Wl[64][132];
  const int hg = threadIdx.x & 15;
  const int rg = threadIdx.x >> 4;  // 0..15
  float acc[2][4] = {{0.f, 0.f, 0.f, 0.f}, {0.f, 0.f, 0.f, 0.f}};

  for (int sb = 0; sb < 512; sb += 128) {
    __syncthreads();
    for (int i = threadIdx.x; i < 32 * 32; i += 256) {
      int r = i >> 5, s4 = i & 31;
      ((float4*)&Fl[r][0])[s4] =
          ((const float4*)(F + (size_t)(rt * 32 + r) * 8192 + s0 + sb))[s4];
    }
    for (int i = threadIdx.x; i < 64 * 32; i += 256) {
      int hh = i >> 5, s4 = i & 31;
      float4 v = make_float4(0.f, 0.f, 0.f, 0.f);
      if (hh < 50) v = ((const float4*)(W + (size_t)hh * 8192 + s0 + sb))[s4];
      ((float4*)&Wl[hh][0])[s4] = v;
    }
    __syncthreads();
    for (int s4 = 0; s4 < 32; ++s4) {
      float4 fa = ((const float4*)&Fl[rg * 2][0])[s4];
      float4 fb = ((const float4*)&Fl[rg * 2 + 1][0])[s4];
#pragma unroll
      for (int j = 0; j < 4; ++j) {
        float4 w = ((const float4*)&Wl[hg + 16 * j][0])[s4];
        acc[0][j] = fmaf(fa.x, w.x, fmaf(fa.y, w.y, fmaf(fa.z, w.z, fmaf(fa.w, w.w, acc[0][j]))));
        acc[1][j] = fmaf(fb.x, w.x, fmaf(fb.y, w.y, fmaf(fb.z, w.z, fmaf(fb.w, w.w, acc[1][j]))));
      }
    }
  }
#pragma unroll
  for (int rr = 0; rr < 2; ++rr)
#pragma unroll
    for (int j = 0; j < 4; ++j)
      partial[((size_t)ch * 1024 + rt * 32 + rg * 2 + rr) * 64 + hg + 16 * j] = acc[rr][j];
}

// reduce partials + bias + relu, then FC2 -> out[row][24]
__global__ __launch_bounds__(64) void fc_stage2(
    const float* __restrict__ partial, const float* __restrict__ fc1b,
    const float* __restrict__ fc2w, const float* __restrict__ fc2b,
    float* __restrict__ out)
{
  const int row = blockIdx.x;
  const int h = threadIdx.x;      // 0..63
  __shared__ float hs[64];
  float v = 0.f;
  if (h < 50) {
    for (int ch = 0; ch < 16; ++ch)
      v += partial[((size_t)ch * 1024 + row) * 64 + h];
    v += fc1b[h];
    v = v > 0.f ? v : 0.f;
  }
  hs[h] = v;
  __syncthreads();
  if (h < 24) {
    float a = fc2b[h];
    for (int j = 0; j < 50; ++j)
      a = fmaf(hs[j], fc2w[h * 50 + j], a);
    out[(size_t)row * 24 + h] = a;
  }
}

extern "C" void kernel_launch(void* const* d_in, const int* in_sizes, int n_in,
                              void* d_out, int out_size, void* d_ws, size_t ws_size,
                              hipStream_t stream)
{
  const float* x    = (const float*)d_in[0];
  const float* w1a  = (const float*)d_in[1];  // (3,4,32,8,3)
  const float* w2a  = (const float*)d_in[2];  // (3,4,8,32,3)
  const float* fc1w = (const float*)d_in[3];  // (50,8192)
  const float* fc1b = (const float*)d_in[4];  // (50,)
  const float* fc2w = (const float*)d_in[5];  // (24,50)
  const float* fc2b = (const float*)d_in[6];  // (24,)
  float* out = (float*)d_out;

  float* bufX = (float*)d_ws;                          // levels ping buffer (8M floats, fully used)
  float* bufY = bufX + (size_t)8 * 1024 * 1024;        // pong buffer (8M floats)
  float* partial = bufX;                               // 1M floats, reused after levels

  pack_weights<<<dim3(36), dim3(256), 0, stream>>>(w1a, w2a);

  for (int lvl = 0; lvl < 3; ++lvl) {
    const int T2 = (8192 >> lvl) >> 1;
    const int tiles = T2 / TT;
    const int nB = 128 << lvl;
    const float* Xin = (lvl == 0) ? x : bufX;
    float* Es = bufY;
    float* Os = bufY + (size_t)4 * 1024 * 1024;
    level_a<<<dim3(nB * tiles), dim3(256), 0, stream>>>(Xin, Es, Os, lvl, T2, tiles);
    level_b<<<dim3(nB * tiles), dim3(256), 0, stream>>>(Es, Os, bufX, lvl, T2, tiles);
  }
  concat_add<<<dim3(4096), dim3(256), 0, stream>>>(bufX, x, bufY);
  fc1_stage1<<<dim3(512), dim3(256), 0, stream>>>(bufY, fc1w, partial);
  fc_stage2<<<dim3(1024), dim3(64), 0, stream>>>(partial, fc1b, fc2w, fc2b, out);
  (void)in_sizes; (void)n_in; (void)out_size; (void)ws_size;
}

// Round 5
// 394.497 us; speedup vs baseline: 1.3729x; 1.0004x over previous
//
#include <hip/hip_runtime.h>

#define TT 256        // output positions (per side) per block in the level kernels
#define TIN (TT + 4)  // staged input positions: local -2 .. TT+1

typedef _Float16 h2 __attribute__((ext_vector_type(2)));
typedef __fp16 fp16v2 __attribute__((ext_vector_type(2)));

// Packed conv weights in device-global memory (NOT d_ws: level_b writes the
// full 8.4M-float tensor into bufX). Rewritten deterministically each launch.
__device__ unsigned int g_w1pk[12 * 384];   // [lvl*4+pair][oc=32][cp=4][k=3]
__device__ unsigned int g_w2pk[12 * 384];   // [lvl*4+pair][oc=8][icp=16][k=3]

__device__ __forceinline__ h2 pkh(float a, float b) {
  fp16v2 r = __builtin_amdgcn_cvt_pkrtz(a, b);
  return __builtin_bit_cast(h2, r);
}

#if __has_builtin(__builtin_amdgcn_fdot2)
#define FDOT2(w, i, c) __builtin_amdgcn_fdot2((w), (i), (c), false)
#else
#define FDOT2(w, i, c) fmaf((float)(w).x, (float)(i).x, fmaf((float)(w).y, (float)(i).y, (c)))
#endif

__device__ __forceinline__ float fast_tanh(float x) {
  return 1.f - __fdividef(2.f, __expf(2.f * x) + 1.f);
}

// ---- two-stage conv chain through LDS parity planes ------------------------
// hidE[s][hp][i] = hidden pair hp at position 2i   (i in [0,128])
// hidO[s][hp][i] = hidden pair hp at position 2i-1 (i in [0,128])
// Stage 1: thread (s,l) computes hid at pos 2l -> hidE[s][*][l]
//                                 and pos 2l+1 -> hidO[s][*][l+1].
// Halo: wave w computes the 32 hidden ch of one halo position:
//   (s,which) = (w>>1, w&1); which=0 -> pos -1 (hidO idx 0), which=1 -> pos TT
//   (hidE idx TT/2); lane = oc, 12 dot2 each.
// Stage 2: output pos 2l uses (o0,e0,o1); pos 2l+1 uses (e0,o1,e1) where
//   e0=hidE[l], e1=hidE[l+1], o0=hidO[l], o1=hidO[l+1].

// stage-1 main body: A = conv-input rows for this side, in2 window pos 2l-1..2l+2
__device__ __forceinline__ void conv_stage1(
    const float (*A)[TIN], int s, int l,
    const unsigned int* __restrict__ w1,
    h2 (*hidE)[16][130], h2 (*hidO)[16][130])
{
  h2 in2[4][4];
#pragma unroll
  for (int cp = 0; cp < 4; ++cp)
#pragma unroll
    for (int u = 0; u < 4; ++u)   // staged idx (2l-1+u)+2 = 2l+1+u
      in2[cp][u] = pkh(A[2 * cp][2 * l + 1 + u], A[2 * cp + 1][2 * l + 1 + u]);

  for (int ocb = 0; ocb < 4; ++ocb) {
    float h0[8], h1[8];
#pragma unroll
    for (int oo = 0; oo < 8; ++oo) { h0[oo] = 0.f; h1[oo] = 0.f; }
#pragma unroll
    for (int oo = 0; oo < 8; ++oo)
#pragma unroll
      for (int cp = 0; cp < 4; ++cp)
#pragma unroll
        for (int k = 0; k < 3; ++k) {
          const h2 w = __builtin_bit_cast(h2, w1[((ocb * 8 + oo) * 4 + cp) * 3 + k]);
          h0[oo] = FDOT2(w, in2[cp][k], h0[oo]);
          h1[oo] = FDOT2(w, in2[cp][k + 1], h1[oo]);
        }
#pragma unroll
    for (int oo = 0; oo < 8; ++oo) {
      h0[oo] = h0[oo] > 0.f ? h0[oo] : 0.01f * h0[oo];
      h1[oo] = h1[oo] > 0.f ? h1[oo] : 0.01f * h1[oo];
    }
#pragma unroll
    for (int pr = 0; pr < 4; ++pr) {
      hidE[s][ocb * 4 + pr][l]     = pkh(h0[2 * pr], h0[2 * pr + 1]);
      hidO[s][ocb * 4 + pr][l + 1] = pkh(h1[2 * pr], h1[2 * pr + 1]);
    }
  }
}

// halo: one wave handles one (side,which); lanes 0..31 = hidden channel oc
__device__ __forceinline__ void conv_stage1_halo(
    const float (*A0)[TIN], const float (*A1)[TIN],
    const unsigned int* __restrict__ w1base, int pairsel0, int pairsel1,
    h2 (*hidE)[16][130], h2 (*hidO)[16][130])
{
  const int wid = __builtin_amdgcn_readfirstlane((int)(threadIdx.x >> 6));
  const int lane = threadIdx.x & 63;
  if (lane < 32) {
    const int hs = wid >> 1, hw = wid & 1;
    const float (*Ah)[TIN] = hs ? A1 : A0;
    const unsigned int* w1h = w1base + (hs ? pairsel1 : pairsel0) * 384;
    const int base = hw ? (TT + 1) : 0;   // staged idx of window start (pos p-1, p=-1 or TT)
    h2 win[4][3];
#pragma unroll
    for (int cp = 0; cp < 4; ++cp)
#pragma unroll
      for (int u = 0; u < 3; ++u)
        win[cp][u] = pkh(Ah[2 * cp][base + u], Ah[2 * cp + 1][base + u]);
    const int oc = lane;
    float hv = 0.f;
#pragma unroll
    for (int cp = 0; cp < 4; ++cp)
#pragma unroll
      for (int k = 0; k < 3; ++k) {
        const h2 w = __builtin_bit_cast(h2, w1h[(oc * 4 + cp) * 3 + k]);
        hv = FDOT2(w, win[cp][k], hv);
      }
    hv = hv > 0.f ? hv : 0.01f * hv;
    _Float16* dst = hw ? (_Float16*)&hidE[hs][oc >> 1][TT / 2]
                       : (_Float16*)&hidO[hs][oc >> 1][0];
    dst[oc & 1] = (_Float16)hv;
  }
}

// stage 2: layer-2 conv from parity planes, acc[c][0] = pos 2l, acc[c][1] = pos 2l+1
__device__ __forceinline__ void conv_stage2(
    int s, int l, const unsigned int* __restrict__ w2,
    const h2 (*hidE)[16][130], const h2 (*hidO)[16][130],
    float acc[8][2])
{
#pragma unroll
  for (int c = 0; c < 8; ++c) { acc[c][0] = 0.f; acc[c][1] = 0.f; }
#pragma unroll
  for (int hp = 0; hp < 16; ++hp) {
    const h2 e0 = hidE[s][hp][l], e1 = hidE[s][hp][l + 1];
    const h2 o0 = hidO[s][hp][l], o1 = hidO[s][hp][l + 1];
#pragma unroll
    for (int c = 0; c < 8; ++c) {
      const h2 w0 = __builtin_bit_cast(h2, w2[(c * 16 + hp) * 3 + 0]);
      const h2 w1 = __builtin_bit_cast(h2, w2[(c * 16 + hp) * 3 + 1]);
      const h2 w2v = __builtin_bit_cast(h2, w2[(c * 16 + hp) * 3 + 2]);
      acc[c][0] = FDOT2(w0, o0, FDOT2(w1, e0, FDOT2(w2v, o1, acc[c][0])));
      acc[c][1] = FDOT2(w0, e0, FDOT2(w1, o1, FDOT2(w2v, e1, acc[c][1])));
    }
  }
}

// Pack conv weights into half2 pairs (channel-pairing). Grid covers 9216 elems.
__global__ __launch_bounds__(256) void pack_weights(
    const float* __restrict__ w1, const float* __restrict__ w2)
{
  int id = blockIdx.x * 256 + threadIdx.x;
  if (id < 4608) {
    int k = id % 3, t = id / 3;
    int cp = t & 3; t >>= 2;
    int oc = t & 31; int lp = t / 32;
    const float* s = w1 + (size_t)(lp * 32 + oc) * 24 + k;
    g_w1pk[id] = __builtin_bit_cast(unsigned int, pkh(s[(2 * cp) * 3], s[(2 * cp + 1) * 3]));
  } else if (id < 9216) {
    int j = id - 4608;
    int k = j % 3, t = j / 3;
    int icp = t & 15; t >>= 4;
    int oc = t & 7; int lp = t / 8;
    const float* s = w2 + (size_t)(lp * 8 + oc) * 96 + k;
    g_w2pk[j] = __builtin_bit_cast(unsigned int, pkh(s[(2 * icp) * 3], s[(2 * icp + 1) * 3]));
  }
}

// Kernel A: X [nB][8][T] -> Es, Os [nB][8][T2]
//   Es = F_even * exp(conv_op(F_odd , pair1)),  Os = F_odd * exp(conv_op(F_even, pair3))
__global__ __launch_bounds__(256) void level_a(
    const float* __restrict__ X, float* __restrict__ Es, float* __restrict__ Os,
    int lvl, int T2, int tilesPerSeq)
{
  __shared__ float Fo[8][TIN];
  __shared__ float Fe[8][TIN];
  __shared__ h2 hidE[2][16][130];
  __shared__ h2 hidO[2][16][130];
  const int blk = blockIdx.x;
  const int nb  = blk / tilesPerSeq;
  const int t0  = (blk - nb * tilesPerSeq) * TT;
  const float2* Xrow = (const float2*)(X + (size_t)nb * 8 * (2 * (size_t)T2));

  for (int c = 0; c < 8; ++c)
    for (int jj = threadIdx.x; jj < TIN; jj += 256) {
      int j = t0 - 2 + jj;
      j = j < 0 ? 0 : (j > T2 - 1 ? T2 - 1 : j);     // edge padding = clamp
      float2 v = Xrow[(size_t)c * T2 + j];
      Fo[c][jj] = v.x;
      Fe[c][jj] = v.y;
    }
  __syncthreads();

  const int s = __builtin_amdgcn_readfirstlane((int)(threadIdx.x >> 7)); // side
  const int l = threadIdx.x & 127;

  const float (*A)[TIN] = s ? Fe : Fo;                // conv input
  const float (*M)[TIN] = s ? Fo : Fe;                // multiplier source
  const unsigned int* w1 = g_w1pk + (lvl * 4 + (s ? 3 : 1)) * 384;
  const unsigned int* w2 = g_w2pk + (lvl * 4 + (s ? 3 : 1)) * 384;

  conv_stage1(A, s, l, w1, hidE, hidO);
  conv_stage1_halo(Fo, Fe, g_w1pk + lvl * 4 * 384, 1, 3, hidE, hidO);
  __syncthreads();

  float acc[8][2];
  conv_stage2(s, l, w2, hidE, hidO, acc);

  const int tl = 2 * l;
  float* Out = s ? Os : Es;
#pragma unroll
  for (int c = 0; c < 8; ++c) {
    float2 v;
    v.x = M[c][tl + 2] * __expf(fast_tanh(acc[c][0]));
    v.y = M[c][tl + 3] * __expf(fast_tanh(acc[c][1]));
    *(float2*)(Out + ((size_t)nb * 8 + c) * T2 + t0 + tl) = v;
  }
}

// Kernel B: Es, Os [nB][8][T2] -> NEXT [(2i+side)*128+b][8][T2]
//   side0: F_even_final = Os - conv_op(Os, pair0)   -> seq 2i
//   side1: F_odd_final  = Es + conv_op(Es, pair2)   -> seq 2i+1
__global__ __launch_bounds__(256) void level_b(
    const float* __restrict__ Es, const float* __restrict__ Os, float* __restrict__ NEXT,
    int lvl, int T2, int tilesPerSeq)
{
  __shared__ float Ae[8][TIN];
  __shared__ float Ao[8][TIN];
  __shared__ h2 hidE[2][16][130];
  __shared__ h2 hidO[2][16][130];
  const int blk = blockIdx.x;
  const int nb  = blk / tilesPerSeq;
  const int t0  = (blk - nb * tilesPerSeq) * TT;

  for (int c = 0; c < 8; ++c)
    for (int jj = threadIdx.x; jj < TIN; jj += 256) {
      int j = t0 - 2 + jj;
      j = j < 0 ? 0 : (j > T2 - 1 ? T2 - 1 : j);
      size_t base = ((size_t)nb * 8 + c) * T2 + j;
      Ae[c][jj] = Es[base];
      Ao[c][jj] = Os[base];
    }
  __syncthreads();

  const int s = __builtin_amdgcn_readfirstlane((int)(threadIdx.x >> 7));
  const int l = threadIdx.x & 127;

  const float (*A)[TIN] = s ? Ae : Ao;
  const unsigned int* w1 = g_w1pk + (lvl * 4 + (s ? 2 : 0)) * 384;
  const unsigned int* w2 = g_w2pk + (lvl * 4 + (s ? 2 : 0)) * 384;

  conv_stage1(A, s, l, w1, hidE, hidO);
  conv_stage1_halo(Ao, Ae, g_w1pk + lvl * 4 * 384, 0, 2, hidE, hidO);
  __syncthreads();

  float acc[8][2];
  conv_stage2(s, l, w2, hidE, hidO, acc);

  const int tl = 2 * l;
  const float sgn = s ? 1.f : -1.f;
  const int i = nb >> 7;          // B = 128
  const int b = nb & 127;
  const int outseq = 2 * i + s;
#pragma unroll
  for (int c = 0; c < 8; ++c) {
    float2 v;
    v.x = A[c][tl + 2] + sgn * fast_tanh(acc[c][0]);
    v.y = A[c][tl + 3] + sgn * fast_tanh(acc[c][1]);
    *(float2*)(NEXT + (((size_t)outseq * 128 + b) * 8 + c) * T2 + t0 + tl) = v;
  }
}

// F_concat[row][8t+r] = P[bitrev3(r)][b][c][t] + x[row][8t+r],  row = b*8+c
__global__ __launch_bounds__(256) void concat_add(
    const float* __restrict__ P, const float* __restrict__ x, float* __restrict__ F)
{
  const int idx = blockIdx.x * 256 + threadIdx.x;   // 1024 rows * 1024 t
  const int row = idx >> 10;
  const int t   = idx & 1023;
  const int b = row >> 3, c = row & 7;
  const int rev[8] = {0, 4, 2, 6, 1, 5, 3, 7};
  float vals[8];
#pragma unroll
  for (int r = 0; r < 8; ++r)
    vals[r] = P[(((size_t)rev[r] * 128 + b) * 8 + c) * 1024 + t];
  const float4* x4 = (const float4*)(x + (size_t)row * 8192 + t * 8);
  float4 a0 = x4[0], a1 = x4[1];
  float4 o0 = make_float4(vals[0] + a0.x, vals[1] + a0.y, vals[2] + a0.z, vals[3] + a0.w);
  float4 o1 = make_float4(vals[4] + a1.x, vals[5] + a1.y, vals[6] + a1.z, vals[7] + a1.w);
  float4* F4 = (float4*)(F + (size_t)row * 8192 + t * 8);
  F4[0] = o0; F4[1] = o1;
}

// FC1 split-K GEMM stage: partial[ch][row][h64] += F[row][s]*W[h][s] over chunk ch
__global__ __launch_bounds__(256) void fc1_stage1(
    const float* __restrict__ F, const float* __restrict__ W, float* __restrict__ partial)
{
  const int rt = blockIdx.x & 31;   // row tile: 32 rows
  const int ch = blockIdx.x >> 5;   // 16 chunks of 512 s
  const int s0 = ch * 512;
  __shared__ float Fl[32][132];     // +pad to break bank alignment
  __shared__ float Wl[64][132];
  const int hg = threadIdx.x & 15;
  const int rg = threadIdx.x >> 4;  // 0..15
  float acc[2][4] = {{0.f, 0.f, 0.f, 0.f}, {0.f, 0.f, 0.f, 0.f}};

  for (int sb = 0; sb < 512; sb += 128) {
    __syncthreads();
    for (int i = threadIdx.x; i < 32 * 32; i += 256) {
      int r = i >> 5, s4 = i & 31;
      ((float4*)&Fl[r][0])[s4] =
          ((const float4*)(F + (size_t)(rt * 32 + r) * 8192 + s0 + sb))[s4];
    }
    for (int i = threadIdx.x; i < 64 * 32; i += 256) {
      int hh = i >> 5, s4 = i & 31;
      float4 v = make_float4(0.f, 0.f, 0.f, 0.f);
      if (hh < 50) v = ((const float4*)(W + (size_t)hh * 8192 + s0 + sb))[s4];
      ((float4*)&Wl[hh][0])[s4] = v;
    }
    __syncthreads();
    for (int s4 = 0; s4 < 32; ++s4) {
      float4 fa = ((const float4*)&Fl[rg * 2][0])[s4];
      float4 fb = ((const float4*)&Fl[rg * 2 + 1][0])[s4];
#pragma unroll
      for (int j = 0; j < 4; ++j) {
        float4 w = ((const float4*)&Wl[hg + 16 * j][0])[s4];
        acc[0][j] = fmaf(fa.x, w.x, fmaf(fa.y, w.y, fmaf(fa.z, w.z, fmaf(fa.w, w.w, acc[0][j]))));
        acc[1][j] = fmaf(fb.x, w.x, fmaf(fb.y, w.y, fmaf(fb.z, w.z, fmaf(fb.w, w.w, acc[1][j]))));
      }
    }
  }
#pragma unroll
  for (int rr = 0; rr < 2; ++rr)
#pragma unroll
    for (int j = 0; j < 4; ++j)
      partial[((size_t)ch * 1024 + rt * 32 + rg * 2 + rr) * 64 + hg + 16 * j] = acc[rr][j];
}

// reduce partials + bias + relu, then FC2 -> out[row][24]
__global__ __launch_bounds__(64) void fc_stage2(
    const float* __restrict__ partial, const float* __restrict__ fc1b,
    const float* __restrict__ fc2w, const float* __restrict__ fc2b,
    float* __restrict__ out)
{
  const int row = blockIdx.x;
  const int h = threadIdx.x;      // 0..63
  __shared__ float hs[64];
  float v = 0.f;
  if (h < 50) {
    for (int ch = 0; ch < 16; ++ch)
      v += partial[((size_t)ch * 1024 + row) * 64 + h];
    v += fc1b[h];
    v = v > 0.f ? v : 0.f;
  }
  hs[h] = v;
  __syncthreads();
  if (h < 24) {
    float a = fc2b[h];
    for (int j = 0; j < 50; ++j)
      a = fmaf(hs[j], fc2w[h * 50 + j], a);
    out[(size_t)row * 24 + h] = a;
  }
}

extern "C" void kernel_launch(void* const* d_in, const int* in_sizes, int n_in,
                              void* d_out, int out_size, void* d_ws, size_t ws_size,
                              hipStream_t stream)
{
  const float* x    = (const float*)d_in[0];
  const float* w1a  = (const float*)d_in[1];  // (3,4,32,8,3)
  const float* w2a  = (const float*)d_in[2];  // (3,4,8,32,3)
  const float* fc1w = (const float*)d_in[3];  // (50,8192)
  const float* fc1b = (const float*)d_in[4];  // (50,)
  const float* fc2w = (const float*)d_in[5];  // (24,50)
  const float* fc2b = (const float*)d_in[6];  // (24,)
  float* out = (float*)d_out;

  float* bufX = (float*)d_ws;                          // levels ping buffer (8M floats)
  float* bufY = bufX + (size_t)8 * 1024 * 1024;        // pong buffer (8M floats)
  float* partial = bufX;                               // 1M floats, reused after levels

  pack_weights<<<dim3(36), dim3(256), 0, stream>>>(w1a, w2a);

  for (int lvl = 0; lvl < 3; ++lvl) {
    const int T2 = (8192 >> lvl) >> 1;
    const int tiles = T2 / TT;
    const int nB = 128 << lvl;
    const float* Xin = (lvl == 0) ? x : bufX;
    float* Es = bufY;
    float* Os = bufY + (size_t)4 * 1024 * 1024;
    level_a<<<dim3(nB * tiles), dim3(256), 0, stream>>>(Xin, Es, Os, lvl, T2, tiles);
    level_b<<<dim3(nB * tiles), dim3(256), 0, stream>>>(Es, Os, bufX, lvl, T2, tiles);
  }
  concat_add<<<dim3(4096), dim3(256), 0, stream>>>(bufX, x, bufY);
  fc1_stage1<<<dim3(512), dim3(256), 0, stream>>>(bufY, fc1w, partial);
  fc_stage2<<<dim3(1024), dim3(64), 0, stream>>>(partial, fc1b, fc2w, fc2b, out);
  (void)in_sizes; (void)n_in; (void)out_size; (void)ws_size;
}

// Round 6
// 364.179 us; speedup vs baseline: 1.4872x; 1.0833x over previous
//
#include <hip/hip_runtime.h>

#define TT 128        // output positions per side per block
#define TIN (TT + 4)  // staged input positions: pos -2 .. TT+1
#define HID (TT + 2)  // hid positions: pos -1 .. TT

typedef _Float16 h2 __attribute__((ext_vector_type(2)));
typedef __fp16 fp16v2 __attribute__((ext_vector_type(2)));

// Packed conv weights in device-global memory (NOT d_ws: level_b writes the
// full 8.4M-float tensor into bufX). Rewritten deterministically each launch.
__device__ unsigned int g_w1pk[12 * 384];   // [lvl*4+pair][oc=32][cp=4][k=3]
__device__ unsigned int g_w2pk[12 * 384];   // [lvl*4+pair][oc=8][icp=16][k=3]

__device__ __forceinline__ h2 pkh(float a, float b) {
  fp16v2 r = __builtin_amdgcn_cvt_pkrtz(a, b);
  return __builtin_bit_cast(h2, r);
}

#if __has_builtin(__builtin_amdgcn_fdot2)
#define FDOT2(w, i, c) __builtin_amdgcn_fdot2((w), (i), (c), false)
#else
#define FDOT2(w, i, c) fmaf((float)(w).x, (float)(i).x, fmaf((float)(w).y, (float)(i).y, (c)))
#endif

__device__ __forceinline__ float fast_tanh(float x) {
  return 1.f - __fdividef(2.f, __expf(2.f * x) + 1.f);
}

// ---- two-stage conv chain through LDS --------------------------------------
// in_pk[s][cp][idx] = h2(ch 2cp, ch 2cp+1) of side-s conv input at pos idx-2.
// hid[s][hp][idx]   = h2(hid ch 2hp, 2hp+1) at pos idx-1.
// Stage 1: thread (s,p) computes the 32 hid ch at its own pos p -> hid[s][*][p+1].
// Halo: wave w=(tid>>6) handles (hs,hw)=(w>>1,w&1): pos -1 (hw=0) or TT (hw=1);
//       lanes 0..15 each compute hid pair hp.
// Stage 2: thread (s,p): out ch c = sum_hp,k dot2(w2, hid[s][hp][p+k]).

__device__ __forceinline__ void conv_stage1(
    int s, int p, const unsigned int* __restrict__ w1,
    const h2 (*in_pk)[4][TIN], h2 (*hid)[16][HID])
{
  h2 in2[4][3];
#pragma unroll
  for (int cp = 0; cp < 4; ++cp)
#pragma unroll
    for (int u = 0; u < 3; ++u)
      in2[cp][u] = in_pk[s][cp][p + 1 + u];   // input pos p-1..p+1

  for (int ocb = 0; ocb < 4; ++ocb) {
    float h[8];
#pragma unroll
    for (int oo = 0; oo < 8; ++oo) h[oo] = 0.f;
#pragma unroll
    for (int oo = 0; oo < 8; ++oo)
#pragma unroll
      for (int cp = 0; cp < 4; ++cp)
#pragma unroll
        for (int k = 0; k < 3; ++k) {
          const h2 w = __builtin_bit_cast(h2, w1[((ocb * 8 + oo) * 4 + cp) * 3 + k]);
          h[oo] = FDOT2(w, in2[cp][k], h[oo]);
        }
#pragma unroll
    for (int oo = 0; oo < 8; ++oo)
      h[oo] = h[oo] > 0.f ? h[oo] : 0.01f * h[oo];
#pragma unroll
    for (int pr = 0; pr < 4; ++pr)
      hid[s][ocb * 4 + pr][p + 1] = pkh(h[2 * pr], h[2 * pr + 1]);
  }
}

__device__ __forceinline__ void conv_stage1_halo(
    const unsigned int* __restrict__ w1base, int pairsel0, int pairsel1,
    const h2 (*in_pk)[4][TIN], h2 (*hid)[16][HID])
{
  const int wid = __builtin_amdgcn_readfirstlane((int)(threadIdx.x >> 6));
  const int lane = threadIdx.x & 63;
  if (lane < 16) {
    const int hs = wid >> 1, hw = wid & 1;
    const unsigned int* w1h = w1base + (hs ? pairsel1 : pairsel0) * 384;
    const int base = hw ? (TT + 1) : 0;    // staged idx of window start
    h2 win[4][3];
#pragma unroll
    for (int cp = 0; cp < 4; ++cp)
#pragma unroll
      for (int u = 0; u < 3; ++u)
        win[cp][u] = in_pk[hs][cp][base + u];
    const int hp = lane;
    float h0 = 0.f, h1 = 0.f;
#pragma unroll
    for (int cp = 0; cp < 4; ++cp)
#pragma unroll
      for (int k = 0; k < 3; ++k) {
        const h2 wa = __builtin_bit_cast(h2, w1h[((2 * hp) * 4 + cp) * 3 + k]);
        const h2 wb = __builtin_bit_cast(h2, w1h[((2 * hp + 1) * 4 + cp) * 3 + k]);
        h0 = FDOT2(wa, win[cp][k], h0);
        h1 = FDOT2(wb, win[cp][k], h1);
      }
    h0 = h0 > 0.f ? h0 : 0.01f * h0;
    h1 = h1 > 0.f ? h1 : 0.01f * h1;
    hid[hs][hp][hw ? (TT + 1) : 0] = pkh(h0, h1);
  }
}

__device__ __forceinline__ void conv_stage2(
    int s, int p, const unsigned int* __restrict__ w2,
    const h2 (*hid)[16][HID], float acc[8])
{
#pragma unroll
  for (int c = 0; c < 8; ++c) acc[c] = 0.f;
#pragma unroll
  for (int hp = 0; hp < 16; ++hp) {
    const h2 e0 = hid[s][hp][p];
    const h2 e1 = hid[s][hp][p + 1];
    const h2 e2 = hid[s][hp][p + 2];
#pragma unroll
    for (int c = 0; c < 8; ++c) {
      const h2 w0 = __builtin_bit_cast(h2, w2[(c * 16 + hp) * 3 + 0]);
      const h2 w1 = __builtin_bit_cast(h2, w2[(c * 16 + hp) * 3 + 1]);
      const h2 w2v = __builtin_bit_cast(h2, w2[(c * 16 + hp) * 3 + 2]);
      acc[c] = FDOT2(w0, e0, FDOT2(w1, e1, FDOT2(w2v, e2, acc[c])));
    }
  }
}

// Pack conv weights into half2 pairs (channel-pairing). Grid covers 9216 elems.
__global__ __launch_bounds__(256) void pack_weights(
    const float* __restrict__ w1, const float* __restrict__ w2)
{
  int id = blockIdx.x * 256 + threadIdx.x;
  if (id < 4608) {
    int k = id % 3, t = id / 3;
    int cp = t & 3; t >>= 2;
    int oc = t & 31; int lp = t / 32;
    const float* s = w1 + (size_t)(lp * 32 + oc) * 24 + k;
    g_w1pk[id] = __builtin_bit_cast(unsigned int, pkh(s[(2 * cp) * 3], s[(2 * cp + 1) * 3]));
  } else if (id < 9216) {
    int j = id - 4608;
    int k = j % 3, t = j / 3;
    int icp = t & 15; t >>= 4;
    int oc = t & 7; int lp = t / 8;
    const float* s = w2 + (size_t)(lp * 8 + oc) * 96 + k;
    g_w2pk[j] = __builtin_bit_cast(unsigned int, pkh(s[(2 * icp) * 3], s[(2 * icp + 1) * 3]));
  }
}

// Kernel A: X [nB][8][T] -> Es, Os [nB][8][T2]
//   Es = F_even * exp(conv_op(F_odd , pair1)),  Os = F_odd * exp(conv_op(F_even, pair3))
//   F_odd[j] = X[2j] (.x), F_even[j] = X[2j+1] (.y)
__global__ __launch_bounds__(256) void level_a(
    const float* __restrict__ X, float* __restrict__ Es, float* __restrict__ Os,
    int lvl, int T2, int tilesPerSeq)
{
  __shared__ h2 in_pk[2][4][TIN];
  __shared__ h2 hid[2][16][HID];
  const int blk = blockIdx.x;
  const int nb  = blk / tilesPerSeq;
  const int t0  = (blk - nb * tilesPerSeq) * TT;
  const float2* Xrow = (const float2*)(X + (size_t)nb * 8 * (2 * (size_t)T2));

  for (int it = threadIdx.x; it < 4 * TIN; it += 256) {
    const int cp = it / TIN, jj = it - cp * TIN;
    int j = t0 - 2 + jj;
    j = j < 0 ? 0 : (j > T2 - 1 ? T2 - 1 : j);       // edge padding = clamp
    float2 a = Xrow[(size_t)(2 * cp) * T2 + j];
    float2 b = Xrow[(size_t)(2 * cp + 1) * T2 + j];
    in_pk[0][cp][jj] = pkh(a.x, b.x);                // side0 conv input = F_odd
    in_pk[1][cp][jj] = pkh(a.y, b.y);                // side1 conv input = F_even
  }
  __syncthreads();

  const int s = __builtin_amdgcn_readfirstlane((int)(threadIdx.x >> 7));
  const int p = threadIdx.x & 127;
  const unsigned int* w1 = g_w1pk + (lvl * 4 + (s ? 3 : 1)) * 384;
  const unsigned int* w2 = g_w2pk + (lvl * 4 + (s ? 3 : 1)) * 384;

  conv_stage1(s, p, w1, in_pk, hid);
  conv_stage1_halo(g_w1pk + lvl * 4 * 384, 1, 3, in_pk, hid);
  __syncthreads();

  float acc[8];
  conv_stage2(s, p, w2, hid, acc);

  const int tg = t0 + p;
  float* Out = s ? Os : Es;
#pragma unroll
  for (int c = 0; c < 8; ++c) {
    float2 m = Xrow[(size_t)c * T2 + tg];            // L2-hot re-read
    const float mult = s ? m.x : m.y;                // side1 multiplies F_odd
    Out[((size_t)nb * 8 + c) * T2 + tg] = mult * __expf(fast_tanh(acc[c]));
  }
}

// Kernel B: Es, Os [nB][8][T2] -> NEXT [(2i+side)*128+b][8][T2]
//   side0: F_even_final = Os - conv_op(Os, pair0)   -> seq 2i
//   side1: F_odd_final  = Es + conv_op(Es, pair2)   -> seq 2i+1
__global__ __launch_bounds__(256) void level_b(
    const float* __restrict__ Es, const float* __restrict__ Os, float* __restrict__ NEXT,
    int lvl, int T2, int tilesPerSeq)
{
  __shared__ h2 in_pk[2][4][TIN];
  __shared__ h2 hid[2][16][HID];
  const int blk = blockIdx.x;
  const int nb  = blk / tilesPerSeq;
  const int t0  = (blk - nb * tilesPerSeq) * TT;

  for (int it = threadIdx.x; it < 4 * TIN; it += 256) {
    const int cp = it / TIN, jj = it - cp * TIN;
    int j = t0 - 2 + jj;
    j = j < 0 ? 0 : (j > T2 - 1 ? T2 - 1 : j);
    const size_t ra = ((size_t)nb * 8 + 2 * cp) * T2 + j;
    const size_t rb = ((size_t)nb * 8 + 2 * cp + 1) * T2 + j;
    in_pk[0][cp][jj] = pkh(Os[ra], Os[rb]);          // side0 conv input = Os
    in_pk[1][cp][jj] = pkh(Es[ra], Es[rb]);          // side1 conv input = Es
  }
  __syncthreads();

  const int s = __builtin_amdgcn_readfirstlane((int)(threadIdx.x >> 7));
  const int p = threadIdx.x & 127;
  const unsigned int* w1 = g_w1pk + (lvl * 4 + (s ? 2 : 0)) * 384;
  const unsigned int* w2 = g_w2pk + (lvl * 4 + (s ? 2 : 0)) * 384;

  conv_stage1(s, p, w1, in_pk, hid);
  conv_stage1_halo(g_w1pk + lvl * 4 * 384, 0, 2, in_pk, hid);
  __syncthreads();

  float acc[8];
  conv_stage2(s, p, w2, hid, acc);

  const int tg = t0 + p;
  const float sgn = s ? 1.f : -1.f;
  const float* Base = s ? Es : Os;
  const int i = nb >> 7;          // B = 128
  const int b = nb & 127;
  const int outseq = 2 * i + s;
#pragma unroll
  for (int c = 0; c < 8; ++c) {
    const float base = Base[((size_t)nb * 8 + c) * T2 + tg];   // L2-hot re-read
    NEXT[(((size_t)outseq * 128 + b) * 8 + c) * T2 + tg] = base + sgn * fast_tanh(acc[c]);
  }
}

// F_concat[row][8t+r] = P[bitrev3(r)][b][c][t] + x[row][8t+r],  row = b*8+c
__global__ __launch_bounds__(256) void concat_add(
    const float* __restrict__ P, const float* __restrict__ x, float* __restrict__ F)
{
  const int idx = blockIdx.x * 256 + threadIdx.x;   // 1024 rows * 1024 t
  const int row = idx >> 10;
  const int t   = idx & 1023;
  const int b = row >> 3, c = row & 7;
  const int rev[8] = {0, 4, 2, 6, 1, 5, 3, 7};
  float vals[8];
#pragma unroll
  for (int r = 0; r < 8; ++r)
    vals[r] = P[(((size_t)rev[r] * 128 + b) * 8 + c) * 1024 + t];
  const float4* x4 = (const float4*)(x + (size_t)row * 8192 + t * 8);
  float4 a0 = x4[0], a1 = x4[1];
  float4 o0 = make_float4(vals[0] + a0.x, vals[1] + a0.y, vals[2] + a0.z, vals[3] + a0.w);
  float4 o1 = make_float4(vals[4] + a1.x, vals[5] + a1.y, vals[6] + a1.z, vals[7] + a1.w);
  float4* F4 = (float4*)(F + (size_t)row * 8192 + t * 8);
  F4[0] = o0; F4[1] = o1;
}

// FC1 split-K GEMM stage: partial[ch][row][h64] += F[row][s]*W[h][s] over chunk ch
__global__ __launch_bounds__(256) void fc1_stage1(
    const float* __restrict__ F, const float* __restrict__ W, float* __restrict__ partial)
{
  const int rt = blockIdx.x & 31;   // row tile: 32 rows
  const int ch = blockIdx.x >> 5;   // 16 chunks of 512 s
  const int s0 = ch * 512;
  __shared__ float Fl[32][132];     // +pad to break bank alignment
  __shared__ float Wl[64][132];
  const int hg = threadIdx.x & 15;
  const int rg = threadIdx.x >> 4;  // 0..15
  float acc[2][4] = {{0.f, 0.f, 0.f, 0.f}, {0.f, 0.f, 0.f, 0.f}};

  for (int sb = 0; sb < 512; sb += 128) {
    __syncthreads();
    for (int i = threadIdx.x; i < 32 * 32; i += 256) {
      int r = i >> 5, s4 = i & 31;
      ((float4*)&Fl[r][0])[s4] =
          ((const float4*)(F + (size_t)(rt * 32 + r) * 8192 + s0 + sb))[s4];
    }
    for (int i = threadIdx.x; i < 64 * 32; i += 256) {
      int hh = i >> 5, s4 = i & 31;
      float4 v = make_float4(0.f, 0.f, 0.f, 0.f);
      if (hh < 50) v = ((const float4*)(W + (size_t)hh * 8192 + s0 + sb))[s4];
      ((float4*)&Wl[hh][0])[s4] = v;
    }
    __syncthreads();
    for (int s4 = 0; s4 < 32; ++s4) {
      float4 fa = ((const float4*)&Fl[rg * 2][0])[s4];
      float4 fb = ((const float4*)&Fl[rg * 2 + 1][0])[s4];
#pragma unroll
      for (int j = 0; j < 4; ++j) {
        float4 w = ((const float4*)&Wl[hg + 16 * j][0])[s4];
        acc[0][j] = fmaf(fa.x, w.x, fmaf(fa.y, w.y, fmaf(fa.z, w.z, fmaf(fa.w, w.w, acc[0][j]))));
        acc[1][j] = fmaf(fb.x, w.x, fmaf(fb.y, w.y, fmaf(fb.z, w.z, fmaf(fb.w, w.w, acc[1][j]))));
      }
    }
  }
#pragma unroll
  for (int rr = 0; rr < 2; ++rr)
#pragma unroll
    for (int j = 0; j < 4; ++j)
      partial[((size_t)ch * 1024 + rt * 32 + rg * 2 + rr) * 64 + hg + 16 * j] = acc[rr][j];
}

// reduce partials + bias + relu, then FC2 -> out[row][24]
__global__ __launch_bounds__(64) void fc_stage2(
    const float* __restrict__ partial, const float* __restrict__ fc1b,
    const float* __restrict__ fc2w, const float* __restrict__ fc2b,
    float* __restrict__ out)
{
  const int row = blockIdx.x;
  const int h = threadIdx.x;      // 0..63
  __shared__ float hs[64];
  float v = 0.f;
  if (h < 50) {
    for (int ch = 0; ch < 16; ++ch)
      v += partial[((size_t)ch * 1024 + row) * 64 + h];
    v += fc1b[h];
    v = v > 0.f ? v : 0.f;
  }
  hs[h] = v;
  __syncthreads();
  if (h < 24) {
    float a = fc2b[h];
    for (int j = 0; j < 50; ++j)
      a = fmaf(hs[j], fc2w[h * 50 + j], a);
    out[(size_t)row * 24 + h] = a;
  }
}

extern "C" void kernel_launch(void* const* d_in, const int* in_sizes, int n_in,
                              void* d_out, int out_size, void* d_ws, size_t ws_size,
                              hipStream_t stream)
{
  const float* x    = (const float*)d_in[0];
  const float* w1a  = (const float*)d_in[1];  // (3,4,32,8,3)
  const float* w2a  = (const float*)d_in[2];  // (3,4,8,32,3)
  const float* fc1w = (const float*)d_in[3];  // (50,8192)
  const float* fc1b = (const float*)d_in[4];  // (50,)
  const float* fc2w = (const float*)d_in[5];  // (24,50)
  const float* fc2b = (const float*)d_in[6];  // (24,)
  float* out = (float*)d_out;

  float* bufX = (float*)d_ws;                          // levels ping buffer (8M floats)
  float* bufY = bufX + (size_t)8 * 1024 * 1024;        // pong buffer (8M floats)
  float* partial = bufX;                               // 1M floats, reused after levels

  pack_weights<<<dim3(36), dim3(256), 0, stream>>>(w1a, w2a);

  for (int lvl = 0; lvl < 3; ++lvl) {
    const int T2 = (8192 >> lvl) >> 1;
    const int tiles = T2 / TT;
    const int nB = 128 << lvl;
    const float* Xin = (lvl == 0) ? x : bufX;
    float* Es = bufY;
    float* Os = bufY + (size_t)4 * 1024 * 1024;
    level_a<<<dim3(nB * tiles), dim3(256), 0, stream>>>(Xin, Es, Os, lvl, T2, tiles);
    level_b<<<dim3(nB * tiles), dim3(256), 0, stream>>>(Es, Os, bufX, lvl, T2, tiles);
  }
  concat_add<<<dim3(4096), dim3(256), 0, stream>>>(bufX, x, bufY);
  fc1_stage1<<<dim3(512), dim3(256), 0, stream>>>(bufY, fc1w, partial);
  fc_stage2<<<dim3(1024), dim3(64), 0, stream>>>(partial, fc1b, fc2w, fc2b, out);
  (void)in_sizes; (void)n_in; (void)out_size; (void)ws_size;
}

// Round 7
// 205.366 us; speedup vs baseline: 2.6373x; 1.7733x over previous
//
#include <hip/hip_runtime.h>

#define TT 128        // output positions per side per block
#define TIN (TT + 4)  // staged input positions: pos -2 .. TT+1
#define NHID (TT + 2) // hid positions: pos -1 .. TT

typedef _Float16 h2 __attribute__((ext_vector_type(2)));
typedef __fp16 fp16v2 __attribute__((ext_vector_type(2)));
typedef _Float16 f16x8 __attribute__((ext_vector_type(8)));
typedef float f32x4 __attribute__((ext_vector_type(4)));

// Packed weights in device-global memory (NOT d_ws: level_b overwrites it).
__device__ unsigned int g_w1pk[12 * 384];   // halo dot2: [lvl*4+pair][oc32][cp4][k3]
__device__ _Float16 g_w1A[12][2][64][8];    // conv1 A-frags: [pair][Mtile][lane][j], k=kk*8+ic (24..31 zero)
__device__ _Float16 g_w2A[12][3][64][8];    // conv2 A-frags: [pair][kstep][lane][j], rows 8..15 zero

__device__ __forceinline__ h2 pkh(float a, float b) {
  fp16v2 r = __builtin_amdgcn_cvt_pkrtz(a, b);
  return __builtin_bit_cast(h2, r);
}
__device__ __forceinline__ unsigned int pku(float a, float b) {
  return __builtin_bit_cast(unsigned int, pkh(a, b));
}

#if __has_builtin(__builtin_amdgcn_fdot2)
#define FDOT2(w, i, c) __builtin_amdgcn_fdot2((w), (i), (c), false)
#else
#define FDOT2(w, i, c) fmaf((float)(w).x, (float)(i).x, fmaf((float)(w).y, (float)(i).y, (c)))
#endif

__device__ __forceinline__ float fast_tanh(float x) {
  return 1.f - __fdividef(2.f, __expf(2.f * x) + 1.f);
}

// ---- weight packing --------------------------------------------------------
__global__ __launch_bounds__(256) void pack_weights(const float* __restrict__ w1)
{
  int id = blockIdx.x * 256 + threadIdx.x;
  if (id < 4608) {
    int k = id % 3, t = id / 3;
    int cp = t & 3; t >>= 2;
    int oc = t & 31; int lp = t / 32;
    const float* s = w1 + (size_t)(lp * 32 + oc) * 24 + k;
    g_w1pk[id] = pku(s[(2 * cp) * 3], s[(2 * cp + 1) * 3]);
  }
}

__global__ __launch_bounds__(256) void pack_mfma(
    const float* __restrict__ w1, const float* __restrict__ w2)
{
  int id = blockIdx.x * 256 + threadIdx.x;
  if (id >= 12 * 5 * 64) return;
  const int lane = id & 63;
  const int rest = id >> 6;
  const int slot = rest % 5;
  const int pr   = rest / 5;           // lvl*4+pair
  if (slot < 2) {                      // conv1 A-fragment, M-tile = slot
    const int oc = slot * 16 + (lane & 15);
    const int bb = lane >> 4;          // k-group: kk=bb, ic=j
#pragma unroll
    for (int j = 0; j < 8; ++j) {
      float v = (bb < 3) ? w1[((size_t)pr * 32 + oc) * 24 + j * 3 + bb] : 0.f;
      g_w1A[pr][slot][lane][j] = (_Float16)v;
    }
  } else {                             // conv2 A-fragment, k-step t
    const int t = slot - 2;
    const int oc = lane & 15;
#pragma unroll
    for (int j = 0; j < 8; ++j) {
      const int hc = 8 * (lane >> 4) + j;
      float v = (oc < 8) ? w2[((size_t)pr * 8 + oc) * 96 + hc * 3 + t] : 0.f;
      g_w2A[pr][t][lane][j] = (_Float16)v;
    }
  }
}

// ---- hid halo (pos -1 and TT) via 16-lane dot2 -----------------------------
__device__ __forceinline__ void hid_halo(
    const _Float16 (*inS)[TIN][8], _Float16 (*hidS)[NHID][40],
    int side, int hw, const unsigned int* __restrict__ w1h, int lane)
{
  if (lane < 16) {
    const int base = hw ? (TT + 1) : 0;   // staged window start
    h2 win[4][3];
#pragma unroll
    for (int cp = 0; cp < 4; ++cp)
#pragma unroll
      for (int u = 0; u < 3; ++u)
        win[cp][u] = __builtin_bit_cast(h2, *(const unsigned int*)&inS[side][base + u][2 * cp]);
    const int hp = lane;
    float h0 = 0.f, h1 = 0.f;
#pragma unroll
    for (int cp = 0; cp < 4; ++cp)
#pragma unroll
      for (int k = 0; k < 3; ++k) {
        const h2 wa = __builtin_bit_cast(h2, w1h[((2 * hp) * 4 + cp) * 3 + k]);
        const h2 wb = __builtin_bit_cast(h2, w1h[((2 * hp + 1) * 4 + cp) * 3 + k]);
        h0 = FDOT2(wa, win[cp][k], h0);
        h1 = FDOT2(wb, win[cp][k], h1);
      }
    h0 = h0 > 0.f ? h0 : 0.01f * h0;
    h1 = h1 > 0.f ? h1 : 0.01f * h1;
    *(unsigned int*)&hidS[side][hw ? (TT + 1) : 0][2 * hp] = pku(h0, h1);
  }
}

// ---- MFMA conv body shared by both level kernels ---------------------------
// stage1: hid[32][p] = leaky(W1 . im2col(in)), written to hidS
// stage2: acc[8][p]  = W2 . im2col(hid), returned in acc (rows 0..7 on g<2 lanes)
#define CONV_STAGE1(side, wp0, wa0, wa1, inS, hidS, g, col)                       \
  {                                                                               \
    const f32x4 zero_ = {0.f, 0.f, 0.f, 0.f};                                     \
    _Pragma("unroll")                                                             \
    for (int nt = 0; nt < 4; ++nt) {                                              \
      const int p0 = (wp0) + nt * 16;                                             \
      const f16x8 bf = *(const f16x8*)&inS[side][p0 + (col) + 1 + (g)][0];        \
      f32x4 d0 = __builtin_amdgcn_mfma_f32_16x16x32_f16(wa0, bf, zero_, 0, 0, 0); \
      f32x4 d1 = __builtin_amdgcn_mfma_f32_16x16x32_f16(wa1, bf, zero_, 0, 0, 0); \
      _Pragma("unroll")                                                           \
      for (int r = 0; r < 4; ++r) {                                               \
        d0[r] = d0[r] > 0.f ? d0[r] : 0.01f * d0[r];                              \
        d1[r] = d1[r] > 0.f ? d1[r] : 0.01f * d1[r];                              \
      }                                                                           \
      const int hp = p0 + (col) + 1;                                              \
      *(uint2*)&hidS[side][hp][4 * (g)] =                                         \
          make_uint2(pku(d0[0], d0[1]), pku(d0[2], d0[3]));                       \
      *(uint2*)&hidS[side][hp][16 + 4 * (g)] =                                    \
          make_uint2(pku(d1[0], d1[1]), pku(d1[2], d1[3]));                       \
    }                                                                             \
  }

// Kernel A: X [nB][8][T] -> Es, Os [nB][8][T2]
__global__ __launch_bounds__(256) void level_a(
    const float* __restrict__ X, float* __restrict__ Es, float* __restrict__ Os,
    int lvl, int T2, int tilesPerSeq)
{
  __shared__ _Float16 inS[2][TIN][8];     // [side][pos+2][ch] f16
  __shared__ _Float16 hidS[2][NHID][40];  // [side][pos+1][hc(32)+pad8]
  const int blk = blockIdx.x;
  const int nb  = blk / tilesPerSeq;
  const int t0  = (blk - nb * tilesPerSeq) * TT;
  const float2* Xrow = (const float2*)(X + (size_t)nb * 8 * (2 * (size_t)T2));

  for (int jj = threadIdx.x; jj < TIN; jj += 256) {
    int j = t0 - 2 + jj;
    j = j < 0 ? 0 : (j > T2 - 1 ? T2 - 1 : j);       // edge padding = clamp
    unsigned int u0[4], u1[4];
#pragma unroll
    for (int cp = 0; cp < 4; ++cp) {
      float2 a = Xrow[(size_t)(2 * cp) * T2 + j];
      float2 b = Xrow[(size_t)(2 * cp + 1) * T2 + j];
      u0[cp] = pku(a.x, b.x);                        // side0 input = F_odd
      u1[cp] = pku(a.y, b.y);                        // side1 input = F_even
    }
    *(uint4*)&inS[0][jj][0] = make_uint4(u0[0], u0[1], u0[2], u0[3]);
    *(uint4*)&inS[1][jj][0] = make_uint4(u1[0], u1[1], u1[2], u1[3]);
  }
  __syncthreads();

  const int wid  = __builtin_amdgcn_readfirstlane((int)(threadIdx.x >> 6));
  const int lane = threadIdx.x & 63;
  const int side = wid >> 1;
  const int wp0  = (wid & 1) * 64;
  const int g = lane >> 4, col = lane & 15;

  const int pr = lvl * 4 + (side ? 3 : 1);
  const f16x8 wa0 = *(const f16x8*)&g_w1A[pr][0][lane][0];
  const f16x8 wa1 = *(const f16x8*)&g_w1A[pr][1][lane][0];
  const f16x8 wb0 = *(const f16x8*)&g_w2A[pr][0][lane][0];
  const f16x8 wb1 = *(const f16x8*)&g_w2A[pr][1][lane][0];
  const f16x8 wb2 = *(const f16x8*)&g_w2A[pr][2][lane][0];

  CONV_STAGE1(side, wp0, wa0, wa1, inS, hidS, g, col);
  hid_halo(inS, hidS, side, wid & 1, g_w1pk + pr * 384, lane);
  __syncthreads();

  const f32x4 zero = {0.f, 0.f, 0.f, 0.f};
#pragma unroll
  for (int nt = 0; nt < 4; ++nt) {
    const int p0 = wp0 + nt * 16;
    f32x4 acc = zero;
    const f16x8 b0 = *(const f16x8*)&hidS[side][p0 + col + 0][8 * g];
    acc = __builtin_amdgcn_mfma_f32_16x16x32_f16(wb0, b0, acc, 0, 0, 0);
    const f16x8 b1 = *(const f16x8*)&hidS[side][p0 + col + 1][8 * g];
    acc = __builtin_amdgcn_mfma_f32_16x16x32_f16(wb1, b1, acc, 0, 0, 0);
    const f16x8 b2 = *(const f16x8*)&hidS[side][p0 + col + 2][8 * g];
    acc = __builtin_amdgcn_mfma_f32_16x16x32_f16(wb2, b2, acc, 0, 0, 0);
    if (g < 2) {
      const int tg = t0 + p0 + col;
      float* Out = side ? Os : Es;
#pragma unroll
      for (int r = 0; r < 4; ++r) {
        const int c = 4 * g + r;
        float2 m = Xrow[(size_t)c * T2 + tg];        // L2-hot re-read
        const float mult = side ? m.x : m.y;
        Out[((size_t)nb * 8 + c) * T2 + tg] = mult * __expf(fast_tanh(acc[r]));
      }
    }
  }
}

// Kernel B: Es, Os [nB][8][T2] -> NEXT [(2i+side)*128+b][8][T2]
__global__ __launch_bounds__(256) void level_b(
    const float* __restrict__ Es, const float* __restrict__ Os, float* __restrict__ NEXT,
    int lvl, int T2, int tilesPerSeq)
{
  __shared__ _Float16 inS[2][TIN][8];
  __shared__ _Float16 hidS[2][NHID][40];
  const int blk = blockIdx.x;
  const int nb  = blk / tilesPerSeq;
  const int t0  = (blk - nb * tilesPerSeq) * TT;

  for (int jj = threadIdx.x; jj < TIN; jj += 256) {
    int j = t0 - 2 + jj;
    j = j < 0 ? 0 : (j > T2 - 1 ? T2 - 1 : j);
    unsigned int u0[4], u1[4];
#pragma unroll
    for (int cp = 0; cp < 4; ++cp) {
      const size_t ra = ((size_t)nb * 8 + 2 * cp) * T2 + j;
      const size_t rb = ra + T2;
      u0[cp] = pku(Os[ra], Os[rb]);                  // side0 conv input = Os
      u1[cp] = pku(Es[ra], Es[rb]);                  // side1 conv input = Es
    }
    *(uint4*)&inS[0][jj][0] = make_uint4(u0[0], u0[1], u0[2], u0[3]);
    *(uint4*)&inS[1][jj][0] = make_uint4(u1[0], u1[1], u1[2], u1[3]);
  }
  __syncthreads();

  const int wid  = __builtin_amdgcn_readfirstlane((int)(threadIdx.x >> 6));
  const int lane = threadIdx.x & 63;
  const int side = wid >> 1;
  const int wp0  = (wid & 1) * 64;
  const int g = lane >> 4, col = lane & 15;

  const int pr = lvl * 4 + (side ? 2 : 0);
  const f16x8 wa0 = *(const f16x8*)&g_w1A[pr][0][lane][0];
  const f16x8 wa1 = *(const f16x8*)&g_w1A[pr][1][lane][0];
  const f16x8 wb0 = *(const f16x8*)&g_w2A[pr][0][lane][0];
  const f16x8 wb1 = *(const f16x8*)&g_w2A[pr][1][lane][0];
  const f16x8 wb2 = *(const f16x8*)&g_w2A[pr][2][lane][0];

  CONV_STAGE1(side, wp0, wa0, wa1, inS, hidS, g, col);
  hid_halo(inS, hidS, side, wid & 1, g_w1pk + pr * 384, lane);
  __syncthreads();

  const f32x4 zero = {0.f, 0.f, 0.f, 0.f};
  const float sgn = side ? 1.f : -1.f;
  const float* Base = side ? Es : Os;
  const int i = nb >> 7;          // B = 128
  const int b = nb & 127;
  const int outseq = 2 * i + side;
#pragma unroll
  for (int nt = 0; nt < 4; ++nt) {
    const int p0 = wp0 + nt * 16;
    f32x4 acc = zero;
    const f16x8 b0 = *(const f16x8*)&hidS[side][p0 + col + 0][8 * g];
    acc = __builtin_amdgcn_mfma_f32_16x16x32_f16(wb0, b0, acc, 0, 0, 0);
    const f16x8 b1 = *(const f16x8*)&hidS[side][p0 + col + 1][8 * g];
    acc = __builtin_amdgcn_mfma_f32_16x16x32_f16(wb1, b1, acc, 0, 0, 0);
    const f16x8 b2 = *(const f16x8*)&hidS[side][p0 + col + 2][8 * g];
    acc = __builtin_amdgcn_mfma_f32_16x16x32_f16(wb2, b2, acc, 0, 0, 0);
    if (g < 2) {
      const int tg = t0 + p0 + col;
#pragma unroll
      for (int r = 0; r < 4; ++r) {
        const int c = 4 * g + r;
        const float base = Base[((size_t)nb * 8 + c) * T2 + tg];  // L2-hot re-read
        NEXT[(((size_t)outseq * 128 + b) * 8 + c) * T2 + tg] = base + sgn * fast_tanh(acc[r]);
      }
    }
  }
}

// F_concat[row][8t+r] = P[bitrev3(r)][b][c][t] + x[row][8t+r],  row = b*8+c
__global__ __launch_bounds__(256) void concat_add(
    const float* __restrict__ P, const float* __restrict__ x, float* __restrict__ F)
{
  const int idx = blockIdx.x * 256 + threadIdx.x;   // 1024 rows * 1024 t
  const int row = idx >> 10;
  const int t   = idx & 1023;
  const int b = row >> 3, c = row & 7;
  const int rev[8] = {0, 4, 2, 6, 1, 5, 3, 7};
  float vals[8];
#pragma unroll
  for (int r = 0; r < 8; ++r)
    vals[r] = P[(((size_t)rev[r] * 128 + b) * 8 + c) * 1024 + t];
  const float4* x4 = (const float4*)(x + (size_t)row * 8192 + t * 8);
  float4 a0 = x4[0], a1 = x4[1];
  float4 o0 = make_float4(vals[0] + a0.x, vals[1] + a0.y, vals[2] + a0.z, vals[3] + a0.w);
  float4 o1 = make_float4(vals[4] + a1.x, vals[5] + a1.y, vals[6] + a1.z, vals[7] + a1.w);
  float4* F4 = (float4*)(F + (size_t)row * 8192 + t * 8);
  F4[0] = o0; F4[1] = o1;
}

// FC1 split-K GEMM stage: partial[ch][row][h64] += F[row][s]*W[h][s] over chunk ch
__global__ __launch_bounds__(256) void fc1_stage1(
    const float* __restrict__ F, const float* __restrict__ W, float* __restrict__ partial)
{
  const int rt = blockIdx.x & 31;   // row tile: 32 rows
  const int ch = blockIdx.x >> 5;   // 16 chunks of 512 s
  const int s0 = ch * 512;
  __shared__ float Fl[32][132];
  __shared__ float Wl[64][132];
  const int hg = threadIdx.x & 15;
  const int rg = threadIdx.x >> 4;  // 0..15
  float acc[2][4] = {{0.f, 0.f, 0.f, 0.f}, {0.f, 0.f, 0.f, 0.f}};

  for (int sb = 0; sb < 512; sb += 128) {
    __syncthreads();
    for (int i = threadIdx.x; i < 32 * 32; i += 256) {
      int r = i >> 5, s4 = i & 31;
      ((float4*)&Fl[r][0])[s4] =
          ((const float4*)(F + (size_t)(rt * 32 + r) * 8192 + s0 + sb))[s4];
    }
    for (int i = threadIdx.x; i < 64 * 32; i += 256) {
      int hh = i >> 5, s4 = i & 31;
      float4 v = make_float4(0.f, 0.f, 0.f, 0.f);
      if (hh < 50) v = ((const float4*)(W + (size_t)hh * 8192 + s0 + sb))[s4];
      ((float4*)&Wl[hh][0])[s4] = v;
    }
    __syncthreads();
    for (int s4 = 0; s4 < 32; ++s4) {
      float4 fa = ((const float4*)&Fl[rg * 2][0])[s4];
      float4 fb = ((const float4*)&Fl[rg * 2 + 1][0])[s4];
#pragma unroll
      for (int j = 0; j < 4; ++j) {
        float4 w = ((const float4*)&Wl[hg + 16 * j][0])[s4];
        acc[0][j] = fmaf(fa.x, w.x, fmaf(fa.y, w.y, fmaf(fa.z, w.z, fmaf(fa.w, w.w, acc[0][j]))));
        acc[1][j] = fmaf(fb.x, w.x, fmaf(fb.y, w.y, fmaf(fb.z, w.z, fmaf(fb.w, w.w, acc[1][j]))));
      }
    }
  }
#pragma unroll
  for (int rr = 0; rr < 2; ++rr)
#pragma unroll
    for (int j = 0; j < 4; ++j)
      partial[((size_t)ch * 1024 + rt * 32 + rg * 2 + rr) * 64 + hg + 16 * j] = acc[rr][j];
}

// reduce partials + bias + relu, then FC2 -> out[row][24]
__global__ __launch_bounds__(64) void fc_stage2(
    const float* __restrict__ partial, const float* __restrict__ fc1b,
    const float* __restrict__ fc2w, const float* __restrict__ fc2b,
    float* __restrict__ out)
{
  const int row = blockIdx.x;
  const int h = threadIdx.x;      // 0..63
  __shared__ float hs[64];
  float v = 0.f;
  if (h < 50) {
    for (int ch = 0; ch < 16; ++ch)
      v += partial[((size_t)ch * 1024 + row) * 64 + h];
    v += fc1b[h];
    v = v > 0.f ? v : 0.f;
  }
  hs[h] = v;
  __syncthreads();
  if (h < 24) {
    float a = fc2b[h];
    for (int j = 0; j < 50; ++j)
      a = fmaf(hs[j], fc2w[h * 50 + j], a);
    out[(size_t)row * 24 + h] = a;
  }
}

extern "C" void kernel_launch(void* const* d_in, const int* in_sizes, int n_in,
                              void* d_out, int out_size, void* d_ws, size_t ws_size,
                              hipStream_t stream)
{
  const float* x    = (const float*)d_in[0];
  const float* w1a  = (const float*)d_in[1];  // (3,4,32,8,3)
  const float* w2a  = (const float*)d_in[2];  // (3,4,8,32,3)
  const float* fc1w = (const float*)d_in[3];  // (50,8192)
  const float* fc1b = (const float*)d_in[4];  // (50,)
  const float* fc2w = (const float*)d_in[5];  // (24,50)
  const float* fc2b = (const float*)d_in[6];  // (24,)
  float* out = (float*)d_out;

  float* bufX = (float*)d_ws;                          // levels ping buffer (8M floats)
  float* bufY = bufX + (size_t)8 * 1024 * 1024;        // pong buffer (8M floats)
  float* partial = bufX;                               // 1M floats, reused after levels

  pack_weights<<<dim3(18), dim3(256), 0, stream>>>(w1a);
  pack_mfma<<<dim3(15), dim3(256), 0, stream>>>(w1a, w2a);

  for (int lvl = 0; lvl < 3; ++lvl) {
    const int T2 = (8192 >> lvl) >> 1;
    const int tiles = T2 / TT;
    const int nB = 128 << lvl;
    const float* Xin = (lvl == 0) ? x : bufX;
    float* Es = bufY;
    float* Os = bufY + (size_t)4 * 1024 * 1024;
    level_a<<<dim3(nB * tiles), dim3(256), 0, stream>>>(Xin, Es, Os, lvl, T2, tiles);
    level_b<<<dim3(nB * tiles), dim3(256), 0, stream>>>(Es, Os, bufX, lvl, T2, tiles);
  }
  concat_add<<<dim3(4096), dim3(256), 0, stream>>>(bufX, x, bufY);
  fc1_stage1<<<dim3(512), dim3(256), 0, stream>>>(bufY, fc1w, partial);
  fc_stage2<<<dim3(1024), dim3(64), 0, stream>>>(partial, fc1b, fc2w, fc2b, out);
  (void)in_sizes; (void)n_in; (void)out_size; (void)ws_size;
}

// Round 8
// 167.836 us; speedup vs baseline: 3.2271x; 1.2236x over previous
//
#include <hip/hip_runtime.h>

#define TT   128        // output positions per side per block
#define TIN2 (TT + 8)   // staged X: pos -4 .. TT+3
#define NHA  (TT + 6)   // hidA rows: pos -3 .. TT+2
#define NEO  (TT + 4)   // Es/Os rows: pos -2 .. TT+1
#define NHB  (TT + 2)   // hidB rows: pos -1 .. TT

typedef _Float16 h2 __attribute__((ext_vector_type(2)));
typedef __fp16 fp16v2 __attribute__((ext_vector_type(2)));
typedef _Float16 f16x8 __attribute__((ext_vector_type(8)));
typedef float f32x4 __attribute__((ext_vector_type(4)));

// MFMA A-fragments of conv weights (device-global; rewritten every launch).
__device__ _Float16 g_w1A[12][2][64][8];  // conv1: [lvl*4+pair][Mtile][lane][j], k=kk*8+ic (kk=3 zero)
__device__ _Float16 g_w2A[12][3][64][8];  // conv2: [lvl*4+pair][tap][lane][j], oc rows 8..15 zero

__device__ __forceinline__ h2 pkh(float a, float b) {
  fp16v2 r = __builtin_amdgcn_cvt_pkrtz(a, b);
  return __builtin_bit_cast(h2, r);
}
__device__ __forceinline__ unsigned int pku(float a, float b) {
  return __builtin_bit_cast(unsigned int, pkh(a, b));
}
__device__ __forceinline__ float fast_tanh(float x) {
  return 1.f - __fdividef(2.f, __expf(2.f * x) + 1.f);
}

__global__ __launch_bounds__(256) void pack_mfma(
    const float* __restrict__ w1, const float* __restrict__ w2)
{
  int id = blockIdx.x * 256 + threadIdx.x;
  if (id >= 12 * 5 * 64) return;
  const int lane = id & 63;
  const int rest = id >> 6;
  const int slot = rest % 5;
  const int pr   = rest / 5;           // lvl*4+pair
  if (slot < 2) {                      // conv1 A-fragment, M-tile = slot
    const int oc = slot * 16 + (lane & 15);
    const int bb = lane >> 4;          // tap index; bb=3 -> zero pad
#pragma unroll
    for (int j = 0; j < 8; ++j) {
      float v = (bb < 3) ? w1[((size_t)pr * 32 + oc) * 24 + j * 3 + bb] : 0.f;
      g_w1A[pr][slot][lane][j] = (_Float16)v;
    }
  } else {                             // conv2 A-fragment, tap t
    const int t = slot - 2;
    const int oc = lane & 15;
#pragma unroll
    for (int j = 0; j < 8; ++j) {
      const int hc = 8 * (lane >> 4) + j;
      float v = (oc < 8) ? w2[((size_t)pr * 8 + oc) * 96 + hc * 3 + t] : 0.f;
      g_w2A[pr][t][lane][j] = (_Float16)v;
    }
  }
}

// Fused level: X [nB][8][T] -> NEXT [(2i+side)*128+b][8][T2]
//   A: Es = F_even*exp(tanh(conv(F_odd,p1))), Os = F_odd*exp(tanh(conv(F_even,p3)))
//   B: seq 2i   = Os - tanh(conv(Os,p0));  seq 2i+1 = Es + tanh(conv(Es,p2))
__global__ __launch_bounds__(256) void level_fused(
    const float* __restrict__ X, float* __restrict__ NEXT,
    int lvl, int T2, int tilesPerSeq)
{
  __shared__ _Float16 inS[2][TIN2][8];    // [side][pos+4][ch] f16 conv input
  __shared__ _Float16 hidS[2][NHA][40];   // hid planes (reused A then B)
  __shared__ _Float16 esS[2][NEO][8];     // Es/Os f16 (B conv input)
  __shared__ float    esF[2][NEO][8];     // Es/Os fp32 (B base)

  const int blk = blockIdx.x;
  const int nb  = blk / tilesPerSeq;
  const int t0  = (blk - nb * tilesPerSeq) * TT;
  const float2* Xrow = (const float2*)(X + (size_t)nb * 8 * (2 * (size_t)T2));

  for (int jj = threadIdx.x; jj < TIN2; jj += 256) {
    int j = t0 - 4 + jj;
    j = j < 0 ? 0 : (j > T2 - 1 ? T2 - 1 : j);       // edge padding = clamp
    unsigned int u0[4], u1[4];
#pragma unroll
    for (int cp = 0; cp < 4; ++cp) {
      float2 a = Xrow[(size_t)(2 * cp) * T2 + j];
      float2 b = Xrow[(size_t)(2 * cp + 1) * T2 + j];
      u0[cp] = pku(a.x, b.x);                        // side0 input = F_odd
      u1[cp] = pku(a.y, b.y);                        // side1 input = F_even
    }
    *(uint4*)&inS[0][jj][0] = make_uint4(u0[0], u0[1], u0[2], u0[3]);
    *(uint4*)&inS[1][jj][0] = make_uint4(u1[0], u1[1], u1[2], u1[3]);
  }
  __syncthreads();

  const int wid  = __builtin_amdgcn_readfirstlane((int)(threadIdx.x >> 6));
  const int lane = threadIdx.x & 63;
  const int side = wid >> 1, half = wid & 1;
  const int g = lane >> 4, col = lane & 15;
  const int tb = half * 64;            // halves overlap rows 64..79 (benign identical writes)

  const int pa = lvl * 4 + (side ? 3 : 1);
  const int pb = lvl * 4 + (side ? 2 : 0);
  const f16x8 a1w0 = *(const f16x8*)&g_w1A[pa][0][lane][0];
  const f16x8 a1w1 = *(const f16x8*)&g_w1A[pa][1][lane][0];
  const f16x8 a2w0 = *(const f16x8*)&g_w2A[pa][0][lane][0];
  const f16x8 a2w1 = *(const f16x8*)&g_w2A[pa][1][lane][0];
  const f16x8 a2w2 = *(const f16x8*)&g_w2A[pa][2][lane][0];
  const f16x8 b1w0 = *(const f16x8*)&g_w1A[pb][0][lane][0];
  const f16x8 b1w1 = *(const f16x8*)&g_w1A[pb][1][lane][0];
  const f16x8 b2w0 = *(const f16x8*)&g_w2A[pb][0][lane][0];
  const f16x8 b2w1 = *(const f16x8*)&g_w2A[pb][1][lane][0];
  const f16x8 b2w2 = *(const f16x8*)&g_w2A[pb][2][lane][0];
  const f32x4 zero = {0.f, 0.f, 0.f, 0.f};

  // ---- A1: hidA rows (pos -3..TT+2) ----
#pragma unroll
  for (int nt = 0; nt < 5; ++nt) {
    const int row = tb + nt * 16 + col;
    const int rr = (row + g > TIN2 - 1) ? (TIN2 - 1) : (row + g);
    const f16x8 bf = *(const f16x8*)&inS[side][rr][0];
    f32x4 d0 = __builtin_amdgcn_mfma_f32_16x16x32_f16(a1w0, bf, zero, 0, 0, 0);
    f32x4 d1 = __builtin_amdgcn_mfma_f32_16x16x32_f16(a1w1, bf, zero, 0, 0, 0);
#pragma unroll
    for (int r = 0; r < 4; ++r) {
      d0[r] = d0[r] > 0.f ? d0[r] : 0.01f * d0[r];
      d1[r] = d1[r] > 0.f ? d1[r] : 0.01f * d1[r];
    }
    if (row < NHA) {
      *(uint2*)&hidS[side][row][4 * g]      = make_uint2(pku(d0[0], d0[1]), pku(d0[2], d0[3]));
      *(uint2*)&hidS[side][row][16 + 4 * g] = make_uint2(pku(d1[0], d1[1]), pku(d1[2], d1[3]));
    }
  }
  __syncthreads();

  // ---- A2: Es/Os rows (pos -2..TT+1) ----
#pragma unroll
  for (int nt = 0; nt < 5; ++nt) {
    const int row = tb + nt * 16 + col;
    f32x4 acc = zero;
    {
      int rr = (row     > NHA - 1) ? (NHA - 1) : row;
      acc = __builtin_amdgcn_mfma_f32_16x16x32_f16(a2w0, *(const f16x8*)&hidS[side][rr][8 * g], acc, 0, 0, 0);
      rr = (row + 1 > NHA - 1) ? (NHA - 1) : (row + 1);
      acc = __builtin_amdgcn_mfma_f32_16x16x32_f16(a2w1, *(const f16x8*)&hidS[side][rr][8 * g], acc, 0, 0, 0);
      rr = (row + 2 > NHA - 1) ? (NHA - 1) : (row + 2);
      acc = __builtin_amdgcn_mfma_f32_16x16x32_f16(a2w2, *(const f16x8*)&hidS[side][rr][8 * g], acc, 0, 0, 0);
    }
    if (g < 2 && row < NEO) {
      int jm = t0 + row - 2;
      jm = jm < 0 ? 0 : (jm > T2 - 1 ? T2 - 1 : jm);
      float v[4];
#pragma unroll
      for (int r = 0; r < 4; ++r) {
        const int c = 4 * g + r;
        float2 m = Xrow[(size_t)c * T2 + jm];        // L2-hot multiplier re-read (fp32)
        const float mult = side ? m.x : m.y;
        v[r] = mult * __expf(fast_tanh(acc[r]));
      }
      *(uint2*)&esS[side][row][4 * g] = make_uint2(pku(v[0], v[1]), pku(v[2], v[3]));
      *(float4*)&esF[side][row][4 * g] = make_float4(v[0], v[1], v[2], v[3]);
    }
  }
  __syncthreads();

  // ---- B1: hidB rows (pos -1..TT), conv input = other side's Es/Os ----
  const int srcB = side ^ 1;
  const int eoLo = (t0 == 0) ? 2 : 0;                       // replicate-edge padding of Os/Es
  const int eoHi = (t0 + TT >= T2) ? (TT + 1) : (NEO - 1);
#pragma unroll
  for (int nt = 0; nt < 5; ++nt) {
    const int row = tb + nt * 16 + col;
    int rr = row + g;
    rr = rr < eoLo ? eoLo : (rr > eoHi ? eoHi : rr);
    const f16x8 bf = *(const f16x8*)&esS[srcB][rr][0];
    f32x4 d0 = __builtin_amdgcn_mfma_f32_16x16x32_f16(b1w0, bf, zero, 0, 0, 0);
    f32x4 d1 = __builtin_amdgcn_mfma_f32_16x16x32_f16(b1w1, bf, zero, 0, 0, 0);
#pragma unroll
    for (int r = 0; r < 4; ++r) {
      d0[r] = d0[r] > 0.f ? d0[r] : 0.01f * d0[r];
      d1[r] = d1[r] > 0.f ? d1[r] : 0.01f * d1[r];
    }
    if (row < NHB) {
      *(uint2*)&hidS[side][row][4 * g]      = make_uint2(pku(d0[0], d0[1]), pku(d0[2], d0[3]));
      *(uint2*)&hidS[side][row][16 + 4 * g] = make_uint2(pku(d1[0], d1[1]), pku(d1[2], d1[3]));
    }
  }
  __syncthreads();

  // ---- B2: outputs ----
  const float sgn = side ? 1.f : -1.f;
  const int i = nb >> 7;          // B = 128
  const int b = nb & 127;
  const int outseq = 2 * i + side;
#pragma unroll
  for (int nt = 0; nt < 4; ++nt) {
    const int row = half * 64 + nt * 16 + col;      // output pos, exact [0,128)
    f32x4 acc = zero;
    acc = __builtin_amdgcn_mfma_f32_16x16x32_f16(b2w0, *(const f16x8*)&hidS[side][row][8 * g], acc, 0, 0, 0);
    acc = __builtin_amdgcn_mfma_f32_16x16x32_f16(b2w1, *(const f16x8*)&hidS[side][row + 1][8 * g], acc, 0, 0, 0);
    acc = __builtin_amdgcn_mfma_f32_16x16x32_f16(b2w2, *(const f16x8*)&hidS[side][row + 2][8 * g], acc, 0, 0, 0);
    if (g < 2) {
      const int tg = t0 + row;
#pragma unroll
      for (int r = 0; r < 4; ++r) {
        const int c = 4 * g + r;
        const float base = esF[srcB][row + 2][c];
        NEXT[(((size_t)outseq * 128 + b) * 8 + c) * T2 + tg] = base + sgn * fast_tanh(acc[r]);
      }
    }
  }
}

// FC1 split-K with inlined realign+residual: F[row][8t+r] = P[rev3(r)][b][c][t] + x[row][8t+r]
__global__ __launch_bounds__(256) void fc1_fused(
    const float* __restrict__ P, const float* __restrict__ x,
    const float* __restrict__ W, float* __restrict__ partial)
{
  const int rt = blockIdx.x & 31;   // row tile: 32 rows
  const int ch = blockIdx.x >> 5;   // 16 chunks of 512 s
  const int s0 = ch * 512;
  __shared__ float Fl[32][132];
  __shared__ float Wl[64][132];
  const int hg = threadIdx.x & 15;
  const int rg = threadIdx.x >> 4;  // 0..15
  float acc[2][4] = {{0.f, 0.f, 0.f, 0.f}, {0.f, 0.f, 0.f, 0.f}};

  for (int sb = 0; sb < 512; sb += 128) {
    __syncthreads();
    for (int i = threadIdx.x; i < 32 * 32; i += 256) {
      const int r = i >> 5, s4 = i & 31;
      const int row = rt * 32 + r;
      const int b = row >> 3, c = row & 7;
      const int base = s0 + sb + 4 * s4;
      const int t = base >> 3, r0 = base & 7;       // r0 in {0,4}
      const float4 xv = *(const float4*)(x + (size_t)row * 8192 + base);
      float4 fv;
#pragma unroll
      for (int j = 0; j < 4; ++j) {
        const int rr = r0 + j;
        const int rev = ((rr & 1) << 2) | (rr & 2) | ((rr >> 2) & 1);   // bitrev3
        (&fv.x)[j] = P[(((size_t)rev * 128 + b) * 8 + c) * 1024 + t] + (&xv.x)[j];
      }
      ((float4*)&Fl[r][0])[s4] = fv;
    }
    for (int i = threadIdx.x; i < 64 * 32; i += 256) {
      const int hh = i >> 5, s4 = i & 31;
      float4 v = make_float4(0.f, 0.f, 0.f, 0.f);
      if (hh < 50) v = ((const float4*)(W + (size_t)hh * 8192 + s0 + sb))[s4];
      ((float4*)&Wl[hh][0])[s4] = v;
    }
    __syncthreads();
    for (int s4 = 0; s4 < 32; ++s4) {
      const float4 fa = ((const float4*)&Fl[rg * 2][0])[s4];
      const float4 fb = ((const float4*)&Fl[rg * 2 + 1][0])[s4];
#pragma unroll
      for (int j = 0; j < 4; ++j) {
        const float4 w = ((const float4*)&Wl[hg + 16 * j][0])[s4];
        acc[0][j] = fmaf(fa.x, w.x, fmaf(fa.y, w.y, fmaf(fa.z, w.z, fmaf(fa.w, w.w, acc[0][j]))));
        acc[1][j] = fmaf(fb.x, w.x, fmaf(fb.y, w.y, fmaf(fb.z, w.z, fmaf(fb.w, w.w, acc[1][j]))));
      }
    }
  }
#pragma unroll
  for (int rr = 0; rr < 2; ++rr)
#pragma unroll
    for (int j = 0; j < 4; ++j)
      partial[((size_t)ch * 1024 + rt * 32 + rg * 2 + rr) * 64 + hg + 16 * j] = acc[rr][j];
}

// reduce partials + bias + relu, then FC2 -> out[row][24]
__global__ __launch_bounds__(64) void fc_stage2(
    const float* __restrict__ partial, const float* __restrict__ fc1b,
    const float* __restrict__ fc2w, const float* __restrict__ fc2b,
    float* __restrict__ out)
{
  const int row = blockIdx.x;
  const int h = threadIdx.x;      // 0..63
  __shared__ float hs[64];
  float v = 0.f;
  if (h < 50) {
    for (int ch = 0; ch < 16; ++ch)
      v += partial[((size_t)ch * 1024 + row) * 64 + h];
    v += fc1b[h];
    v = v > 0.f ? v : 0.f;
  }
  hs[h] = v;
  __syncthreads();
  if (h < 24) {
    float a = fc2b[h];
    for (int j = 0; j < 50; ++j)
      a = fmaf(hs[j], fc2w[h * 50 + j], a);
    out[(size_t)row * 24 + h] = a;
  }
}

extern "C" void kernel_launch(void* const* d_in, const int* in_sizes, int n_in,
                              void* d_out, int out_size, void* d_ws, size_t ws_size,
                              hipStream_t stream)
{
  const float* x    = (const float*)d_in[0];
  const float* w1a  = (const float*)d_in[1];  // (3,4,32,8,3)
  const float* w2a  = (const float*)d_in[2];  // (3,4,8,32,3)
  const float* fc1w = (const float*)d_in[3];  // (50,8192)
  const float* fc1b = (const float*)d_in[4];  // (50,)
  const float* fc2w = (const float*)d_in[5];  // (24,50)
  const float* fc2b = (const float*)d_in[6];  // (24,)
  float* out = (float*)d_out;

  float* bufX = (float*)d_ws;                          // 8M floats
  float* bufY = bufX + (size_t)8 * 1024 * 1024;        // 8M floats
  float* partial = bufY;                               // reused after levels (bufY dead then)

  pack_mfma<<<dim3(15), dim3(256), 0, stream>>>(w1a, w2a);

  // lvl0: x -> bufX ; lvl1: bufX -> bufY ; lvl2: bufY -> bufX
  level_fused<<<dim3(4096), dim3(256), 0, stream>>>(x,    bufX, 0, 4096, 32);
  level_fused<<<dim3(4096), dim3(256), 0, stream>>>(bufX, bufY, 1, 2048, 16);
  level_fused<<<dim3(4096), dim3(256), 0, stream>>>(bufY, bufX, 2, 1024, 8);

  fc1_fused<<<dim3(512), dim3(256), 0, stream>>>(bufX, x, fc1w, partial);
  fc_stage2<<<dim3(1024), dim3(64), 0, stream>>>(partial, fc1b, fc2w, fc2b, out);
  (void)in_sizes; (void)n_in; (void)out_size; (void)ws_size;
}

// Round 9
// 140.569 us; speedup vs baseline: 3.8530x; 1.1940x over previous
//
#include <hip/hip_runtime.h>

#define TT   128        // output positions per side per block
#define TIN2 (TT + 8)   // staged X: pos -4 .. TT+3
#define NHA  (TT + 6)   // hidA rows: pos -3 .. TT+2
#define NEO  (TT + 4)   // Es/Os rows: pos -2 .. TT+1
#define NHB  (TT + 2)   // hidB rows: pos -1 .. TT
#define NEF  (TT + 2)   // esF rows kept: pos -2 .. TT-1 (B2 needs pos 0..TT-1 only)
#define HROW 44         // hidS row stride in halves (88 B: 11-bank odd stride, <=2-way)

typedef _Float16 h2 __attribute__((ext_vector_type(2)));
typedef __fp16 fp16v2 __attribute__((ext_vector_type(2)));
typedef _Float16 f16x4 __attribute__((ext_vector_type(4)));
typedef _Float16 f16x8 __attribute__((ext_vector_type(8)));
typedef float f32x4 __attribute__((ext_vector_type(4)));

// MFMA A-fragments of conv weights (device-global; rewritten every launch).
__device__ _Float16 g_w1A[12][2][64][8];  // conv1: [lvl*4+pair][Mtile][lane][j], k=kk*8+ic (kk=3 zero)
__device__ _Float16 g_w2A[12][3][64][8];  // conv2: [lvl*4+pair][tap][lane][j], oc rows 8..15 zero

__device__ __forceinline__ h2 pkh(float a, float b) {
  fp16v2 r = __builtin_amdgcn_cvt_pkrtz(a, b);
  return __builtin_bit_cast(h2, r);
}
__device__ __forceinline__ unsigned int pku(float a, float b) {
  return __builtin_bit_cast(unsigned int, pkh(a, b));
}
__device__ __forceinline__ float fast_tanh(float x) {
  return 1.f - __fdividef(2.f, __expf(2.f * x) + 1.f);
}
// lanes 0-31 keep a_low; lanes 32-63 receive b_low from (lane-32)
__device__ __forceinline__ float lane_spread(float a_low, float b_low, int lane) {
  float s = __shfl_xor(b_low, 32);
  return (lane >= 32) ? s : a_low;
}
// two 8B LDS loads (88B row stride is only 8B-aligned)
__device__ __forceinline__ f16x8 ld_hid(const _Float16* p) {
  const f16x4 lo = *(const f16x4*)p;
  const f16x4 hi = *(const f16x4*)(p + 4);
  f16x8 r;
  r[0] = lo[0]; r[1] = lo[1]; r[2] = lo[2]; r[3] = lo[3];
  r[4] = hi[0]; r[5] = hi[1]; r[6] = hi[2]; r[7] = hi[3];
  return r;
}

__global__ __launch_bounds__(256) void pack_mfma(
    const float* __restrict__ w1, const float* __restrict__ w2)
{
  int id = blockIdx.x * 256 + threadIdx.x;
  if (id >= 12 * 5 * 64) return;
  const int lane = id & 63;
  const int rest = id >> 6;
  const int slot = rest % 5;
  const int pr   = rest / 5;           // lvl*4+pair
  if (slot < 2) {                      // conv1 A-fragment, M-tile = slot
    const int oc = slot * 16 + (lane & 15);
    const int bb = lane >> 4;          // tap index; bb=3 -> zero pad
#pragma unroll
    for (int j = 0; j < 8; ++j) {
      float v = (bb < 3) ? w1[((size_t)pr * 32 + oc) * 24 + j * 3 + bb] : 0.f;
      g_w1A[pr][slot][lane][j] = (_Float16)v;
    }
  } else {                             // conv2 A-fragment, tap t
    const int t = slot - 2;
    const int oc = lane & 15;
#pragma unroll
    for (int j = 0; j < 8; ++j) {
      const int hc = 8 * (lane >> 4) + j;
      float v = (oc < 8) ? w2[((size_t)pr * 8 + oc) * 96 + hc * 3 + t] : 0.f;
      g_w2A[pr][t][lane][j] = (_Float16)v;
    }
  }
}

// Fused level: X [nB][8][T] -> NEXT [(2i+side)*128+b][8][T2]
//   A: Es = F_even*exp(tanh(conv(F_odd,p1))), Os = F_odd*exp(tanh(conv(F_even,p3)))
//   B: seq 2i   = Os - tanh(conv(Os,p0));  seq 2i+1 = Es + tanh(conv(Es,p2))
__global__ __launch_bounds__(256) void level_fused(
    const float* __restrict__ X, float* __restrict__ NEXT,
    int lvl, int T2, int tilesPerSeq)
{
  __shared__ _Float16 inS[2][TIN2][8];    // [side][pos+4][ch] f16 conv input
  __shared__ _Float16 hidS[2][NHA][HROW]; // hid planes (reused A then B), 88B rows
  __shared__ _Float16 esS[2][NEO][8];     // Es/Os f16 (B conv input)
  __shared__ float    esF[2][NEF][8];     // Es/Os fp32 (B base), rows pos -2..TT-1

  const int blk = blockIdx.x;
  const int nb  = blk / tilesPerSeq;
  const int t0  = (blk - nb * tilesPerSeq) * TT;
  const float2* Xrow = (const float2*)(X + (size_t)nb * 8 * (2 * (size_t)T2));

  for (int jj = threadIdx.x; jj < TIN2; jj += 256) {
    int j = t0 - 4 + jj;
    j = j < 0 ? 0 : (j > T2 - 1 ? T2 - 1 : j);       // edge padding = clamp
    unsigned int u0[4], u1[4];
#pragma unroll
    for (int cp = 0; cp < 4; ++cp) {
      float2 a = Xrow[(size_t)(2 * cp) * T2 + j];
      float2 b = Xrow[(size_t)(2 * cp + 1) * T2 + j];
      u0[cp] = pku(a.x, b.x);                        // side0 input = F_odd
      u1[cp] = pku(a.y, b.y);                        // side1 input = F_even
    }
    *(uint4*)&inS[0][jj][0] = make_uint4(u0[0], u0[1], u0[2], u0[3]);
    *(uint4*)&inS[1][jj][0] = make_uint4(u1[0], u1[1], u1[2], u1[3]);
  }
  __syncthreads();

  const int wid  = __builtin_amdgcn_readfirstlane((int)(threadIdx.x >> 6));
  const int lane = threadIdx.x & 63;
  const int side = wid >> 1, half = wid & 1;
  const int g = lane >> 4, col = lane & 15;
  const int tb = half * 64;            // halves overlap rows 64..79 (benign identical writes)
  const int rp = ((lane >> 4) & 1) * 2 + (lane >> 5);   // row-pair after lane_spread

  const int pa = lvl * 4 + (side ? 3 : 1);
  const int pb = lvl * 4 + (side ? 2 : 0);
  const f16x8 a1w0 = *(const f16x8*)&g_w1A[pa][0][lane][0];
  const f16x8 a1w1 = *(const f16x8*)&g_w1A[pa][1][lane][0];
  const f16x8 a2w0 = *(const f16x8*)&g_w2A[pa][0][lane][0];
  const f16x8 a2w1 = *(const f16x8*)&g_w2A[pa][1][lane][0];
  const f16x8 a2w2 = *(const f16x8*)&g_w2A[pa][2][lane][0];
  const f16x8 b1w0 = *(const f16x8*)&g_w1A[pb][0][lane][0];
  const f16x8 b1w1 = *(const f16x8*)&g_w1A[pb][1][lane][0];
  const f16x8 b2w0 = *(const f16x8*)&g_w2A[pb][0][lane][0];
  const f16x8 b2w1 = *(const f16x8*)&g_w2A[pb][1][lane][0];
  const f16x8 b2w2 = *(const f16x8*)&g_w2A[pb][2][lane][0];
  const f32x4 zero = {0.f, 0.f, 0.f, 0.f};

  // ---- A1: hidA rows (pos -3..TT+2) ----
#pragma unroll
  for (int nt = 0; nt < 5; ++nt) {
    const int row = tb + nt * 16 + col;
    const int rr = (row + g > TIN2 - 1) ? (TIN2 - 1) : (row + g);
    const f16x8 bf = *(const f16x8*)&inS[side][rr][0];
    f32x4 d0 = __builtin_amdgcn_mfma_f32_16x16x32_f16(a1w0, bf, zero, 0, 0, 0);
    f32x4 d1 = __builtin_amdgcn_mfma_f32_16x16x32_f16(a1w1, bf, zero, 0, 0, 0);
#pragma unroll
    for (int r = 0; r < 4; ++r) {
      d0[r] = d0[r] > 0.f ? d0[r] : 0.01f * d0[r];
      d1[r] = d1[r] > 0.f ? d1[r] : 0.01f * d1[r];
    }
    if (row < NHA) {
      *(uint2*)&hidS[side][row][4 * g]      = make_uint2(pku(d0[0], d0[1]), pku(d0[2], d0[3]));
      *(uint2*)&hidS[side][row][16 + 4 * g] = make_uint2(pku(d1[0], d1[1]), pku(d1[2], d1[3]));
    }
  }
  __syncthreads();

  // ---- A2: Es/Os rows (pos -2..TT+1), epilogue spread over all 64 lanes ----
#pragma unroll
  for (int nt = 0; nt < 5; ++nt) {
    const int row = tb + nt * 16 + col;
    f32x4 acc = zero;
    {
      int rr = (row     > NHA - 1) ? (NHA - 1) : row;
      acc = __builtin_amdgcn_mfma_f32_16x16x32_f16(a2w0, ld_hid(&hidS[side][rr][8 * g]), acc, 0, 0, 0);
      rr = (row + 1 > NHA - 1) ? (NHA - 1) : (row + 1);
      acc = __builtin_amdgcn_mfma_f32_16x16x32_f16(a2w1, ld_hid(&hidS[side][rr][8 * g]), acc, 0, 0, 0);
      rr = (row + 2 > NHA - 1) ? (NHA - 1) : (row + 2);
      acc = __builtin_amdgcn_mfma_f32_16x16x32_f16(a2w2, ld_hid(&hidS[side][rr][8 * g]), acc, 0, 0, 0);
    }
    if (row < NEO) {
      const float va = lane_spread(acc[0], acc[2], lane);
      const float vb = lane_spread(acc[1], acc[3], lane);
      const h2 mpk = *(const h2*)&inS[side ^ 1][row + 2][2 * rp];  // multiplier (f16, staged)
      const float v0 = (float)mpk[0] * __expf(fast_tanh(va));
      const float v1 = (float)mpk[1] * __expf(fast_tanh(vb));
      *(unsigned int*)&esS[side][row][2 * rp] = pku(v0, v1);
      if (row < NEF) *(float2*)&esF[side][row][2 * rp] = make_float2(v0, v1);
    }
  }
  __syncthreads();

  // ---- B1: hidB rows (pos -1..TT), conv input = other side's Es/Os ----
  const int srcB = side ^ 1;
  const int eoLo = (t0 == 0) ? 2 : 0;                       // replicate-edge padding of Os/Es
  const int eoHi = (t0 + TT >= T2) ? (TT + 1) : (NEO - 1);
#pragma unroll
  for (int nt = 0; nt < 5; ++nt) {
    const int row = tb + nt * 16 + col;
    int rr = row + g;
    rr = rr < eoLo ? eoLo : (rr > eoHi ? eoHi : rr);
    const f16x8 bf = *(const f16x8*)&esS[srcB][rr][0];
    f32x4 d0 = __builtin_amdgcn_mfma_f32_16x16x32_f16(b1w0, bf, zero, 0, 0, 0);
    f32x4 d1 = __builtin_amdgcn_mfma_f32_16x16x32_f16(b1w1, bf, zero, 0, 0, 0);
#pragma unroll
    for (int r = 0; r < 4; ++r) {
      d0[r] = d0[r] > 0.f ? d0[r] : 0.01f * d0[r];
      d1[r] = d1[r] > 0.f ? d1[r] : 0.01f * d1[r];
    }
    if (row < NHB) {
      *(uint2*)&hidS[side][row][4 * g]      = make_uint2(pku(d0[0], d0[1]), pku(d0[2], d0[3]));
      *(uint2*)&hidS[side][row][16 + 4 * g] = make_uint2(pku(d1[0], d1[1]), pku(d1[2], d1[3]));
    }
  }
  __syncthreads();

  // ---- B2: outputs, epilogue spread over all 64 lanes ----
  const float sgn = side ? 1.f : -1.f;
  const int i = nb >> 7;          // B = 128
  const int b = nb & 127;
  const int outseq = 2 * i + side;
#pragma unroll
  for (int nt = 0; nt < 4; ++nt) {
    const int row = half * 64 + nt * 16 + col;      // output pos, exact [0,128)
    f32x4 acc = zero;
    acc = __builtin_amdgcn_mfma_f32_16x16x32_f16(b2w0, ld_hid(&hidS[side][row][8 * g]), acc, 0, 0, 0);
    acc = __builtin_amdgcn_mfma_f32_16x16x32_f16(b2w1, ld_hid(&hidS[side][row + 1][8 * g]), acc, 0, 0, 0);
    acc = __builtin_amdgcn_mfma_f32_16x16x32_f16(b2w2, ld_hid(&hidS[side][row + 2][8 * g]), acc, 0, 0, 0);
    const float va = lane_spread(acc[0], acc[2], lane);
    const float vb = lane_spread(acc[1], acc[3], lane);
    const float2 base = *(const float2*)&esF[srcB][row + 2][2 * rp];
    const int tg = t0 + row;
    const int c0 = 2 * rp;
    NEXT[(((size_t)outseq * 128 + b) * 8 + c0) * T2 + tg]     = base.x + sgn * fast_tanh(va);
    NEXT[(((size_t)outseq * 128 + b) * 8 + c0 + 1) * T2 + tg] = base.y + sgn * fast_tanh(vb);
  }
}

// FC1 split-K with inlined realign+residual: F[row][8t+r] = P[rev3(r)][b][c][t] + x[row][8t+r]
__global__ __launch_bounds__(256) void fc1_fused(
    const float* __restrict__ P, const float* __restrict__ x,
    const float* __restrict__ W, float* __restrict__ partial)
{
  const int rt = blockIdx.x & 31;   // row tile: 32 rows
  const int ch = blockIdx.x >> 5;   // 16 chunks of 512 s
  const int s0 = ch * 512;
  __shared__ float Fl[32][132];
  __shared__ float Wl[64][132];
  const int hg = threadIdx.x & 15;
  const int rg = threadIdx.x >> 4;  // 0..15
  float acc[2][4] = {{0.f, 0.f, 0.f, 0.f}, {0.f, 0.f, 0.f, 0.f}};

  for (int sb = 0; sb < 512; sb += 128) {
    __syncthreads();
    for (int i = threadIdx.x; i < 32 * 32; i += 256) {
      const int r = i >> 5, s4 = i & 31;
      const int row = rt * 32 + r;
      const int b = row >> 3, c = row & 7;
      const int base = s0 + sb + 4 * s4;
      const int t = base >> 3, r0 = base & 7;       // r0 in {0,4}
      const float4 xv = *(const float4*)(x + (size_t)row * 8192 + base);
      float4 fv;
#pragma unroll
      for (int j = 0; j < 4; ++j) {
        const int rr = r0 + j;
        const int rev = ((rr & 1) << 2) | (rr & 2) | ((rr >> 2) & 1);   // bitrev3
        (&fv.x)[j] = P[(((size_t)rev * 128 + b) * 8 + c) * 1024 + t] + (&xv.x)[j];
      }
      ((float4*)&Fl[r][0])[s4] = fv;
    }
    for (int i = threadIdx.x; i < 64 * 32; i += 256) {
      const int hh = i >> 5, s4 = i & 31;
      float4 v = make_float4(0.f, 0.f, 0.f, 0.f);
      if (hh < 50) v = ((const float4*)(W + (size_t)hh * 8192 + s0 + sb))[s4];
      ((float4*)&Wl[hh][0])[s4] = v;
    }
    __syncthreads();
    for (int s4 = 0; s4 < 32; ++s4) {
      const float4 fa = ((const float4*)&Fl[rg * 2][0])[s4];
      const float4 fb = ((const float4*)&Fl[rg * 2 + 1][0])[s4];
#pragma unroll
      for (int j = 0; j < 4; ++j) {
        const float4 w = ((const float4*)&Wl[hg + 16 * j][0])[s4];
        acc[0][j] = fmaf(fa.x, w.x, fmaf(fa.y, w.y, fmaf(fa.z, w.z, fmaf(fa.w, w.w, acc[0][j]))));
        acc[1][j] = fmaf(fb.x, w.x, fmaf(fb.y, w.y, fmaf(fb.z, w.z, fmaf(fb.w, w.w, acc[1][j]))));
      }
    }
  }
#pragma unroll
  for (int rr = 0; rr < 2; ++rr)
#pragma unroll
    for (int j = 0; j < 4; ++j)
      partial[((size_t)ch * 1024 + rt * 32 + rg * 2 + rr) * 64 + hg + 16 * j] = acc[rr][j];
}

// reduce partials + bias + relu, then FC2 -> out[row][24]
__global__ __launch_bounds__(64) void fc_stage2(
    const float* __restrict__ partial, const float* __restrict__ fc1b,
    const float* __restrict__ fc2w, const float* __restrict__ fc2b,
    float* __restrict__ out)
{
  const int row = blockIdx.x;
  const int h = threadIdx.x;      // 0..63
  __shared__ float hs[64];
  float v = 0.f;
  if (h < 50) {
    for (int ch = 0; ch < 16; ++ch)
      v += partial[((size_t)ch * 1024 + row) * 64 + h];
    v += fc1b[h];
    v = v > 0.f ? v : 0.f;
  }
  hs[h] = v;
  __syncthreads();
  if (h < 24) {
    float a = fc2b[h];
    for (int j = 0; j < 50; ++j)
      a = fmaf(hs[j], fc2w[h * 50 + j], a);
    out[(size_t)row * 24 + h] = a;
  }
}

extern "C" void kernel_launch(void* const* d_in, const int* in_sizes, int n_in,
                              void* d_out, int out_size, void* d_ws, size_t ws_size,
                              hipStream_t stream)
{
  const float* x    = (const float*)d_in[0];
  const float* w1a  = (const float*)d_in[1];  // (3,4,32,8,3)
  const float* w2a  = (const float*)d_in[2];  // (3,4,8,32,3)
  const float* fc1w = (const float*)d_in[3];  // (50,8192)
  const float* fc1b = (const float*)d_in[4];  // (50,)
  const float* fc2w = (const float*)d_in[5];  // (24,50)
  const float* fc2b = (const float*)d_in[6];  // (24,)
  float* out = (float*)d_out;

  float* bufX = (float*)d_ws;                          // 8M floats
  float* bufY = bufX + (size_t)8 * 1024 * 1024;        // 8M floats
  float* partial = bufY;                               // reused after levels (bufY dead then)

  pack_mfma<<<dim3(15), dim3(256), 0, stream>>>(w1a, w2a);

  // lvl0: x -> bufX ; lvl1: bufX -> bufY ; lvl2: bufY -> bufX
  level_fused<<<dim3(4096), dim3(256), 0, stream>>>(x,    bufX, 0, 4096, 32);
  level_fused<<<dim3(4096), dim3(256), 0, stream>>>(bufX, bufY, 1, 2048, 16);
  level_fused<<<dim3(4096), dim3(256), 0, stream>>>(bufY, bufX, 2, 1024, 8);

  fc1_fused<<<dim3(512), dim3(256), 0, stream>>>(bufX, x, fc1w, partial);
  fc_stage2<<<dim3(1024), dim3(64), 0, stream>>>(partial, fc1b, fc2w, fc2b, out);
  (void)in_sizes; (void)n_in; (void)out_size; (void)ws_size;
}

// Round 10
// 129.617 us; speedup vs baseline: 4.1786x; 1.0845x over previous
//
#include <hip/hip_runtime.h>

#define TT   128        // output positions per side per block
#define TIN2 (TT + 8)   // staged X: pos -4 .. TT+3
#define NHA  (TT + 6)   // hidA rows: pos -3 .. TT+2
#define NEO  (TT + 4)   // Es/Os rows: pos -2 .. TT+1
#define NHB  (TT + 2)   // hidB rows: pos -1 .. TT
#define HROW 44         // hidS row stride in halves (88 B: 11-bank odd stride, <=2-way)

typedef _Float16 h2 __attribute__((ext_vector_type(2)));
typedef __fp16 fp16v2 __attribute__((ext_vector_type(2)));
typedef _Float16 f16x4 __attribute__((ext_vector_type(4)));
typedef _Float16 f16x8 __attribute__((ext_vector_type(8)));
typedef float f32x4 __attribute__((ext_vector_type(4)));

// MFMA A-fragments of conv weights (device-global; rewritten every launch).
__device__ _Float16 g_w1A[12][2][64][8];  // conv1: [lvl*4+pair][Mtile][lane][j], k=kk*8+ic (kk=3 zero)
__device__ _Float16 g_w2A[12][3][64][8];  // conv2: [lvl*4+pair][tap][lane][j], oc rows 8..15 zero

__device__ __forceinline__ h2 pkh(float a, float b) {
  fp16v2 r = __builtin_amdgcn_cvt_pkrtz(a, b);
  return __builtin_bit_cast(h2, r);
}
__device__ __forceinline__ unsigned int pku(float a, float b) {
  return __builtin_bit_cast(unsigned int, pkh(a, b));
}
__device__ __forceinline__ float fast_tanh(float x) {
  return 1.f - __fdividef(2.f, __expf(2.f * x) + 1.f);
}
// packed leaky: max(x, 0.01x) elementwise on 2 halves (v_pk_mul + v_pk_max)
__device__ __forceinline__ unsigned int lky(unsigned int u) {
  h2 v = __builtin_bit_cast(h2, u);
  h2 s = v * (h2){(_Float16)0.01f, (_Float16)0.01f};
  h2 m = __builtin_elementwise_max(v, s);
  return __builtin_bit_cast(unsigned int, m);
}
// lanes 0-31 keep a_low; lanes 32-63 receive b_low from (lane-32)
__device__ __forceinline__ float lane_spread(float a_low, float b_low, int lane) {
  float s = __shfl_xor(b_low, 32);
  return (lane >= 32) ? s : a_low;
}
// two 8B LDS loads (88B row stride is only 8B-aligned)
__device__ __forceinline__ f16x8 ld_hid(const _Float16* p) {
  const f16x4 lo = *(const f16x4*)p;
  const f16x4 hi = *(const f16x4*)(p + 4);
  f16x8 r;
  r[0] = lo[0]; r[1] = lo[1]; r[2] = lo[2]; r[3] = lo[3];
  r[4] = hi[0]; r[5] = hi[1]; r[6] = hi[2]; r[7] = hi[3];
  return r;
}

__global__ __launch_bounds__(256) void pack_mfma(
    const float* __restrict__ w1, const float* __restrict__ w2)
{
  int id = blockIdx.x * 256 + threadIdx.x;
  if (id >= 12 * 5 * 64) return;
  const int lane = id & 63;
  const int rest = id >> 6;
  const int slot = rest % 5;
  const int pr   = rest / 5;           // lvl*4+pair
  if (slot < 2) {                      // conv1 A-fragment, M-tile = slot
    const int oc = slot * 16 + (lane & 15);
    const int bb = lane >> 4;          // tap index; bb=3 -> zero pad
#pragma unroll
    for (int j = 0; j < 8; ++j) {
      float v = (bb < 3) ? w1[((size_t)pr * 32 + oc) * 24 + j * 3 + bb] : 0.f;
      g_w1A[pr][slot][lane][j] = (_Float16)v;
    }
  } else {                             // conv2 A-fragment, tap t
    const int t = slot - 2;
    const int oc = lane & 15;
#pragma unroll
    for (int j = 0; j < 8; ++j) {
      const int hc = 8 * (lane >> 4) + j;
      float v = (oc < 8) ? w2[((size_t)pr * 8 + oc) * 96 + hc * 3 + t] : 0.f;
      g_w2A[pr][t][lane][j] = (_Float16)v;
    }
  }
}

// Fused level: X [nB][8][T] -> NEXT(f16) [(2i+side)*128+b][8][T2]
//   A: Es = F_even*exp(tanh(conv(F_odd,p1))), Os = F_odd*exp(tanh(conv(F_even,p3)))
//   B: seq 2i   = Os - tanh(conv(Os,p0));  seq 2i+1 = Es + tanh(conv(Es,p2))
template <bool IN16>
__global__ __launch_bounds__(256) void level_fused(
    const void* __restrict__ Xv, _Float16* __restrict__ NEXT,
    int lvl, int T2, int tilesPerSeq)
{
  __shared__ _Float16 inS[2][TIN2][8];    // [side][pos+4][ch] f16 conv input
  __shared__ _Float16 hidS[2][NHA][HROW]; // hid planes (reused A then B), 88B rows
  __shared__ _Float16 esS[2][NEO][8];     // Es/Os f16 (B conv input + base)

  const int blk = blockIdx.x;
  const int nb  = blk / tilesPerSeq;
  const int t0  = (blk - nb * tilesPerSeq) * TT;

  if constexpr (IN16) {
    const _Float16* Xh = (const _Float16*)Xv;
    const unsigned int* Xu = (const unsigned int*)(Xh + (size_t)nb * 8 * (2 * (size_t)T2));
    for (int jj = threadIdx.x; jj < TIN2; jj += 256) {
      int j = t0 - 4 + jj;
      j = j < 0 ? 0 : (j > T2 - 1 ? T2 - 1 : j);     // clamp in side-position space
      unsigned int u0[4], u1[4];
#pragma unroll
      for (int cp = 0; cp < 4; ++cp) {
        const h2 va = __builtin_bit_cast(h2, Xu[(size_t)(2 * cp) * T2 + j]);
        const h2 vb = __builtin_bit_cast(h2, Xu[(size_t)(2 * cp + 1) * T2 + j]);
        u0[cp] = __builtin_bit_cast(unsigned int, (h2){va[0], vb[0]});  // side0 = odd
        u1[cp] = __builtin_bit_cast(unsigned int, (h2){va[1], vb[1]});  // side1 = even
      }
      *(uint4*)&inS[0][jj][0] = make_uint4(u0[0], u0[1], u0[2], u0[3]);
      *(uint4*)&inS[1][jj][0] = make_uint4(u1[0], u1[1], u1[2], u1[3]);
    }
  } else {
    const float* X = (const float*)Xv;
    const float2* Xrow = (const float2*)(X + (size_t)nb * 8 * (2 * (size_t)T2));
    for (int jj = threadIdx.x; jj < TIN2; jj += 256) {
      int j = t0 - 4 + jj;
      j = j < 0 ? 0 : (j > T2 - 1 ? T2 - 1 : j);
      unsigned int u0[4], u1[4];
#pragma unroll
      for (int cp = 0; cp < 4; ++cp) {
        float2 a = Xrow[(size_t)(2 * cp) * T2 + j];
        float2 b = Xrow[(size_t)(2 * cp + 1) * T2 + j];
        u0[cp] = pku(a.x, b.x);
        u1[cp] = pku(a.y, b.y);
      }
      *(uint4*)&inS[0][jj][0] = make_uint4(u0[0], u0[1], u0[2], u0[3]);
      *(uint4*)&inS[1][jj][0] = make_uint4(u1[0], u1[1], u1[2], u1[3]);
    }
  }
  __syncthreads();

  const int wid  = __builtin_amdgcn_readfirstlane((int)(threadIdx.x >> 6));
  const int lane = threadIdx.x & 63;
  const int side = wid >> 1, half = wid & 1;
  const int g = lane >> 4, col = lane & 15;
  const int tb = half * 64;            // halves overlap rows 64..79 (benign identical writes)
  const int rp = ((lane >> 4) & 1) * 2 + (lane >> 5);   // row-pair after lane_spread

  const int pa = lvl * 4 + (side ? 3 : 1);
  const int pb = lvl * 4 + (side ? 2 : 0);
  const f16x8 a1w0 = *(const f16x8*)&g_w1A[pa][0][lane][0];
  const f16x8 a1w1 = *(const f16x8*)&g_w1A[pa][1][lane][0];
  const f16x8 a2w0 = *(const f16x8*)&g_w2A[pa][0][lane][0];
  const f16x8 a2w1 = *(const f16x8*)&g_w2A[pa][1][lane][0];
  const f16x8 a2w2 = *(const f16x8*)&g_w2A[pa][2][lane][0];
  const f16x8 b1w0 = *(const f16x8*)&g_w1A[pb][0][lane][0];
  const f16x8 b1w1 = *(const f16x8*)&g_w1A[pb][1][lane][0];
  const f16x8 b2w0 = *(const f16x8*)&g_w2A[pb][0][lane][0];
  const f16x8 b2w1 = *(const f16x8*)&g_w2A[pb][1][lane][0];
  const f16x8 b2w2 = *(const f16x8*)&g_w2A[pb][2][lane][0];
  const f32x4 zero = {0.f, 0.f, 0.f, 0.f};

  // ---- A1: hidA rows (pos -3..TT+2) ----
#pragma unroll
  for (int nt = 0; nt < 5; ++nt) {
    const int row = tb + nt * 16 + col;
    const int rr = (row + g > TIN2 - 1) ? (TIN2 - 1) : (row + g);
    const f16x8 bf = *(const f16x8*)&inS[side][rr][0];
    f32x4 d0 = __builtin_amdgcn_mfma_f32_16x16x32_f16(a1w0, bf, zero, 0, 0, 0);
    f32x4 d1 = __builtin_amdgcn_mfma_f32_16x16x32_f16(a1w1, bf, zero, 0, 0, 0);
    if (row < NHA) {
      *(uint2*)&hidS[side][row][4 * g] =
          make_uint2(lky(pku(d0[0], d0[1])), lky(pku(d0[2], d0[3])));
      *(uint2*)&hidS[side][row][16 + 4 * g] =
          make_uint2(lky(pku(d1[0], d1[1])), lky(pku(d1[2], d1[3])));
    }
  }
  __syncthreads();

  // ---- A2: Es/Os rows (pos -2..TT+1), epilogue spread over all 64 lanes ----
#pragma unroll
  for (int nt = 0; nt < 5; ++nt) {
    const int row = tb + nt * 16 + col;
    f32x4 acc = zero;
    {
      int rr = (row     > NHA - 1) ? (NHA - 1) : row;
      acc = __builtin_amdgcn_mfma_f32_16x16x32_f16(a2w0, ld_hid(&hidS[side][rr][8 * g]), acc, 0, 0, 0);
      rr = (row + 1 > NHA - 1) ? (NHA - 1) : (row + 1);
      acc = __builtin_amdgcn_mfma_f32_16x16x32_f16(a2w1, ld_hid(&hidS[side][rr][8 * g]), acc, 0, 0, 0);
      rr = (row + 2 > NHA - 1) ? (NHA - 1) : (row + 2);
      acc = __builtin_amdgcn_mfma_f32_16x16x32_f16(a2w2, ld_hid(&hidS[side][rr][8 * g]), acc, 0, 0, 0);
    }
    if (row < NEO) {
      const float va = lane_spread(acc[0], acc[2], lane);
      const float vb = lane_spread(acc[1], acc[3], lane);
      const h2 mpk = *(const h2*)&inS[side ^ 1][row + 2][2 * rp];  // multiplier (f16, staged)
      const float v0 = (float)mpk[0] * __expf(fast_tanh(va));
      const float v1 = (float)mpk[1] * __expf(fast_tanh(vb));
      *(unsigned int*)&esS[side][row][2 * rp] = pku(v0, v1);
    }
  }
  __syncthreads();

  // ---- B1: hidB rows (pos -1..TT), conv input = other side's Es/Os ----
  const int srcB = side ^ 1;
  const int eoLo = (t0 == 0) ? 2 : 0;                       // replicate-edge padding of Os/Es
  const int eoHi = (t0 + TT >= T2) ? (TT + 1) : (NEO - 1);
#pragma unroll
  for (int nt = 0; nt < 5; ++nt) {
    const int row = tb + nt * 16 + col;
    int rr = row + g;
    rr = rr < eoLo ? eoLo : (rr > eoHi ? eoHi : rr);
    const f16x8 bf = *(const f16x8*)&esS[srcB][rr][0];
    f32x4 d0 = __builtin_amdgcn_mfma_f32_16x16x32_f16(b1w0, bf, zero, 0, 0, 0);
    f32x4 d1 = __builtin_amdgcn_mfma_f32_16x16x32_f16(b1w1, bf, zero, 0, 0, 0);
    if (row < NHB) {
      *(uint2*)&hidS[side][row][4 * g] =
          make_uint2(lky(pku(d0[0], d0[1])), lky(pku(d0[2], d0[3])));
      *(uint2*)&hidS[side][row][16 + 4 * g] =
          make_uint2(lky(pku(d1[0], d1[1])), lky(pku(d1[2], d1[3])));
    }
  }
  __syncthreads();

  // ---- B2: outputs (f16), epilogue spread over all 64 lanes ----
  const float sgn = side ? 1.f : -1.f;
  const int i = nb >> 7;          // B = 128
  const int b = nb & 127;
  const int outseq = 2 * i + side;
#pragma unroll
  for (int nt = 0; nt < 4; ++nt) {
    const int row = half * 64 + nt * 16 + col;      // output pos, exact [0,128)
    f32x4 acc = zero;
    acc = __builtin_amdgcn_mfma_f32_16x16x32_f16(b2w0, ld_hid(&hidS[side][row][8 * g]), acc, 0, 0, 0);
    acc = __builtin_amdgcn_mfma_f32_16x16x32_f16(b2w1, ld_hid(&hidS[side][row + 1][8 * g]), acc, 0, 0, 0);
    acc = __builtin_amdgcn_mfma_f32_16x16x32_f16(b2w2, ld_hid(&hidS[side][row + 2][8 * g]), acc, 0, 0, 0);
    const float va = lane_spread(acc[0], acc[2], lane);
    const float vb = lane_spread(acc[1], acc[3], lane);
    const h2 base = *(const h2*)&esS[srcB][row + 2][2 * rp];
    const int tg = t0 + row;
    const int c0 = 2 * rp;
    NEXT[(((size_t)outseq * 128 + b) * 8 + c0) * T2 + tg]     = (_Float16)((float)base[0] + sgn * fast_tanh(va));
    NEXT[(((size_t)outseq * 128 + b) * 8 + c0 + 1) * T2 + tg] = (_Float16)((float)base[1] + sgn * fast_tanh(vb));
  }
}

// FC1 split-K (dot2, f16 operands): F[row][8t+r] = P[rev3(r)][b][c][t] + x[row][8t+r]
__global__ __launch_bounds__(256) void fc1_fused(
    const _Float16* __restrict__ P, const float* __restrict__ x,
    const float* __restrict__ W, float* __restrict__ partial)
{
  const int rt = blockIdx.x & 31;   // row tile: 32 rows
  const int ch = blockIdx.x >> 5;   // 16 chunks of 512 s
  const int s0 = ch * 512;
  __shared__ unsigned int Fl[32][68];   // h2 pairs: 64 h2 = 128 s per sub-block
  __shared__ unsigned int Wl[64][68];
  const int hg = threadIdx.x & 15;
  const int rg = threadIdx.x >> 4;  // 0..15
  float acc[2][4] = {{0.f, 0.f, 0.f, 0.f}, {0.f, 0.f, 0.f, 0.f}};

  for (int sb = 0; sb < 512; sb += 128) {
    __syncthreads();
    for (int i = threadIdx.x; i < 32 * 32; i += 256) {
      const int r = i >> 5, s4 = i & 31;
      const int row = rt * 32 + r;
      const int b = row >> 3, c = row & 7;
      const int base = s0 + sb + 4 * s4;
      const int t = base >> 3, r0 = base & 7;       // r0 in {0,4}
      const float4 xv = *(const float4*)(x + (size_t)row * 8192 + base);
      _Float16 p[4];
#pragma unroll
      for (int j = 0; j < 4; ++j) {
        const int rr = r0 + j;
        const int rev = ((rr & 1) << 2) | (rr & 2) | ((rr >> 2) & 1);   // bitrev3
        p[j] = P[(((size_t)rev * 128 + b) * 8 + c) * 1024 + t];
      }
      const h2 f01 = pkh(xv.x, xv.y) + (h2){p[0], p[1]};
      const h2 f23 = pkh(xv.z, xv.w) + (h2){p[2], p[3]};
      *(uint2*)&Fl[r][s4 * 2] = make_uint2(__builtin_bit_cast(unsigned int, f01),
                                           __builtin_bit_cast(unsigned int, f23));
    }
    for (int i = threadIdx.x; i < 64 * 32; i += 256) {
      const int hh = i >> 5, s4 = i & 31;
      float4 v = make_float4(0.f, 0.f, 0.f, 0.f);
      if (hh < 50) v = ((const float4*)(W + (size_t)hh * 8192 + s0 + sb))[s4];
      *(uint2*)&Wl[hh][s4 * 2] = make_uint2(pku(v.x, v.y), pku(v.z, v.w));
    }
    __syncthreads();
    for (int q = 0; q < 16; ++q) {
      const uint4 fa = *(const uint4*)&Fl[rg * 2][q * 4];
      const uint4 fb = *(const uint4*)&Fl[rg * 2 + 1][q * 4];
#pragma unroll
      for (int j = 0; j < 4; ++j) {
        const uint4 w = *(const uint4*)&Wl[hg + 16 * j][q * 4];
#pragma unroll
        for (int e = 0; e < 4; ++e) {
          const h2 we = __builtin_bit_cast(h2, (&w.x)[e]);
          acc[0][j] = __builtin_amdgcn_fdot2(we, __builtin_bit_cast(h2, (&fa.x)[e]), acc[0][j], false);
          acc[1][j] = __builtin_amdgcn_fdot2(we, __builtin_bit_cast(h2, (&fb.x)[e]), acc[1][j], false);
        }
      }
    }
  }
#pragma unroll
  for (int rr = 0; rr < 2; ++rr)
#pragma unroll
    for (int j = 0; j < 4; ++j)
      partial[((size_t)ch * 1024 + rt * 32 + rg * 2 + rr) * 64 + hg + 16 * j] = acc[rr][j];
}

// reduce partials + bias + relu, then FC2 -> out[row][24]
__global__ __launch_bounds__(64) void fc_stage2(
    const float* __restrict__ partial, const float* __restrict__ fc1b,
    const float* __restrict__ fc2w, const float* __restrict__ fc2b,
    float* __restrict__ out)
{
  const int row = blockIdx.x;
  const int h = threadIdx.x;      // 0..63
  __shared__ float hs[64];
  float v = 0.f;
  if (h < 50) {
    for (int ch = 0; ch < 16; ++ch)
      v += partial[((size_t)ch * 1024 + row) * 64 + h];
    v += fc1b[h];
    v = v > 0.f ? v : 0.f;
  }
  hs[h] = v;
  __syncthreads();
  if (h < 24) {
    float a = fc2b[h];
    for (int j = 0; j < 50; ++j)
      a = fmaf(hs[j], fc2w[h * 50 + j], a);
    out[(size_t)row * 24 + h] = a;
  }
}

extern "C" void kernel_launch(void* const* d_in, const int* in_sizes, int n_in,
                              void* d_out, int out_size, void* d_ws, size_t ws_size,
                              hipStream_t stream)
{
  const float* x    = (const float*)d_in[0];
  const float* w1a  = (const float*)d_in[1];  // (3,4,32,8,3)
  const float* w2a  = (const float*)d_in[2];  // (3,4,8,32,3)
  const float* fc1w = (const float*)d_in[3];  // (50,8192)
  const float* fc1b = (const float*)d_in[4];  // (50,)
  const float* fc2w = (const float*)d_in[5];  // (24,50)
  const float* fc2b = (const float*)d_in[6];  // (24,)
  float* out = (float*)d_out;

  _Float16* bufA = (_Float16*)d_ws;                       // 8.4M halves (16.8 MB)
  _Float16* bufB = bufA + (size_t)9 * 1024 * 1024;        // 8.4M halves
  float* partial = (float*)((char*)d_ws + (size_t)40 * 1024 * 1024);  // 4 MB

  pack_mfma<<<dim3(15), dim3(256), 0, stream>>>(w1a, w2a);

  // lvl0: x(f32) -> bufA(f16) ; lvl1: bufA -> bufB ; lvl2: bufB -> bufA
  level_fused<false><<<dim3(4096), dim3(256), 0, stream>>>(x,    bufA, 0, 4096, 32);
  level_fused<true ><<<dim3(4096), dim3(256), 0, stream>>>(bufA, bufB, 1, 2048, 16);
  level_fused<true ><<<dim3(4096), dim3(256), 0, stream>>>(bufB, bufA, 2, 1024, 8);

  fc1_fused<<<dim3(512), dim3(256), 0, stream>>>(bufA, x, fc1w, partial);
  fc_stage2<<<dim3(1024), dim3(64), 0, stream>>>(partial, fc1b, fc2w, fc2b, out);
  (void)in_sizes; (void)n_in; (void)out_size; (void)ws_size;
}

// Round 11
// 128.295 us; speedup vs baseline: 4.2216x; 1.0103x over previous
//
#include <hip/hip_runtime.h>

#define TT   128        // output positions per side per block
#define TIN2 (TT + 8)   // staged X: pos -4 .. TT+3
#define NHA  (TT + 6)   // hidA rows: pos -3 .. TT+2
#define NEO  (TT + 4)   // Es/Os rows: pos -2 .. TT+1
#define NHB  (TT + 2)   // hidB rows: pos -1 .. TT
#define HROW 44         // hidS row stride in halves (88 B: 11-bank odd stride, <=2-way)

typedef _Float16 h2 __attribute__((ext_vector_type(2)));
typedef __fp16 fp16v2 __attribute__((ext_vector_type(2)));
typedef _Float16 f16x4 __attribute__((ext_vector_type(4)));
typedef _Float16 f16x8 __attribute__((ext_vector_type(8)));
typedef float f32x4 __attribute__((ext_vector_type(4)));

// MFMA A-fragments of conv weights (device-global; rewritten every launch).
__device__ _Float16 g_w1A[12][2][64][8];  // conv1: [lvl*4+pair][Mtile][lane][j], k=kk*8+ic (kk=3 zero)
__device__ _Float16 g_w2A[12][3][64][8];  // conv2: [lvl*4+pair][tap][lane][j], oc rows 8..15 zero

__device__ __forceinline__ h2 pkh(float a, float b) {
  fp16v2 r = __builtin_amdgcn_cvt_pkrtz(a, b);
  return __builtin_bit_cast(h2, r);
}
__device__ __forceinline__ unsigned int pku(float a, float b) {
  return __builtin_bit_cast(unsigned int, pkh(a, b));
}
__device__ __forceinline__ float fast_tanh(float x) {
  return 1.f - __fdividef(2.f, __expf(2.f * x) + 1.f);
}
// packed leaky: max(x, 0.01x) elementwise on 2 halves (v_pk_mul + v_pk_max)
__device__ __forceinline__ unsigned int lky(unsigned int u) {
  h2 v = __builtin_bit_cast(h2, u);
  h2 s = v * (h2){(_Float16)0.01f, (_Float16)0.01f};
  h2 m = __builtin_elementwise_max(v, s);
  return __builtin_bit_cast(unsigned int, m);
}
// lanes 0-31 keep a_low; lanes 32-63 receive b_low from (lane-32)
__device__ __forceinline__ float lane_spread(float a_low, float b_low, int lane) {
  float s = __shfl_xor(b_low, 32);
  return (lane >= 32) ? s : a_low;
}
// two 8B LDS loads (88B row stride is only 8B-aligned)
__device__ __forceinline__ f16x8 ld_hid(const _Float16* p) {
  const f16x4 lo = *(const f16x4*)p;
  const f16x4 hi = *(const f16x4*)(p + 4);
  f16x8 r;
  r[0] = lo[0]; r[1] = lo[1]; r[2] = lo[2]; r[3] = lo[3];
  r[4] = hi[0]; r[5] = hi[1]; r[6] = hi[2]; r[7] = hi[3];
  return r;
}

__global__ __launch_bounds__(256) void pack_mfma(
    const float* __restrict__ w1, const float* __restrict__ w2)
{
  int id = blockIdx.x * 256 + threadIdx.x;
  if (id >= 12 * 5 * 64) return;
  const int lane = id & 63;
  const int rest = id >> 6;
  const int slot = rest % 5;
  const int pr   = rest / 5;           // lvl*4+pair
  if (slot < 2) {                      // conv1 A-fragment, M-tile = slot
    const int oc = slot * 16 + (lane & 15);
    const int bb = lane >> 4;          // tap index; bb=3 -> zero pad
#pragma unroll
    for (int j = 0; j < 8; ++j) {
      float v = (bb < 3) ? w1[((size_t)pr * 32 + oc) * 24 + j * 3 + bb] : 0.f;
      g_w1A[pr][slot][lane][j] = (_Float16)v;
    }
  } else {                             // conv2 A-fragment, tap t
    const int t = slot - 2;
    const int oc = lane & 15;
#pragma unroll
    for (int j = 0; j < 8; ++j) {
      const int hc = 8 * (lane >> 4) + j;
      float v = (oc < 8) ? w2[((size_t)pr * 8 + oc) * 96 + hc * 3 + t] : 0.f;
      g_w2A[pr][t][lane][j] = (_Float16)v;
    }
  }
}

// Fused level. Input: lvl0 = f32 channel-major [nB][8][T]; lvl1/2 = f16 pos-major
// [nB][T][8]. Output (all levels): f16 pos-major NEXT[(2i+side)*128+b][T2][8].
//   A: Es = F_even*exp(tanh(conv(F_odd,p1))), Os = F_odd*exp(tanh(conv(F_even,p3)))
//   B: seq 2i   = Os - tanh(conv(Os,p0));  seq 2i+1 = Es + tanh(conv(Es,p2))
template <bool IN16>
__global__ __launch_bounds__(256) void level_fused(
    const void* __restrict__ Xv, _Float16* __restrict__ NEXT,
    int lvl, int T2, int tilesPerSeq)
{
  __shared__ _Float16 inS[2][TIN2][8];    // [side][pos+4][ch] f16 conv input
  __shared__ _Float16 hidS[2][NHA][HROW]; // hid planes (reused A then B), 88B rows
  __shared__ _Float16 esS[2][NEO][8];     // Es/Os f16 (B conv input + base)

  const int blk = blockIdx.x;
  const int nb  = blk / tilesPerSeq;
  const int t0  = (blk - nb * tilesPerSeq) * TT;

  if constexpr (IN16) {
    // pos-major f16: row (2p+s) of 8 f16 = 16B -> one uint4 per (side,pos)
    const _Float16* Xh = (const _Float16*)Xv + (size_t)nb * (2 * (size_t)T2) * 8;
    for (int it = threadIdx.x; it < 2 * TIN2; it += 256) {
      const int s = it & 1, jj = it >> 1;
      int p = t0 - 4 + jj;
      p = p < 0 ? 0 : (p > T2 - 1 ? T2 - 1 : p);     // clamp in side-position space
      *(uint4*)&inS[s][jj][0] = *(const uint4*)&Xh[(size_t)(2 * p + s) * 8];
    }
  } else {
    const float* X = (const float*)Xv;
    const float2* Xrow = (const float2*)(X + (size_t)nb * 8 * (2 * (size_t)T2));
    for (int jj = threadIdx.x; jj < TIN2; jj += 256) {
      int j = t0 - 4 + jj;
      j = j < 0 ? 0 : (j > T2 - 1 ? T2 - 1 : j);
      unsigned int u0[4], u1[4];
#pragma unroll
      for (int cp = 0; cp < 4; ++cp) {
        float2 a = Xrow[(size_t)(2 * cp) * T2 + j];
        float2 b = Xrow[(size_t)(2 * cp + 1) * T2 + j];
        u0[cp] = pku(a.x, b.x);                      // side0 = odd
        u1[cp] = pku(a.y, b.y);                      // side1 = even
      }
      *(uint4*)&inS[0][jj][0] = make_uint4(u0[0], u0[1], u0[2], u0[3]);
      *(uint4*)&inS[1][jj][0] = make_uint4(u1[0], u1[1], u1[2], u1[3]);
    }
  }
  __syncthreads();

  const int wid  = __builtin_amdgcn_readfirstlane((int)(threadIdx.x >> 6));
  const int lane = threadIdx.x & 63;
  const int side = wid >> 1, half = wid & 1;
  const int g = lane >> 4, col = lane & 15;
  const int tb = half * 64;            // halves overlap rows 64..79 (benign identical writes)
  const int rp = ((lane >> 4) & 1) * 2 + (lane >> 5);   // row-pair after lane_spread

  const int pa = lvl * 4 + (side ? 3 : 1);
  const int pb = lvl * 4 + (side ? 2 : 0);
  const f16x8 a1w0 = *(const f16x8*)&g_w1A[pa][0][lane][0];
  const f16x8 a1w1 = *(const f16x8*)&g_w1A[pa][1][lane][0];
  const f16x8 a2w0 = *(const f16x8*)&g_w2A[pa][0][lane][0];
  const f16x8 a2w1 = *(const f16x8*)&g_w2A[pa][1][lane][0];
  const f16x8 a2w2 = *(const f16x8*)&g_w2A[pa][2][lane][0];
  const f16x8 b1w0 = *(const f16x8*)&g_w1A[pb][0][lane][0];
  const f16x8 b1w1 = *(const f16x8*)&g_w1A[pb][1][lane][0];
  const f16x8 b2w0 = *(const f16x8*)&g_w2A[pb][0][lane][0];
  const f16x8 b2w1 = *(const f16x8*)&g_w2A[pb][1][lane][0];
  const f16x8 b2w2 = *(const f16x8*)&g_w2A[pb][2][lane][0];
  const f32x4 zero = {0.f, 0.f, 0.f, 0.f};

  // ---- A1: hidA rows (pos -3..TT+2) ----
#pragma unroll
  for (int nt = 0; nt < 5; ++nt) {
    const int row = tb + nt * 16 + col;
    const int rr = (row + g > TIN2 - 1) ? (TIN2 - 1) : (row + g);
    const f16x8 bf = *(const f16x8*)&inS[side][rr][0];
    f32x4 d0 = __builtin_amdgcn_mfma_f32_16x16x32_f16(a1w0, bf, zero, 0, 0, 0);
    f32x4 d1 = __builtin_amdgcn_mfma_f32_16x16x32_f16(a1w1, bf, zero, 0, 0, 0);
    if (row < NHA) {
      *(uint2*)&hidS[side][row][4 * g] =
          make_uint2(lky(pku(d0[0], d0[1])), lky(pku(d0[2], d0[3])));
      *(uint2*)&hidS[side][row][16 + 4 * g] =
          make_uint2(lky(pku(d1[0], d1[1])), lky(pku(d1[2], d1[3])));
    }
  }
  __syncthreads();

  // ---- A2: Es/Os rows (pos -2..TT+1), epilogue spread over all 64 lanes ----
#pragma unroll
  for (int nt = 0; nt < 5; ++nt) {
    const int row = tb + nt * 16 + col;
    f32x4 acc = zero;
    {
      int rr = (row     > NHA - 1) ? (NHA - 1) : row;
      acc = __builtin_amdgcn_mfma_f32_16x16x32_f16(a2w0, ld_hid(&hidS[side][rr][8 * g]), acc, 0, 0, 0);
      rr = (row + 1 > NHA - 1) ? (NHA - 1) : (row + 1);
      acc = __builtin_amdgcn_mfma_f32_16x16x32_f16(a2w1, ld_hid(&hidS[side][rr][8 * g]), acc, 0, 0, 0);
      rr = (row + 2 > NHA - 1) ? (NHA - 1) : (row + 2);
      acc = __builtin_amdgcn_mfma_f32_16x16x32_f16(a2w2, ld_hid(&hidS[side][rr][8 * g]), acc, 0, 0, 0);
    }
    if (row < NEO) {
      const float va = lane_spread(acc[0], acc[2], lane);
      const float vb = lane_spread(acc[1], acc[3], lane);
      const h2 mpk = *(const h2*)&inS[side ^ 1][row + 2][2 * rp];  // multiplier (f16, staged)
      const float v0 = (float)mpk[0] * __expf(fast_tanh(va));
      const float v1 = (float)mpk[1] * __expf(fast_tanh(vb));
      *(unsigned int*)&esS[side][row][2 * rp] = pku(v0, v1);
    }
  }
  __syncthreads();

  // ---- B1: hidB rows (pos -1..TT), conv input = other side's Es/Os ----
  const int srcB = side ^ 1;
  const int eoLo = (t0 == 0) ? 2 : 0;                       // replicate-edge padding of Os/Es
  const int eoHi = (t0 + TT >= T2) ? (TT + 1) : (NEO - 1);
#pragma unroll
  for (int nt = 0; nt < 5; ++nt) {
    const int row = tb + nt * 16 + col;
    int rr = row + g;
    rr = rr < eoLo ? eoLo : (rr > eoHi ? eoHi : rr);
    const f16x8 bf = *(const f16x8*)&esS[srcB][rr][0];
    f32x4 d0 = __builtin_amdgcn_mfma_f32_16x16x32_f16(b1w0, bf, zero, 0, 0, 0);
    f32x4 d1 = __builtin_amdgcn_mfma_f32_16x16x32_f16(b1w1, bf, zero, 0, 0, 0);
    if (row < NHB) {
      *(uint2*)&hidS[side][row][4 * g] =
          make_uint2(lky(pku(d0[0], d0[1])), lky(pku(d0[2], d0[3])));
      *(uint2*)&hidS[side][row][16 + 4 * g] =
          make_uint2(lky(pku(d1[0], d1[1])), lky(pku(d1[2], d1[3])));
    }
  }
  __syncthreads();

  // ---- B2: outputs (f16 pos-major), one coalesced 4B store per lane-iter ----
  const float sgn = side ? 1.f : -1.f;
  const int i = nb >> 7;          // B = 128
  const int b = nb & 127;
  const int outseq = 2 * i + side;
  _Float16* outbase = NEXT + ((size_t)outseq * 128 + b) * (size_t)T2 * 8;
#pragma unroll
  for (int nt = 0; nt < 4; ++nt) {
    const int row = half * 64 + nt * 16 + col;      // output pos, exact [0,128)
    f32x4 acc = zero;
    acc = __builtin_amdgcn_mfma_f32_16x16x32_f16(b2w0, ld_hid(&hidS[side][row][8 * g]), acc, 0, 0, 0);
    acc = __builtin_amdgcn_mfma_f32_16x16x32_f16(b2w1, ld_hid(&hidS[side][row + 1][8 * g]), acc, 0, 0, 0);
    acc = __builtin_amdgcn_mfma_f32_16x16x32_f16(b2w2, ld_hid(&hidS[side][row + 2][8 * g]), acc, 0, 0, 0);
    const float va = lane_spread(acc[0], acc[2], lane);
    const float vb = lane_spread(acc[1], acc[3], lane);
    const h2 base = *(const h2*)&esS[srcB][row + 2][2 * rp];
    const int tg = t0 + row;
    *(unsigned int*)&outbase[(size_t)tg * 8 + 2 * rp] =
        pku((float)base[0] + sgn * fast_tanh(va), (float)base[1] + sgn * fast_tanh(vb));
  }
}

// FC1 split-K (dot2, f16 operands): F[row][8t+r] = P[rev3(r)][b][t][c] + x[row][8t+r]
// P is f16 pos-major: [seq8*128+b][t(1024)][c(8)]
__global__ __launch_bounds__(256) void fc1_fused(
    const _Float16* __restrict__ P, const float* __restrict__ x,
    const float* __restrict__ W, float* __restrict__ partial)
{
  const int rt = blockIdx.x & 31;   // row tile: 32 rows
  const int ch = blockIdx.x >> 5;   // 16 chunks of 512 s
  const int s0 = ch * 512;
  __shared__ unsigned int Fl[32][68];   // h2 pairs: 64 h2 = 128 s per sub-block
  __shared__ unsigned int Wl[64][68];
  const int hg = threadIdx.x & 15;
  const int rg = threadIdx.x >> 4;  // 0..15
  float acc[2][4] = {{0.f, 0.f, 0.f, 0.f}, {0.f, 0.f, 0.f, 0.f}};

  for (int sb = 0; sb < 512; sb += 128) {
    __syncthreads();
    for (int i = threadIdx.x; i < 32 * 32; i += 256) {
      const int r = i >> 5, s4 = i & 31;
      const int row = rt * 32 + r;
      const int b = row >> 3, c = row & 7;
      const int base = s0 + sb + 4 * s4;
      const int t = base >> 3, r0 = base & 7;       // r0 in {0,4}
      const float4 xv = *(const float4*)(x + (size_t)row * 8192 + base);
      _Float16 p[4];
#pragma unroll
      for (int j = 0; j < 4; ++j) {
        const int rr = r0 + j;
        const int rev = ((rr & 1) << 2) | (rr & 2) | ((rr >> 2) & 1);   // bitrev3
        p[j] = P[(((size_t)rev * 128 + b) * 1024 + t) * 8 + c];
      }
      const h2 f01 = pkh(xv.x, xv.y) + (h2){p[0], p[1]};
      const h2 f23 = pkh(xv.z, xv.w) + (h2){p[2], p[3]};
      *(uint2*)&Fl[r][s4 * 2] = make_uint2(__builtin_bit_cast(unsigned int, f01),
                                           __builtin_bit_cast(unsigned int, f23));
    }
    for (int i = threadIdx.x; i < 64 * 32; i += 256) {
      const int hh = i >> 5, s4 = i & 31;
      float4 v = make_float4(0.f, 0.f, 0.f, 0.f);
      if (hh < 50) v = ((const float4*)(W + (size_t)hh * 8192 + s0 + sb))[s4];
      *(uint2*)&Wl[hh][s4 * 2] = make_uint2(pku(v.x, v.y), pku(v.z, v.w));
    }
    __syncthreads();
    for (int q = 0; q < 16; ++q) {
      const uint4 fa = *(const uint4*)&Fl[rg * 2][q * 4];
      const uint4 fb = *(const uint4*)&Fl[rg * 2 + 1][q * 4];
#pragma unroll
      for (int j = 0; j < 4; ++j) {
        const uint4 w = *(const uint4*)&Wl[hg + 16 * j][q * 4];
#pragma unroll
        for (int e = 0; e < 4; ++e) {
          const h2 we = __builtin_bit_cast(h2, (&w.x)[e]);
          acc[0][j] = __builtin_amdgcn_fdot2(we, __builtin_bit_cast(h2, (&fa.x)[e]), acc[0][j], false);
          acc[1][j] = __builtin_amdgcn_fdot2(we, __builtin_bit_cast(h2, (&fb.x)[e]), acc[1][j], false);
        }
      }
    }
  }
#pragma unroll
  for (int rr = 0; rr < 2; ++rr)
#pragma unroll
    for (int j = 0; j < 4; ++j)
      partial[((size_t)ch * 1024 + rt * 32 + rg * 2 + rr) * 64 + hg + 16 * j] = acc[rr][j];
}

// reduce partials + bias + relu, then FC2 -> out[row][24]; 4 rows per block
__global__ __launch_bounds__(256) void fc_stage2(
    const float* __restrict__ partial, const float* __restrict__ fc1b,
    const float* __restrict__ fc2w, const float* __restrict__ fc2b,
    float* __restrict__ out)
{
  const int rr = threadIdx.x >> 6;            // row within block: 0..3
  const int row = blockIdx.x * 4 + rr;
  const int h = threadIdx.x & 63;             // 0..63
  __shared__ float hs[4][64];
  float v = 0.f;
  if (h < 50) {
    for (int ch = 0; ch < 16; ++ch)
      v += partial[((size_t)ch * 1024 + row) * 64 + h];
    v += fc1b[h];
    v = v > 0.f ? v : 0.f;
  }
  hs[rr][h] = v;
  __syncthreads();
  if (h < 24) {
    float a = fc2b[h];
    for (int j = 0; j < 50; ++j)
      a = fmaf(hs[rr][j], fc2w[h * 50 + j], a);
    out[(size_t)row * 24 + h] = a;
  }
}

extern "C" void kernel_launch(void* const* d_in, const int* in_sizes, int n_in,
                              void* d_out, int out_size, void* d_ws, size_t ws_size,
                              hipStream_t stream)
{
  const float* x    = (const float*)d_in[0];
  const float* w1a  = (const float*)d_in[1];  // (3,4,32,8,3)
  const float* w2a  = (const float*)d_in[2];  // (3,4,8,32,3)
  const float* fc1w = (const float*)d_in[3];  // (50,8192)
  const float* fc1b = (const float*)d_in[4];  // (50,)
  const float* fc2w = (const float*)d_in[5];  // (24,50)
  const float* fc2b = (const float*)d_in[6];  // (24,)
  float* out = (float*)d_out;

  _Float16* bufA = (_Float16*)d_ws;                       // 8.4M halves (16.8 MB)
  _Float16* bufB = bufA + (size_t)9 * 1024 * 1024;        // 8.4M halves
  float* partial = (float*)((char*)d_ws + (size_t)40 * 1024 * 1024);  // 4 MB

  pack_mfma<<<dim3(15), dim3(256), 0, stream>>>(w1a, w2a);

  // lvl0: x(f32 ch-major) -> bufA(f16 pos-major) ; lvl1: bufA -> bufB ; lvl2: bufB -> bufA
  level_fused<false><<<dim3(4096), dim3(256), 0, stream>>>(x,    bufA, 0, 4096, 32);
  level_fused<true ><<<dim3(4096), dim3(256), 0, stream>>>(bufA, bufB, 1, 2048, 16);
  level_fused<true ><<<dim3(4096), dim3(256), 0, stream>>>(bufB, bufA, 2, 1024, 8);

  fc1_fused<<<dim3(512), dim3(256), 0, stream>>>(bufA, x, fc1w, partial);
  fc_stage2<<<dim3(256), dim3(256), 0, stream>>>(partial, fc1b, fc2w, fc2b, out);
  (void)in_sizes; (void)n_in; (void)out_size; (void)ws_size;
}

// Round 12
// 123.767 us; speedup vs baseline: 4.3761x; 1.0366x over previous
//
#include <hip/hip_runtime.h>

#define TT   128        // output positions per side per block
#define TIN2 (TT + 8)   // staged X: pos -4 .. TT+3
#define NHA  (TT + 6)   // hidA rows: pos -3 .. TT+2
#define NEO  (TT + 4)   // Es/Os rows: pos -2 .. TT+1
#define NHB  (TT + 2)   // hidB rows: pos -1 .. TT
#define HROW 40         // hid row stride in halves (80 B = 5*16: b128-aligned, 20-bank stride -> 2-way, free)

typedef _Float16 h2 __attribute__((ext_vector_type(2)));
typedef __fp16 fp16v2 __attribute__((ext_vector_type(2)));
typedef _Float16 f16x8 __attribute__((ext_vector_type(8)));
typedef float f32x4 __attribute__((ext_vector_type(4)));

// MFMA A-fragments of conv weights (device-global; rewritten every launch).
__device__ _Float16 g_w1A[12][2][64][8];  // conv1: [lvl*4+pair][Mtile][lane][j], k=kk*8+ic (kk=3 zero)
__device__ _Float16 g_w2A[12][3][64][8];  // conv2: [lvl*4+pair][tap][lane][j], hc PERMUTED (see pack), oc rows 8..15 zero

__device__ __forceinline__ h2 pkh(float a, float b) {
  fp16v2 r = __builtin_amdgcn_cvt_pkrtz(a, b);
  return __builtin_bit_cast(h2, r);
}
__device__ __forceinline__ unsigned int pku(float a, float b) {
  return __builtin_bit_cast(unsigned int, pkh(a, b));
}
__device__ __forceinline__ float fast_tanh(float x) {
  return 1.f - __fdividef(2.f, __expf(2.f * x) + 1.f);
}
// packed leaky: max(x, 0.01x) elementwise on 2 halves (v_pk_mul + v_pk_max)
__device__ __forceinline__ unsigned int lky(unsigned int u) {
  h2 v = __builtin_bit_cast(h2, u);
  h2 s = v * (h2){(_Float16)0.01f, (_Float16)0.01f};
  h2 m = __builtin_elementwise_max(v, s);
  return __builtin_bit_cast(unsigned int, m);
}
// lanes 0-31 keep a_low; lanes 32-63 receive b_low from (lane-32)
__device__ __forceinline__ float lane_spread(float a_low, float b_low, int lane) {
  float s = __shfl_xor(b_low, 32);
  return (lane >= 32) ? s : a_low;
}

__global__ __launch_bounds__(256) void pack_mfma(
    const float* __restrict__ w1, const float* __restrict__ w2)
{
  int id = blockIdx.x * 256 + threadIdx.x;
  if (id >= 12 * 5 * 64) return;
  const int lane = id & 63;
  const int rest = id >> 6;
  const int slot = rest % 5;
  const int pr   = rest / 5;           // lvl*4+pair
  if (slot < 2) {                      // conv1 A-fragment, M-tile = slot
    const int oc = slot * 16 + (lane & 15);
    const int bb = lane >> 4;          // tap index; bb=3 -> zero pad
#pragma unroll
    for (int j = 0; j < 8; ++j) {
      float v = (bb < 3) ? w1[((size_t)pr * 32 + oc) * 24 + j * 3 + bb] : 0.f;
      g_w1A[pr][slot][lane][j] = (_Float16)v;
    }
  } else {                             // conv2 A-fragment, tap t; hc permuted to match
    const int t = slot - 2;            // hid LDS layout: offset 8*kk+j -> hc below
    const int oc = lane & 15;
    const int kk = lane >> 4;
#pragma unroll
    for (int j = 0; j < 8; ++j) {
      const int hc = (j < 4) ? (4 * kk + j) : (16 + 4 * kk + (j - 4));
      float v = (oc < 8) ? w2[((size_t)pr * 8 + oc) * 96 + hc * 3 + t] : 0.f;
      g_w2A[pr][t][lane][j] = (_Float16)v;
    }
  }
}

// Fused level. Input: lvl0 = f32 channel-major [nB][8][T]; lvl1/2 = f16 pos-major
// [nB][T][8]. Output (all levels): f16 pos-major NEXT[(2i+side)*128+b][T2][8].
//   A: Es = F_even*exp(tanh(conv(F_odd,p1))), Os = F_odd*exp(tanh(conv(F_even,p3)))
//   B: seq 2i   = Os - tanh(conv(Os,p0));  seq 2i+1 = Es + tanh(conv(Es,p2))
template <bool IN16>
__global__ __launch_bounds__(256) void level_fused(
    const void* __restrict__ Xv, _Float16* __restrict__ NEXT,
    int lvl, int T2, int tilesPerSeq)
{
  __shared__ __align__(16) _Float16 inS[2][TIN2][8];    // [side][pos+4][ch]
  __shared__ __align__(16) _Float16 hidS[2][NHA][HROW]; // hid planes (A then B), 80B rows
  __shared__ __align__(16) _Float16 esS[2][NEO][8];     // Es/Os f16 (B conv input + base)

  const int blk = blockIdx.x;
  const int nb  = blk / tilesPerSeq;
  const int t0  = (blk - nb * tilesPerSeq) * TT;

  if constexpr (IN16) {
    // pos-major f16: row (2p+s) of 8 f16 = 16B -> one uint4 per (side,pos)
    const _Float16* Xh = (const _Float16*)Xv + (size_t)nb * (2 * (size_t)T2) * 8;
    for (int it = threadIdx.x; it < 2 * TIN2; it += 256) {
      const int s = it & 1, jj = it >> 1;
      int p = t0 - 4 + jj;
      p = p < 0 ? 0 : (p > T2 - 1 ? T2 - 1 : p);     // clamp in side-position space
      *(uint4*)&inS[s][jj][0] = *(const uint4*)&Xh[(size_t)(2 * p + s) * 8];
    }
  } else {
    const float* X = (const float*)Xv;
    const float2* Xrow = (const float2*)(X + (size_t)nb * 8 * (2 * (size_t)T2));
    for (int jj = threadIdx.x; jj < TIN2; jj += 256) {
      int j = t0 - 4 + jj;
      j = j < 0 ? 0 : (j > T2 - 1 ? T2 - 1 : j);
      unsigned int u0[4], u1[4];
#pragma unroll
      for (int cp = 0; cp < 4; ++cp) {
        float2 a = Xrow[(size_t)(2 * cp) * T2 + j];
        float2 b = Xrow[(size_t)(2 * cp + 1) * T2 + j];
        u0[cp] = pku(a.x, b.x);                      // side0 = odd
        u1[cp] = pku(a.y, b.y);                      // side1 = even
      }
      *(uint4*)&inS[0][jj][0] = make_uint4(u0[0], u0[1], u0[2], u0[3]);
      *(uint4*)&inS[1][jj][0] = make_uint4(u1[0], u1[1], u1[2], u1[3]);
    }
  }
  __syncthreads();

  const int wid  = __builtin_amdgcn_readfirstlane((int)(threadIdx.x >> 6));
  const int lane = threadIdx.x & 63;
  const int side = wid >> 1, half = wid & 1;
  const int g = lane >> 4, col = lane & 15;
  const int tb = half * 64;            // halves overlap rows 64..79 (benign identical writes)
  const int rp = ((lane >> 4) & 1) * 2 + (lane >> 5);   // row-pair after lane_spread

  const int pa = lvl * 4 + (side ? 3 : 1);
  const int pb = lvl * 4 + (side ? 2 : 0);
  const f16x8 a1w0 = *(const f16x8*)&g_w1A[pa][0][lane][0];
  const f16x8 a1w1 = *(const f16x8*)&g_w1A[pa][1][lane][0];
  const f16x8 a2w0 = *(const f16x8*)&g_w2A[pa][0][lane][0];
  const f16x8 a2w1 = *(const f16x8*)&g_w2A[pa][1][lane][0];
  const f16x8 a2w2 = *(const f16x8*)&g_w2A[pa][2][lane][0];
  const f16x8 b1w0 = *(const f16x8*)&g_w1A[pb][0][lane][0];
  const f16x8 b1w1 = *(const f16x8*)&g_w1A[pb][1][lane][0];
  const f16x8 b2w0 = *(const f16x8*)&g_w2A[pb][0][lane][0];
  const f16x8 b2w1 = *(const f16x8*)&g_w2A[pb][1][lane][0];
  const f16x8 b2w2 = *(const f16x8*)&g_w2A[pb][2][lane][0];
  const f32x4 zero = {0.f, 0.f, 0.f, 0.f};

  // ---- A1: hidA rows (pos -3..TT+2); one b128 write/lane/tile (permuted oc) ----
#pragma unroll
  for (int nt = 0; nt < 5; ++nt) {
    const int row = tb + nt * 16 + col;
    const int rr = (row + g > TIN2 - 1) ? (TIN2 - 1) : (row + g);
    const f16x8 bf = *(const f16x8*)&inS[side][rr][0];
    f32x4 d0 = __builtin_amdgcn_mfma_f32_16x16x32_f16(a1w0, bf, zero, 0, 0, 0);
    f32x4 d1 = __builtin_amdgcn_mfma_f32_16x16x32_f16(a1w1, bf, zero, 0, 0, 0);
    if (row < NHA) {
      *(uint4*)&hidS[side][row][8 * g] = make_uint4(
          lky(pku(d0[0], d0[1])), lky(pku(d0[2], d0[3])),
          lky(pku(d1[0], d1[1])), lky(pku(d1[2], d1[3])));
    }
  }
  __syncthreads();

  // ---- A2: Es/Os rows (pos -2..TT+1), epilogue spread over all 64 lanes ----
#pragma unroll
  for (int nt = 0; nt < 5; ++nt) {
    const int row = tb + nt * 16 + col;
    f32x4 acc = zero;
    {
      int rr = (row     > NHA - 1) ? (NHA - 1) : row;
      acc = __builtin_amdgcn_mfma_f32_16x16x32_f16(a2w0, *(const f16x8*)&hidS[side][rr][8 * g], acc, 0, 0, 0);
      rr = (row + 1 > NHA - 1) ? (NHA - 1) : (row + 1);
      acc = __builtin_amdgcn_mfma_f32_16x16x32_f16(a2w1, *(const f16x8*)&hidS[side][rr][8 * g], acc, 0, 0, 0);
      rr = (row + 2 > NHA - 1) ? (NHA - 1) : (row + 2);
      acc = __builtin_amdgcn_mfma_f32_16x16x32_f16(a2w2, *(const f16x8*)&hidS[side][rr][8 * g], acc, 0, 0, 0);
    }
    if (row < NEO) {
      const float va = lane_spread(acc[0], acc[2], lane);
      const float vb = lane_spread(acc[1], acc[3], lane);
      const h2 mpk = *(const h2*)&inS[side ^ 1][row + 2][2 * rp];  // multiplier (f16, staged)
      const float v0 = (float)mpk[0] * __expf(fast_tanh(va));
      const float v1 = (float)mpk[1] * __expf(fast_tanh(vb));
      *(unsigned int*)&esS[side][row][2 * rp] = pku(v0, v1);
    }
  }
  __syncthreads();

  // ---- B1: hidB rows (pos -1..TT), conv input = other side's Es/Os ----
  const int srcB = side ^ 1;
  const int eoLo = (t0 == 0) ? 2 : 0;                       // replicate-edge padding of Os/Es
  const int eoHi = (t0 + TT >= T2) ? (TT + 1) : (NEO - 1);
#pragma unroll
  for (int nt = 0; nt < 5; ++nt) {
    const int row = tb + nt * 16 + col;
    int rr = row + g;
    rr = rr < eoLo ? eoLo : (rr > eoHi ? eoHi : rr);
    const f16x8 bf = *(const f16x8*)&esS[srcB][rr][0];
    f32x4 d0 = __builtin_amdgcn_mfma_f32_16x16x32_f16(b1w0, bf, zero, 0, 0, 0);
    f32x4 d1 = __builtin_amdgcn_mfma_f32_16x16x32_f16(b1w1, bf, zero, 0, 0, 0);
    if (row < NHB) {
      *(uint4*)&hidS[side][row][8 * g] = make_uint4(
          lky(pku(d0[0], d0[1])), lky(pku(d0[2], d0[3])),
          lky(pku(d1[0], d1[1])), lky(pku(d1[2], d1[3])));
    }
  }
  __syncthreads();

  // ---- B2: outputs (f16 pos-major), one coalesced 4B store per lane-iter ----
  const float sgn = side ? 1.f : -1.f;
  const int i = nb >> 7;          // B = 128
  const int b = nb & 127;
  const int outseq = 2 * i + side;
  _Float16* outbase = NEXT + ((size_t)outseq * 128 + b) * (size_t)T2 * 8;
#pragma unroll
  for (int nt = 0; nt < 4; ++nt) {
    const int row = half * 64 + nt * 16 + col;      // output pos, exact [0,128)
    f32x4 acc = zero;
    acc = __builtin_amdgcn_mfma_f32_16x16x32_f16(b2w0, *(const f16x8*)&hidS[side][row][8 * g], acc, 0, 0, 0);
    acc = __builtin_amdgcn_mfma_f32_16x16x32_f16(b2w1, *(const f16x8*)&hidS[side][row + 1][8 * g], acc, 0, 0, 0);
    acc = __builtin_amdgcn_mfma_f32_16x16x32_f16(b2w2, *(const f16x8*)&hidS[side][row + 2][8 * g], acc, 0, 0, 0);
    const float va = lane_spread(acc[0], acc[2], lane);
    const float vb = lane_spread(acc[1], acc[3], lane);
    const h2 base = *(const h2*)&esS[srcB][row + 2][2 * rp];
    const int tg = t0 + row;
    *(unsigned int*)&outbase[(size_t)tg * 8 + 2 * rp] =
        pku((float)base[0] + sgn * fast_tanh(va), (float)base[1] + sgn * fast_tanh(vb));
  }
}

// FC1 split-K (dot2, f16 operands): F[row][8t+r] = P[rev3(r)][b][t][c] + x[row][8t+r]
// P is f16 pos-major: [seq8*128+b][t(1024)][c(8)]
__global__ __launch_bounds__(256) void fc1_fused(
    const _Float16* __restrict__ P, const float* __restrict__ x,
    const float* __restrict__ W, float* __restrict__ partial)
{
  const int rt = blockIdx.x & 31;   // row tile: 32 rows
  const int ch = blockIdx.x >> 5;   // 16 chunks of 512 s
  const int s0 = ch * 512;
  __shared__ unsigned int Fl[32][68];   // h2 pairs: 64 h2 = 128 s per sub-block
  __shared__ unsigned int Wl[64][68];
  const int hg = threadIdx.x & 15;
  const int rg = threadIdx.x >> 4;  // 0..15
  float acc[2][4] = {{0.f, 0.f, 0.f, 0.f}, {0.f, 0.f, 0.f, 0.f}};

  for (int sb = 0; sb < 512; sb += 128) {
    __syncthreads();
    for (int i = threadIdx.x; i < 32 * 32; i += 256) {
      const int r = i >> 5, s4 = i & 31;
      const int row = rt * 32 + r;
      const int b = row >> 3, c = row & 7;
      const int base = s0 + sb + 4 * s4;
      const int t = base >> 3, r0 = base & 7;       // r0 in {0,4}
      const float4 xv = *(const float4*)(x + (size_t)row * 8192 + base);
      _Float16 p[4];
#pragma unroll
      for (int j = 0; j < 4; ++j) {
        const int rr = r0 + j;
        const int rev = ((rr & 1) << 2) | (rr & 2) | ((rr >> 2) & 1);   // bitrev3
        p[j] = P[(((size_t)rev * 128 + b) * 1024 + t) * 8 + c];
      }
      const h2 f01 = pkh(xv.x, xv.y) + (h2){p[0], p[1]};
      const h2 f23 = pkh(xv.z, xv.w) + (h2){p[2], p[3]};
      *(uint2*)&Fl[r][s4 * 2] = make_uint2(__builtin_bit_cast(unsigned int, f01),
                                           __builtin_bit_cast(unsigned int, f23));
    }
    for (int i = threadIdx.x; i < 64 * 32; i += 256) {
      const int hh = i >> 5, s4 = i & 31;
      float4 v = make_float4(0.f, 0.f, 0.f, 0.f);
      if (hh < 50) v = ((const float4*)(W + (size_t)hh * 8192 + s0 + sb))[s4];
      *(uint2*)&Wl[hh][s4 * 2] = make_uint2(pku(v.x, v.y), pku(v.z, v.w));
    }
    __syncthreads();
    for (int q = 0; q < 16; ++q) {
      const uint4 fa = *(const uint4*)&Fl[rg * 2][q * 4];
      const uint4 fb = *(const uint4*)&Fl[rg * 2 + 1][q * 4];
#pragma unroll
      for (int j = 0; j < 4; ++j) {
        const uint4 w = *(const uint4*)&Wl[hg + 16 * j][q * 4];
#pragma unroll
        for (int e = 0; e < 4; ++e) {
          const h2 we = __builtin_bit_cast(h2, (&w.x)[e]);
          acc[0][j] = __builtin_amdgcn_fdot2(we, __builtin_bit_cast(h2, (&fa.x)[e]), acc[0][j], false);
          acc[1][j] = __builtin_amdgcn_fdot2(we, __builtin_bit_cast(h2, (&fb.x)[e]), acc[1][j], false);
        }
      }
    }
  }
#pragma unroll
  for (int rr = 0; rr < 2; ++rr)
#pragma unroll
    for (int j = 0; j < 4; ++j)
      partial[((size_t)ch * 1024 + rt * 32 + rg * 2 + rr) * 64 + hg + 16 * j] = acc[rr][j];
}

// reduce partials + bias + relu, then FC2 -> out[row][24]; 4 rows per block
__global__ __launch_bounds__(256) void fc_stage2(
    const float* __restrict__ partial, const float* __restrict__ fc1b,
    const float* __restrict__ fc2w, const float* __restrict__ fc2b,
    float* __restrict__ out)
{
  const int rr = threadIdx.x >> 6;            // row within block: 0..3
  const int row = blockIdx.x * 4 + rr;
  const int h = threadIdx.x & 63;             // 0..63
  __shared__ float hs[4][64];
  float v = 0.f;
  if (h < 50) {
    for (int ch = 0; ch < 16; ++ch)
      v += partial[((size_t)ch * 1024 + row) * 64 + h];
    v += fc1b[h];
    v = v > 0.f ? v : 0.f;
  }
  hs[rr][h] = v;
  __syncthreads();
  if (h < 24) {
    float a = fc2b[h];
    for (int j = 0; j < 50; ++j)
      a = fmaf(hs[rr][j], fc2w[h * 50 + j], a);
    out[(size_t)row * 24 + h] = a;
  }
}

extern "C" void kernel_launch(void* const* d_in, const int* in_sizes, int n_in,
                              void* d_out, int out_size, void* d_ws, size_t ws_size,
                              hipStream_t stream)
{
  const float* x    = (const float*)d_in[0];
  const float* w1a  = (const float*)d_in[1];  // (3,4,32,8,3)
  const float* w2a  = (const float*)d_in[2];  // (3,4,8,32,3)
  const float* fc1w = (const float*)d_in[3];  // (50,8192)
  const float* fc1b = (const float*)d_in[4];  // (50,)
  const float* fc2w = (const float*)d_in[5];  // (24,50)
  const float* fc2b = (const float*)d_in[6];  // (24,)
  float* out = (float*)d_out;

  _Float16* bufA = (_Float16*)d_ws;                       // 8.4M halves (16.8 MB)
  _Float16* bufB = bufA + (size_t)9 * 1024 * 1024;        // 8.4M halves
  float* partial = (float*)((char*)d_ws + (size_t)40 * 1024 * 1024);  // 4 MB

  pack_mfma<<<dim3(15), dim3(256), 0, stream>>>(w1a, w2a);

  // lvl0: x(f32 ch-major) -> bufA(f16 pos-major) ; lvl1: bufA -> bufB ; lvl2: bufB -> bufA
  level_fused<false><<<dim3(4096), dim3(256), 0, stream>>>(x,    bufA, 0, 4096, 32);
  level_fused<true ><<<dim3(4096), dim3(256), 0, stream>>>(bufA, bufB, 1, 2048, 16);
  level_fused<true ><<<dim3(4096), dim3(256), 0, stream>>>(bufB, bufA, 2, 1024, 8);

  fc1_fused<<<dim3(512), dim3(256), 0, stream>>>(bufA, x, fc1w, partial);
  fc_stage2<<<dim3(256), dim3(256), 0, stream>>>(partial, fc1b, fc2w, fc2b, out);
  (void)in_sizes; (void)n_in; (void)out_size; (void)ws_size;
}

// Round 13
// 123.074 us; speedup vs baseline: 4.4007x; 1.0056x over previous
//
#include <hip/hip_runtime.h>

#define TT   128        // output positions per side per block
#define TIN2 (TT + 8)   // staged X: pos -4 .. TT+3
#define NHA  (TT + 6)   // hidA rows: pos -3 .. TT+2
#define NEO  (TT + 4)   // Es/Os rows: pos -2 .. TT+1
#define NHB  (TT + 2)   // hidB rows: pos -1 .. TT

typedef _Float16 h2 __attribute__((ext_vector_type(2)));
typedef __fp16 fp16v2 __attribute__((ext_vector_type(2)));
typedef _Float16 f16x8 __attribute__((ext_vector_type(8)));
typedef float f32x4 __attribute__((ext_vector_type(4)));

// MFMA A-fragments of conv weights (device-global; rewritten every launch).
__device__ _Float16 g_w1A[12][2][64][8];  // conv1: [lvl*4+pair][Mtile][lane][j], k=kk*8+ic (kk=3 zero)
__device__ _Float16 g_w2A[12][3][64][8];  // conv2: [lvl*4+pair][tap][lane][j], hc PERMUTED (see pack), oc rows 8..15 zero

__device__ __forceinline__ h2 pkh(float a, float b) {
  fp16v2 r = __builtin_amdgcn_cvt_pkrtz(a, b);
  return __builtin_bit_cast(h2, r);
}
__device__ __forceinline__ unsigned int pku(float a, float b) {
  return __builtin_bit_cast(unsigned int, pkh(a, b));
}
__device__ __forceinline__ float fast_tanh(float x) {
  return 1.f - __fdividef(2.f, __expf(2.f * x) + 1.f);
}
// packed leaky: max(x, 0.01x) elementwise on 2 halves (v_pk_mul + v_pk_max)
__device__ __forceinline__ unsigned int lky(unsigned int u) {
  h2 v = __builtin_bit_cast(h2, u);
  h2 s = v * (h2){(_Float16)0.01f, (_Float16)0.01f};
  h2 m = __builtin_elementwise_max(v, s);
  return __builtin_bit_cast(unsigned int, m);
}
// lanes 0-31 keep a_low; lanes 32-63 receive b_low from (lane-32)
__device__ __forceinline__ float lane_spread(float a_low, float b_low, int lane) {
  float s = __shfl_xor(b_low, 32);
  return (lane >= 32) ? s : a_low;
}
// swizzled 16B-group slot within a 64B hid row: g ^ ((row>>1)&3).
// row = 16m + col per lane -> the XOR term is lane-invariant and hoisted.
#define HID_PTR(hid, side, row, g) (&(hid)[side][row][(((g) ^ (((row) >> 1) & 3)) * 8)])

__global__ __launch_bounds__(256) void pack_mfma(
    const float* __restrict__ w1, const float* __restrict__ w2)
{
  int id = blockIdx.x * 256 + threadIdx.x;
  if (id >= 12 * 5 * 64) return;
  const int lane = id & 63;
  const int rest = id >> 6;
  const int slot = rest % 5;
  const int pr   = rest / 5;           // lvl*4+pair
  if (slot < 2) {                      // conv1 A-fragment, M-tile = slot
    const int oc = slot * 16 + (lane & 15);
    const int bb = lane >> 4;          // tap index; bb=3 -> zero pad
#pragma unroll
    for (int j = 0; j < 8; ++j) {
      float v = (bb < 3) ? w1[((size_t)pr * 32 + oc) * 24 + j * 3 + bb] : 0.f;
      g_w1A[pr][slot][lane][j] = (_Float16)v;
    }
  } else {                             // conv2 A-fragment, tap t; hc permuted to match
    const int t = slot - 2;            // hid LDS layout: offset 8*kk+j -> hc below
    const int oc = lane & 15;
    const int kk = lane >> 4;
#pragma unroll
    for (int j = 0; j < 8; ++j) {
      const int hc = (j < 4) ? (4 * kk + j) : (16 + 4 * kk + (j - 4));
      float v = (oc < 8) ? w2[((size_t)pr * 8 + oc) * 96 + hc * 3 + t] : 0.f;
      g_w2A[pr][t][lane][j] = (_Float16)v;
    }
  }
}

// Fused level. Input: lvl0 = f32 channel-major [nB][8][T]; lvl1/2 = f16 pos-major
// [nB][T][8]. Output (all levels): f16 pos-major NEXT[(2i+side)*128+b][T2][8].
//   A: Es = F_even*exp(tanh(conv(F_odd,p1))), Os = F_odd*exp(tanh(conv(F_even,p3)))
//   B: seq 2i   = Os - tanh(conv(Os,p0));  seq 2i+1 = Es + tanh(conv(Es,p2))
template <bool IN16>
__global__ __launch_bounds__(256) void level_fused(
    const void* __restrict__ Xv, _Float16* __restrict__ NEXT,
    int lvl, int T2, int tilesPerSeq)
{
  __shared__ __align__(16) _Float16 inS[2][TIN2][8];    // [side][pos+4][ch]
  __shared__ __align__(16) _Float16 hidS[2][NHA][32];   // 64B rows, swizzled 16B groups
  __shared__ __align__(16) _Float16 esS[2][NEO][8];     // Es/Os f16 (B conv input + base)

  const int blk = blockIdx.x;
  const int nb  = blk / tilesPerSeq;
  const int t0  = (blk - nb * tilesPerSeq) * TT;

  if constexpr (IN16) {
    // pos-major f16: row (2p+s) of 8 f16 = 16B -> one uint4 per (side,pos)
    const _Float16* Xh = (const _Float16*)Xv + (size_t)nb * (2 * (size_t)T2) * 8;
    for (int it = threadIdx.x; it < 2 * TIN2; it += 256) {
      const int s = it & 1, jj = it >> 1;
      int p = t0 - 4 + jj;
      p = p < 0 ? 0 : (p > T2 - 1 ? T2 - 1 : p);     // clamp in side-position space
      *(uint4*)&inS[s][jj][0] = *(const uint4*)&Xh[(size_t)(2 * p + s) * 8];
    }
  } else {
    const float* X = (const float*)Xv;
    const float2* Xrow = (const float2*)(X + (size_t)nb * 8 * (2 * (size_t)T2));
    for (int jj = threadIdx.x; jj < TIN2; jj += 256) {
      int j = t0 - 4 + jj;
      j = j < 0 ? 0 : (j > T2 - 1 ? T2 - 1 : j);
      unsigned int u0[4], u1[4];
#pragma unroll
      for (int cp = 0; cp < 4; ++cp) {
        float2 a = Xrow[(size_t)(2 * cp) * T2 + j];
        float2 b = Xrow[(size_t)(2 * cp + 1) * T2 + j];
        u0[cp] = pku(a.x, b.x);                      // side0 = odd
        u1[cp] = pku(a.y, b.y);                      // side1 = even
      }
      *(uint4*)&inS[0][jj][0] = make_uint4(u0[0], u0[1], u0[2], u0[3]);
      *(uint4*)&inS[1][jj][0] = make_uint4(u1[0], u1[1], u1[2], u1[3]);
    }
  }
  __syncthreads();

  const int wid  = __builtin_amdgcn_readfirstlane((int)(threadIdx.x >> 6));
  const int lane = threadIdx.x & 63;
  const int side = wid >> 1, half = wid & 1;
  const int g = lane >> 4, col = lane & 15;
  const int tb = half * 64;            // halves overlap rows 64..79 (benign identical writes)
  const int rp = ((lane >> 4) & 1) * 2 + (lane >> 5);   // row-pair after lane_spread

  const int pa = lvl * 4 + (side ? 3 : 1);
  const int pb = lvl * 4 + (side ? 2 : 0);
  const f16x8 a1w0 = *(const f16x8*)&g_w1A[pa][0][lane][0];
  const f16x8 a1w1 = *(const f16x8*)&g_w1A[pa][1][lane][0];
  const f16x8 a2w0 = *(const f16x8*)&g_w2A[pa][0][lane][0];
  const f16x8 a2w1 = *(const f16x8*)&g_w2A[pa][1][lane][0];
  const f16x8 a2w2 = *(const f16x8*)&g_w2A[pa][2][lane][0];
  const f16x8 b1w0 = *(const f16x8*)&g_w1A[pb][0][lane][0];
  const f16x8 b1w1 = *(const f16x8*)&g_w1A[pb][1][lane][0];
  const f16x8 b2w0 = *(const f16x8*)&g_w2A[pb][0][lane][0];
  const f16x8 b2w1 = *(const f16x8*)&g_w2A[pb][1][lane][0];
  const f16x8 b2w2 = *(const f16x8*)&g_w2A[pb][2][lane][0];
  const f32x4 zero = {0.f, 0.f, 0.f, 0.f};

  // ---- A1: hidA rows (pos -3..TT+2); one swizzled b128 write/lane/tile ----
#pragma unroll
  for (int nt = 0; nt < 5; ++nt) {
    const int row = tb + nt * 16 + col;
    const int rr = (row + g > TIN2 - 1) ? (TIN2 - 1) : (row + g);
    const f16x8 bf = *(const f16x8*)&inS[side][rr][0];
    f32x4 d0 = __builtin_amdgcn_mfma_f32_16x16x32_f16(a1w0, bf, zero, 0, 0, 0);
    f32x4 d1 = __builtin_amdgcn_mfma_f32_16x16x32_f16(a1w1, bf, zero, 0, 0, 0);
    if (row < NHA) {
      *(uint4*)HID_PTR(hidS, side, row, g) = make_uint4(
          lky(pku(d0[0], d0[1])), lky(pku(d0[2], d0[3])),
          lky(pku(d1[0], d1[1])), lky(pku(d1[2], d1[3])));
    }
  }
  __syncthreads();

  // ---- A2: Es/Os rows (pos -2..TT+1), epilogue spread over all 64 lanes ----
  // No bounds-clamp on reads: rows >= NEO belong to discarded lanes; OOB LDS
  // reads are faultless and their MFMA results are never written.
#pragma unroll
  for (int nt = 0; nt < 5; ++nt) {
    const int row = tb + nt * 16 + col;
    f32x4 acc = zero;
    acc = __builtin_amdgcn_mfma_f32_16x16x32_f16(a2w0, *(const f16x8*)HID_PTR(hidS, side, row,     g), acc, 0, 0, 0);
    acc = __builtin_amdgcn_mfma_f32_16x16x32_f16(a2w1, *(const f16x8*)HID_PTR(hidS, side, row + 1, g), acc, 0, 0, 0);
    acc = __builtin_amdgcn_mfma_f32_16x16x32_f16(a2w2, *(const f16x8*)HID_PTR(hidS, side, row + 2, g), acc, 0, 0, 0);
    if (row < NEO) {
      const float va = lane_spread(acc[0], acc[2], lane);
      const float vb = lane_spread(acc[1], acc[3], lane);
      const h2 mpk = *(const h2*)&inS[side ^ 1][row + 2][2 * rp];  // multiplier (f16, staged)
      const float v0 = (float)mpk[0] * __expf(fast_tanh(va));
      const float v1 = (float)mpk[1] * __expf(fast_tanh(vb));
      *(unsigned int*)&esS[side][row][2 * rp] = pku(v0, v1);
    }
  }
  __syncthreads();

  // ---- B1: hidB rows (pos -1..TT), conv input = other side's Es/Os ----
  const int srcB = side ^ 1;
  const int eoLo = (t0 == 0) ? 2 : 0;                       // replicate-edge padding of Os/Es
  const int eoHi = (t0 + TT >= T2) ? (TT + 1) : (NEO - 1);
#pragma unroll
  for (int nt = 0; nt < 5; ++nt) {
    const int row = tb + nt * 16 + col;
    int rr = row + g;
    rr = rr < eoLo ? eoLo : (rr > eoHi ? eoHi : rr);
    const f16x8 bf = *(const f16x8*)&esS[srcB][rr][0];
    f32x4 d0 = __builtin_amdgcn_mfma_f32_16x16x32_f16(b1w0, bf, zero, 0, 0, 0);
    f32x4 d1 = __builtin_amdgcn_mfma_f32_16x16x32_f16(b1w1, bf, zero, 0, 0, 0);
    if (row < NHB) {
      *(uint4*)HID_PTR(hidS, side, row, g) = make_uint4(
          lky(pku(d0[0], d0[1])), lky(pku(d0[2], d0[3])),
          lky(pku(d1[0], d1[1])), lky(pku(d1[2], d1[3])));
    }
  }
  __syncthreads();

  // ---- B2: outputs (f16 pos-major), one coalesced 4B store per lane-iter ----
  const float sgn = side ? 1.f : -1.f;
  const int i = nb >> 7;          // B = 128
  const int b = nb & 127;
  const int outseq = 2 * i + side;
  _Float16* outbase = NEXT + ((size_t)outseq * 128 + b) * (size_t)T2 * 8;
#pragma unroll
  for (int nt = 0; nt < 4; ++nt) {
    const int row = half * 64 + nt * 16 + col;      // output pos, exact [0,128)
    f32x4 acc = zero;
    acc = __builtin_amdgcn_mfma_f32_16x16x32_f16(b2w0, *(const f16x8*)HID_PTR(hidS, side, row,     g), acc, 0, 0, 0);
    acc = __builtin_amdgcn_mfma_f32_16x16x32_f16(b2w1, *(const f16x8*)HID_PTR(hidS, side, row + 1, g), acc, 0, 0, 0);
    acc = __builtin_amdgcn_mfma_f32_16x16x32_f16(b2w2, *(const f16x8*)HID_PTR(hidS, side, row + 2, g), acc, 0, 0, 0);
    const float va = lane_spread(acc[0], acc[2], lane);
    const float vb = lane_spread(acc[1], acc[3], lane);
    const h2 base = *(const h2*)&esS[srcB][row + 2][2 * rp];
    const int tg = t0 + row;
    *(unsigned int*)&outbase[(size_t)tg * 8 + 2 * rp] =
        pku((float)base[0] + sgn * fast_tanh(va), (float)base[1] + sgn * fast_tanh(vb));
  }
}

// FC1 split-K (dot2, f16 operands): F[row][8t+r] = P[rev3(r)][b][t][c] + x[row][8t+r]
// P is f16 pos-major: [seq8*128+b][t(1024)][c(8)]
__global__ __launch_bounds__(256) void fc1_fused(
    const _Float16* __restrict__ P, const float* __restrict__ x,
    const float* __restrict__ W, float* __restrict__ partial)
{
  const int rt = blockIdx.x & 31;   // row tile: 32 rows
  const int ch = blockIdx.x >> 5;   // 16 chunks of 512 s
  const int s0 = ch * 512;
  __shared__ unsigned int Fl[32][68];   // h2 pairs: 64 h2 = 128 s per sub-block
  __shared__ unsigned int Wl[64][68];
  const int hg = threadIdx.x & 15;
  const int rg = threadIdx.x >> 4;  // 0..15
  float acc[2][4] = {{0.f, 0.f, 0.f, 0.f}, {0.f, 0.f, 0.f, 0.f}};

  for (int sb = 0; sb < 512; sb += 128) {
    __syncthreads();
    for (int i = threadIdx.x; i < 32 * 32; i += 256) {
      const int r = i >> 5, s4 = i & 31;
      const int row = rt * 32 + r;
      const int b = row >> 3, c = row & 7;
      const int base = s0 + sb + 4 * s4;
      const int t = base >> 3, r0 = base & 7;       // r0 in {0,4}
      const float4 xv = *(const float4*)(x + (size_t)row * 8192 + base);
      _Float16 p[4];
#pragma unroll
      for (int j = 0; j < 4; ++j) {
        const int rr = r0 + j;
        const int rev = ((rr & 1) << 2) | (rr & 2) | ((rr >> 2) & 1);   // bitrev3
        p[j] = P[(((size_t)rev * 128 + b) * 1024 + t) * 8 + c];
      }
      const h2 f01 = pkh(xv.x, xv.y) + (h2){p[0], p[1]};
      const h2 f23 = pkh(xv.z, xv.w) + (h2){p[2], p[3]};
      *(uint2*)&Fl[r][s4 * 2] = make_uint2(__builtin_bit_cast(unsigned int, f01),
                                           __builtin_bit_cast(unsigned int, f23));
    }
    for (int i = threadIdx.x; i < 64 * 32; i += 256) {
      const int hh = i >> 5, s4 = i & 31;
      float4 v = make_float4(0.f, 0.f, 0.f, 0.f);
      if (hh < 50) v = ((const float4*)(W + (size_t)hh * 8192 + s0 + sb))[s4];
      *(uint2*)&Wl[hh][s4 * 2] = make_uint2(pku(v.x, v.y), pku(v.z, v.w));
    }
    __syncthreads();
    for (int q = 0; q < 16; ++q) {
      const uint4 fa = *(const uint4*)&Fl[rg * 2][q * 4];
      const uint4 fb = *(const uint4*)&Fl[rg * 2 + 1][q * 4];
#pragma unroll
      for (int j = 0; j < 4; ++j) {
        const uint4 w = *(const uint4*)&Wl[hg + 16 * j][q * 4];
#pragma unroll
        for (int e = 0; e < 4; ++e) {
          const h2 we = __builtin_bit_cast(h2, (&w.x)[e]);
          acc[0][j] = __builtin_amdgcn_fdot2(we, __builtin_bit_cast(h2, (&fa.x)[e]), acc[0][j], false);
          acc[1][j] = __builtin_amdgcn_fdot2(we, __builtin_bit_cast(h2, (&fb.x)[e]), acc[1][j], false);
        }
      }
    }
  }
#pragma unroll
  for (int rr = 0; rr < 2; ++rr)
#pragma unroll
    for (int j = 0; j < 4; ++j)
      partial[((size_t)ch * 1024 + rt * 32 + rg * 2 + rr) * 64 + hg + 16 * j] = acc[rr][j];
}

// reduce partials + bias + relu, then FC2 -> out[row][24]; 4 rows per block
__global__ __launch_bounds__(256) void fc_stage2(
    const float* __restrict__ partial, const float* __restrict__ fc1b,
    const float* __restrict__ fc2w, const float* __restrict__ fc2b,
    float* __restrict__ out)
{
  const int rr = threadIdx.x >> 6;            // row within block: 0..3
  const int row = blockIdx.x * 4 + rr;
  const int h = threadIdx.x & 63;             // 0..63
  __shared__ float hs[4][64];
  float v = 0.f;
  if (h < 50) {
    for (int ch = 0; ch < 16; ++ch)
      v += partial[((size_t)ch * 1024 + row) * 64 + h];
    v += fc1b[h];
    v = v > 0.f ? v : 0.f;
  }
  hs[rr][h] = v;
  __syncthreads();
  if (h < 24) {
    float a = fc2b[h];
    for (int j = 0; j < 50; ++j)
      a = fmaf(hs[rr][j], fc2w[h * 50 + j], a);
    out[(size_t)row * 24 + h] = a;
  }
}

extern "C" void kernel_launch(void* const* d_in, const int* in_sizes, int n_in,
                              void* d_out, int out_size, void* d_ws, size_t ws_size,
                              hipStream_t stream)
{
  const float* x    = (const float*)d_in[0];
  const float* w1a  = (const float*)d_in[1];  // (3,4,32,8,3)
  const float* w2a  = (const float*)d_in[2];  // (3,4,8,32,3)
  const float* fc1w = (const float*)d_in[3];  // (50,8192)
  const float* fc1b = (const float*)d_in[4];  // (50,)
  const float* fc2w = (const float*)d_in[5];  // (24,50)
  const float* fc2b = (const float*)d_in[6];  // (24,)
  float* out = (float*)d_out;

  _Float16* bufA = (_Float16*)d_ws;                       // 8.4M halves (16.8 MB)
  _Float16* bufB = bufA + (size_t)9 * 1024 * 1024;        // 8.4M halves
  float* partial = (float*)((char*)d_ws + (size_t)40 * 1024 * 1024);  // 4 MB

  pack_mfma<<<dim3(15), dim3(256), 0, stream>>>(w1a, w2a);

  // lvl0: x(f32 ch-major) -> bufA(f16 pos-major) ; lvl1: bufA -> bufB ; lvl2: bufB -> bufA
  level_fused<false><<<dim3(4096), dim3(256), 0, stream>>>(x,    bufA, 0, 4096, 32);
  level_fused<true ><<<dim3(4096), dim3(256), 0, stream>>>(bufA, bufB, 1, 2048, 16);
  level_fused<true ><<<dim3(4096), dim3(256), 0, stream>>>(bufB, bufA, 2, 1024, 8);

  fc1_fused<<<dim3(512), dim3(256), 0, stream>>>(bufA, x, fc1w, partial);
  fc_stage2<<<dim3(256), dim3(256), 0, stream>>>(partial, fc1b, fc2w, fc2b, out);
  (void)in_sizes; (void)n_in; (void)out_size; (void)ws_size;
}

// Round 14
// 118.127 us; speedup vs baseline: 4.5850x; 1.0419x over previous
//
#include <hip/hip_runtime.h>

#define TT   256        // output positions per side per block
#define TIN2 (TT + 8)   // staged X: pos -4 .. TT+3
#define NHA  (TT + 6)   // hidA rows: pos -3 .. TT+2
#define NEO  (TT + 4)   // Es/Os rows: pos -2 .. TT+1
#define NHB  (TT + 2)   // hidB rows: pos -1 .. TT

typedef _Float16 h2 __attribute__((ext_vector_type(2)));
typedef __fp16 fp16v2 __attribute__((ext_vector_type(2)));
typedef _Float16 f16x8 __attribute__((ext_vector_type(8)));
typedef float f32x4 __attribute__((ext_vector_type(4)));

// MFMA A-fragments of conv weights (device-global; rewritten every launch).
__device__ _Float16 g_w1A[12][2][64][8];  // conv1: [lvl*4+pair][Mtile][lane][j], k=kk*8+ic (kk=3 zero)
__device__ _Float16 g_w2A[12][3][64][8];  // conv2: [lvl*4+pair][tap][lane][j], hc PERMUTED (see pack), oc rows 8..15 zero

__device__ __forceinline__ h2 pkh(float a, float b) {
  fp16v2 r = __builtin_amdgcn_cvt_pkrtz(a, b);
  return __builtin_bit_cast(h2, r);
}
__device__ __forceinline__ unsigned int pku(float a, float b) {
  return __builtin_bit_cast(unsigned int, pkh(a, b));
}
__device__ __forceinline__ float fast_tanh(float x) {
  return 1.f - __fdividef(2.f, __expf(2.f * x) + 1.f);
}
// packed leaky: max(x, 0.01x) elementwise on 2 halves (v_pk_mul + v_pk_max)
__device__ __forceinline__ unsigned int lky(unsigned int u) {
  h2 v = __builtin_bit_cast(h2, u);
  h2 s = v * (h2){(_Float16)0.01f, (_Float16)0.01f};
  h2 m = __builtin_elementwise_max(v, s);
  return __builtin_bit_cast(unsigned int, m);
}
// lanes 0-31 keep a_low; lanes 32-63 receive b_low from (lane-32)
__device__ __forceinline__ float lane_spread(float a_low, float b_low, int lane) {
  float s = __shfl_xor(b_low, 32);
  return (lane >= 32) ? s : a_low;
}
// swizzled 16B-group slot within a 64B hid row (bijective per row, same on R/W)
#define HID_PTR(hid, side, row, g) (&(hid)[side][row][(((g) ^ (((row) >> 1) & 3)) * 8)])

__global__ __launch_bounds__(256) void pack_mfma(
    const float* __restrict__ w1, const float* __restrict__ w2)
{
  int id = blockIdx.x * 256 + threadIdx.x;
  if (id >= 12 * 5 * 64) return;
  const int lane = id & 63;
  const int rest = id >> 6;
  const int slot = rest % 5;
  const int pr   = rest / 5;           // lvl*4+pair
  if (slot < 2) {                      // conv1 A-fragment, M-tile = slot
    const int oc = slot * 16 + (lane & 15);
    const int bb = lane >> 4;          // tap index; bb=3 -> zero pad
#pragma unroll
    for (int j = 0; j < 8; ++j) {
      float v = (bb < 3) ? w1[((size_t)pr * 32 + oc) * 24 + j * 3 + bb] : 0.f;
      g_w1A[pr][slot][lane][j] = (_Float16)v;
    }
  } else {                             // conv2 A-fragment, tap t; hc permuted to match
    const int t = slot - 2;            // hid LDS layout: offset 8*kk+j -> hc below
    const int oc = lane & 15;
    const int kk = lane >> 4;
#pragma unroll
    for (int j = 0; j < 8; ++j) {
      const int hc = (j < 4) ? (4 * kk + j) : (16 + 4 * kk + (j - 4));
      float v = (oc < 8) ? w2[((size_t)pr * 8 + oc) * 96 + hc * 3 + t] : 0.f;
      g_w2A[pr][t][lane][j] = (_Float16)v;
    }
  }
}

// Fused level, 512 threads = 8 waves = 2 sides x 4 quarters.
// Input: lvl0 = f32 channel-major [nB][8][T]; lvl1/2 = f16 pos-major [nB][T][8].
// Output: f16 pos-major NEXT[(2i+side)*128+b][T2][8].
//   A: Es = F_even*exp(tanh(conv(F_odd,p1))), Os = F_odd*exp(tanh(conv(F_even,p3)))
//   B: seq 2i   = Os - tanh(conv(Os,p0));  seq 2i+1 = Es + tanh(conv(Es,p2))
template <bool IN16>
__global__ __launch_bounds__(512) void level_fused(
    const void* __restrict__ Xv, _Float16* __restrict__ NEXT,
    int lvl, int T2, int tilesPerSeq)
{
  __shared__ __align__(16) _Float16 inS[2][TIN2][8];    // [side][pos+4][ch]
  __shared__ __align__(16) _Float16 hidS[2][NHA][32];   // 64B rows, swizzled 16B groups
  __shared__ __align__(16) _Float16 esS[2][NEO][8];     // Es/Os f16 (B conv input + base)

  const int blk = blockIdx.x;
  const int nb  = blk / tilesPerSeq;
  const int t0  = (blk - nb * tilesPerSeq) * TT;

  if constexpr (IN16) {
    // pos-major f16: row (2p+s) of 8 f16 = 16B -> one uint4 per (side,pos)
    const _Float16* Xh = (const _Float16*)Xv + (size_t)nb * (2 * (size_t)T2) * 8;
    for (int it = threadIdx.x; it < 2 * TIN2; it += 512) {
      const int s = it & 1, jj = it >> 1;
      int p = t0 - 4 + jj;
      p = p < 0 ? 0 : (p > T2 - 1 ? T2 - 1 : p);     // clamp in side-position space
      *(uint4*)&inS[s][jj][0] = *(const uint4*)&Xh[(size_t)(2 * p + s) * 8];
    }
  } else {
    const float* X = (const float*)Xv;
    const float2* Xrow = (const float2*)(X + (size_t)nb * 8 * (2 * (size_t)T2));
    for (int jj = threadIdx.x; jj < TIN2; jj += 512) {
      int j = t0 - 4 + jj;
      j = j < 0 ? 0 : (j > T2 - 1 ? T2 - 1 : j);
      unsigned int u0[4], u1[4];
#pragma unroll
      for (int cp = 0; cp < 4; ++cp) {
        float2 a = Xrow[(size_t)(2 * cp) * T2 + j];
        float2 b = Xrow[(size_t)(2 * cp + 1) * T2 + j];
        u0[cp] = pku(a.x, b.x);                      // side0 = odd
        u1[cp] = pku(a.y, b.y);                      // side1 = even
      }
      *(uint4*)&inS[0][jj][0] = make_uint4(u0[0], u0[1], u0[2], u0[3]);
      *(uint4*)&inS[1][jj][0] = make_uint4(u1[0], u1[1], u1[2], u1[3]);
    }
  }
  __syncthreads();

  const int wid  = __builtin_amdgcn_readfirstlane((int)(threadIdx.x >> 6));
  const int lane = threadIdx.x & 63;
  const int side = wid >> 2, q = wid & 3;            // 2 sides x 4 quarters
  const int g = lane >> 4, col = lane & 15;
  // disjoint 16-row tiles: q0 gets 5, q1..q3 get 4 (17 tiles cover 272 slots)
  const int tstart = (q == 0) ? 0 : (1 + 4 * q);     // 0,5,9,13
  const int tcnt   = (q == 0) ? 5 : 4;
  const int rp = ((lane >> 4) & 1) * 2 + (lane >> 5);   // row-pair after lane_spread

  const int pa = lvl * 4 + (side ? 3 : 1);
  const int pb = lvl * 4 + (side ? 2 : 0);
  const f16x8 a1w0 = *(const f16x8*)&g_w1A[pa][0][lane][0];
  const f16x8 a1w1 = *(const f16x8*)&g_w1A[pa][1][lane][0];
  const f16x8 a2w0 = *(const f16x8*)&g_w2A[pa][0][lane][0];
  const f16x8 a2w1 = *(const f16x8*)&g_w2A[pa][1][lane][0];
  const f16x8 a2w2 = *(const f16x8*)&g_w2A[pa][2][lane][0];
  const f16x8 b1w0 = *(const f16x8*)&g_w1A[pb][0][lane][0];
  const f16x8 b1w1 = *(const f16x8*)&g_w1A[pb][1][lane][0];
  const f16x8 b2w0 = *(const f16x8*)&g_w2A[pb][0][lane][0];
  const f16x8 b2w1 = *(const f16x8*)&g_w2A[pb][1][lane][0];
  const f16x8 b2w2 = *(const f16x8*)&g_w2A[pb][2][lane][0];
  const f32x4 zero = {0.f, 0.f, 0.f, 0.f};

  // ---- A1: hidA rows (pos -3..TT+2); one swizzled b128 write/lane/tile ----
#pragma unroll
  for (int nt = 0; nt < 5; ++nt) {
    if (nt >= tcnt) break;
    const int row = (tstart + nt) * 16 + col;
    const int rr = (row + g > TIN2 - 1) ? (TIN2 - 1) : (row + g);
    const f16x8 bf = *(const f16x8*)&inS[side][rr][0];
    f32x4 d0 = __builtin_amdgcn_mfma_f32_16x16x32_f16(a1w0, bf, zero, 0, 0, 0);
    f32x4 d1 = __builtin_amdgcn_mfma_f32_16x16x32_f16(a1w1, bf, zero, 0, 0, 0);
    if (row < NHA) {
      *(uint4*)HID_PTR(hidS, side, row, g) = make_uint4(
          lky(pku(d0[0], d0[1])), lky(pku(d0[2], d0[3])),
          lky(pku(d1[0], d1[1])), lky(pku(d1[2], d1[3])));
    }
  }
  __syncthreads();

  // ---- A2: Es/Os rows (pos -2..TT+1), epilogue spread over all 64 lanes ----
  // No bounds-clamp on reads: OOB LDS reads are faultless; results discarded.
#pragma unroll
  for (int nt = 0; nt < 5; ++nt) {
    if (nt >= tcnt) break;
    const int row = (tstart + nt) * 16 + col;
    f32x4 acc = zero;
    acc = __builtin_amdgcn_mfma_f32_16x16x32_f16(a2w0, *(const f16x8*)HID_PTR(hidS, side, row,     g), acc, 0, 0, 0);
    acc = __builtin_amdgcn_mfma_f32_16x16x32_f16(a2w1, *(const f16x8*)HID_PTR(hidS, side, row + 1, g), acc, 0, 0, 0);
    acc = __builtin_amdgcn_mfma_f32_16x16x32_f16(a2w2, *(const f16x8*)HID_PTR(hidS, side, row + 2, g), acc, 0, 0, 0);
    if (row < NEO) {
      const float va = lane_spread(acc[0], acc[2], lane);
      const float vb = lane_spread(acc[1], acc[3], lane);
      const h2 mpk = *(const h2*)&inS[side ^ 1][row + 2][2 * rp];  // multiplier (f16, staged)
      const float v0 = (float)mpk[0] * __expf(fast_tanh(va));
      const float v1 = (float)mpk[1] * __expf(fast_tanh(vb));
      *(unsigned int*)&esS[side][row][2 * rp] = pku(v0, v1);
    }
  }
  __syncthreads();

  // ---- B1: hidB rows (pos -1..TT), conv input = other side's Es/Os ----
  const int srcB = side ^ 1;
  const int eoLo = (t0 == 0) ? 2 : 0;                       // replicate-edge padding of Os/Es
  const int eoHi = (t0 + TT >= T2) ? (TT + 1) : (NEO - 1);
#pragma unroll
  for (int nt = 0; nt < 5; ++nt) {
    if (nt >= tcnt) break;
    const int row = (tstart + nt) * 16 + col;
    int rr = row + g;
    rr = rr < eoLo ? eoLo : (rr > eoHi ? eoHi : rr);
    const f16x8 bf = *(const f16x8*)&esS[srcB][rr][0];
    f32x4 d0 = __builtin_amdgcn_mfma_f32_16x16x32_f16(b1w0, bf, zero, 0, 0, 0);
    f32x4 d1 = __builtin_amdgcn_mfma_f32_16x16x32_f16(b1w1, bf, zero, 0, 0, 0);
    if (row < NHB) {
      *(uint4*)HID_PTR(hidS, side, row, g) = make_uint4(
          lky(pku(d0[0], d0[1])), lky(pku(d0[2], d0[3])),
          lky(pku(d1[0], d1[1])), lky(pku(d1[2], d1[3])));
    }
  }
  __syncthreads();

  // ---- B2: outputs (f16 pos-major), one coalesced 4B store per lane-iter ----
  const float sgn = side ? 1.f : -1.f;
  const int i = nb >> 7;          // B = 128
  const int b = nb & 127;
  const int outseq = 2 * i + side;
  _Float16* outbase = NEXT + ((size_t)outseq * 128 + b) * (size_t)T2 * 8;
#pragma unroll
  for (int nt = 0; nt < 4; ++nt) {
    const int row = q * 64 + nt * 16 + col;         // output pos, exact [0,256)
    f32x4 acc = zero;
    acc = __builtin_amdgcn_mfma_f32_16x16x32_f16(b2w0, *(const f16x8*)HID_PTR(hidS, side, row,     g), acc, 0, 0, 0);
    acc = __builtin_amdgcn_mfma_f32_16x16x32_f16(b2w1, *(const f16x8*)HID_PTR(hidS, side, row + 1, g), acc, 0, 0, 0);
    acc = __builtin_amdgcn_mfma_f32_16x16x32_f16(b2w2, *(const f16x8*)HID_PTR(hidS, side, row + 2, g), acc, 0, 0, 0);
    const float va = lane_spread(acc[0], acc[2], lane);
    const float vb = lane_spread(acc[1], acc[3], lane);
    const h2 base = *(const h2*)&esS[srcB][row + 2][2 * rp];
    const int tg = t0 + row;
    *(unsigned int*)&outbase[(size_t)tg * 8 + 2 * rp] =
        pku((float)base[0] + sgn * fast_tanh(va), (float)base[1] + sgn * fast_tanh(vb));
  }
}

// FC1 split-K (dot2, f16 operands): F[row][8t+r] = P[rev3(r)][b][t][c] + x[row][8t+r]
// P is f16 pos-major: [seq8*128+b][t(1024)][c(8)]
__global__ __launch_bounds__(256) void fc1_fused(
    const _Float16* __restrict__ P, const float* __restrict__ x,
    const float* __restrict__ W, float* __restrict__ partial)
{
  const int rt = blockIdx.x & 31;   // row tile: 32 rows
  const int ch = blockIdx.x >> 5;   // 16 chunks of 512 s
  const int s0 = ch * 512;
  __shared__ unsigned int Fl[32][68];   // h2 pairs: 64 h2 = 128 s per sub-block
  __shared__ unsigned int Wl[64][68];
  const int hg = threadIdx.x & 15;
  const int rg = threadIdx.x >> 4;  // 0..15
  float acc[2][4] = {{0.f, 0.f, 0.f, 0.f}, {0.f, 0.f, 0.f, 0.f}};

  for (int sb = 0; sb < 512; sb += 128) {
    __syncthreads();
    for (int i = threadIdx.x; i < 32 * 32; i += 256) {
      const int r = i >> 5, s4 = i & 31;
      const int row = rt * 32 + r;
      const int b = row >> 3, c = row & 7;
      const int base = s0 + sb + 4 * s4;
      const int t = base >> 3, r0 = base & 7;       // r0 in {0,4}
      const float4 xv = *(const float4*)(x + (size_t)row * 8192 + base);
      _Float16 p[4];
#pragma unroll
      for (int j = 0; j < 4; ++j) {
        const int rr = r0 + j;
        const int rev = ((rr & 1) << 2) | (rr & 2) | ((rr >> 2) & 1);   // bitrev3
        p[j] = P[(((size_t)rev * 128 + b) * 1024 + t) * 8 + c];
      }
      const h2 f01 = pkh(xv.x, xv.y) + (h2){p[0], p[1]};
      const h2 f23 = pkh(xv.z, xv.w) + (h2){p[2], p[3]};
      *(uint2*)&Fl[r][s4 * 2] = make_uint2(__builtin_bit_cast(unsigned int, f01),
                                           __builtin_bit_cast(unsigned int, f23));
    }
    for (int i = threadIdx.x; i < 64 * 32; i += 256) {
      const int hh = i >> 5, s4 = i & 31;
      float4 v = make_float4(0.f, 0.f, 0.f, 0.f);
      if (hh < 50) v = ((const float4*)(W + (size_t)hh * 8192 + s0 + sb))[s4];
      *(uint2*)&Wl[hh][s4 * 2] = make_uint2(pku(v.x, v.y), pku(v.z, v.w));
    }
    __syncthreads();
    for (int q = 0; q < 16; ++q) {
      const uint4 fa = *(const uint4*)&Fl[rg * 2][q * 4];
      const uint4 fb = *(const uint4*)&Fl[rg * 2 + 1][q * 4];
#pragma unroll
      for (int j = 0; j < 4; ++j) {
        const uint4 w = *(const uint4*)&Wl[hg + 16 * j][q * 4];
#pragma unroll
        for (int e = 0; e < 4; ++e) {
          const h2 we = __builtin_bit_cast(h2, (&w.x)[e]);
          acc[0][j] = __builtin_amdgcn_fdot2(we, __builtin_bit_cast(h2, (&fa.x)[e]), acc[0][j], false);
          acc[1][j] = __builtin_amdgcn_fdot2(we, __builtin_bit_cast(h2, (&fb.x)[e]), acc[1][j], false);
        }
      }
    }
  }
#pragma unroll
  for (int rr = 0; rr < 2; ++rr)
#pragma unroll
    for (int j = 0; j < 4; ++j)
      partial[((size_t)ch * 1024 + rt * 32 + rg * 2 + rr) * 64 + hg + 16 * j] = acc[rr][j];
}

// reduce partials + bias + relu, then FC2 -> out[row][24]; 4 rows per block
__global__ __launch_bounds__(256) void fc_stage2(
    const float* __restrict__ partial, const float* __restrict__ fc1b,
    const float* __restrict__ fc2w, const float* __restrict__ fc2b,
    float* __restrict__ out)
{
  const int rr = threadIdx.x >> 6;            // row within block: 0..3
  const int row = blockIdx.x * 4 + rr;
  const int h = threadIdx.x & 63;             // 0..63
  __shared__ float hs[4][64];
  float v = 0.f;
  if (h < 50) {
    for (int ch = 0; ch < 16; ++ch)
      v += partial[((size_t)ch * 1024 + row) * 64 + h];
    v += fc1b[h];
    v = v > 0.f ? v : 0.f;
  }
  hs[rr][h] = v;
  __syncthreads();
  if (h < 24) {
    float a = fc2b[h];
    for (int j = 0; j < 50; ++j)
      a = fmaf(hs[rr][j], fc2w[h * 50 + j], a);
    out[(size_t)row * 24 + h] = a;
  }
}

extern "C" void kernel_launch(void* const* d_in, const int* in_sizes, int n_in,
                              void* d_out, int out_size, void* d_ws, size_t ws_size,
                              hipStream_t stream)
{
  const float* x    = (const float*)d_in[0];
  const float* w1a  = (const float*)d_in[1];  // (3,4,32,8,3)
  const float* w2a  = (const float*)d_in[2];  // (3,4,8,32,3)
  const float* fc1w = (const float*)d_in[3];  // (50,8192)
  const float* fc1b = (const float*)d_in[4];  // (50,)
  const float* fc2w = (const float*)d_in[5];  // (24,50)
  const float* fc2b = (const float*)d_in[6];  // (24,)
  float* out = (float*)d_out;

  _Float16* bufA = (_Float16*)d_ws;                       // 8.4M halves (16.8 MB)
  _Float16* bufB = bufA + (size_t)9 * 1024 * 1024;        // 8.4M halves
  float* partial = (float*)((char*)d_ws + (size_t)40 * 1024 * 1024);  // 4 MB

  pack_mfma<<<dim3(15), dim3(256), 0, stream>>>(w1a, w2a);

  // lvl0: x(f32 ch-major) -> bufA(f16 pos-major) ; lvl1: bufA -> bufB ; lvl2: bufB -> bufA
  level_fused<false><<<dim3(2048), dim3(512), 0, stream>>>(x,    bufA, 0, 4096, 16);
  level_fused<true ><<<dim3(2048), dim3(512), 0, stream>>>(bufA, bufB, 1, 2048, 8);
  level_fused<true ><<<dim3(2048), dim3(512), 0, stream>>>(bufB, bufA, 2, 1024, 4);

  fc1_fused<<<dim3(512), dim3(256), 0, stream>>>(bufA, x, fc1w, partial);
  fc_stage2<<<dim3(256), dim3(256), 0, stream>>>(partial, fc1b, fc2w, fc2b, out);
  (void)in_sizes; (void)n_in; (void)out_size; (void)ws_size;
}